// Round 4
// baseline (37109.338 us; speedup 1.0000x reference)
//
#include <hip/hip_runtime.h>
#include <cstdint>

#define NPTOT 17742     // (67^2+33^2+16^2+8^2+4^2)*3
#define FEAT 117        // 4 bbox + 81 conf + 32 mask

// ---------------------------------------------------------------------------
// 1x1 conv: out[b,co,p] = bias[co] + sum_ci w[co,ci] * in[b,ci,p]   (Cout=256)
__global__ __launch_bounds__(256) void k_conv1x1(
    const float* __restrict__ in, const float* __restrict__ w,
    const float* __restrict__ bias, float* __restrict__ out, int Cin, int HW) {
  int p = blockIdx.x * 256 + threadIdx.x;
  int co = blockIdx.y, b = blockIdx.z;
  if (p >= HW) return;
  const float* ip = in + (size_t)b * Cin * HW + p;
  const float* wr = w + (size_t)co * Cin;
  float a = bias[co];
  for (int ci = 0; ci < Cin; ++ci) a = fmaf(wr[ci], ip[(size_t)ci * HW], a);
  out[((size_t)b * 256 + co) * HW + p] = a;
}

// ---------------------------------------------------------------------------
// jax-exact bilinear (triangle kernel, half-pixel, invalid-tap zeroing +
// renormalization), accumulated into out: out += resize(in).  C = 256.
__global__ __launch_bounds__(256) void k_resize_add(
    const float* __restrict__ in, float* __restrict__ out,
    int Hi, int Wi, int Ho, int Wo) {
  int p = blockIdx.x * 256 + threadIdx.x;
  int c = blockIdx.y, b = blockIdx.z;
  int HW = Ho * Wo;
  if (p >= HW) return;
  int y = p / Wo, x = p - y * Wo;
  float sy = (y + 0.5f) * (float)Hi / (float)Ho - 0.5f;
  float sx = (x + 0.5f) * (float)Wi / (float)Wo - 0.5f;
  int iy0 = (int)floorf(sy), ix0 = (int)floorf(sx);
  float wy1 = sy - (float)iy0, wy0 = 1.f - wy1;
  float wx1 = sx - (float)ix0, wx0 = 1.f - wx1;
  if (iy0 < 0 || iy0 >= Hi) wy0 = 0.f;
  if (iy0 + 1 < 0 || iy0 + 1 >= Hi) wy1 = 0.f;
  if (ix0 < 0 || ix0 >= Wi) wx0 = 0.f;
  if (ix0 + 1 < 0 || ix0 + 1 >= Wi) wx1 = 0.f;
  float ty = wy0 + wy1, tx = wx0 + wx1;   // never 0 for these shapes
  wy0 /= ty; wy1 /= ty; wx0 /= tx; wx1 /= tx;
  int y0 = min(max(iy0, 0), Hi - 1), y1 = min(max(iy0 + 1, 0), Hi - 1);
  int x0 = min(max(ix0, 0), Wi - 1), x1 = min(max(ix0 + 1, 0), Wi - 1);
  const float* ib = in + ((size_t)b * 256 + c) * Hi * Wi;
  float v = wy0 * (wx0 * ib[y0 * Wi + x0] + wx1 * ib[y0 * Wi + x1]) +
            wy1 * (wx0 * ib[y1 * Wi + x0] + wx1 * ib[y1 * Wi + x1]);
  out[((size_t)b * 256 + c) * HW + p] += v;
}

// ---------------------------------------------------------------------------
// 3x3 conv, zero-pad 0/1, optional relu. Cout = gridDim.y. 1 co per thread.
__global__ __launch_bounds__(256) void k_conv3x3(
    const float* __restrict__ in, const float* __restrict__ w,
    const float* __restrict__ bias, float* __restrict__ out,
    int Cin, int Hi, int Wi, int Ho, int Wo, int pad, int relu) {
  int p = blockIdx.x * 256 + threadIdx.x;
  int co = blockIdx.y, b = blockIdx.z;
  int Cout = gridDim.y;
  int HW = Ho * Wo;
  if (p >= HW) return;
  int y = p / Wo, x = p - y * Wo;
  float a = bias[co];
  const float* ib = in + (size_t)b * Cin * Hi * Wi;
  const float* wr = w + (size_t)co * Cin * 9;
  for (int ci = 0; ci < Cin; ++ci) {
    const float* ic = ib + (size_t)ci * Hi * Wi;
    const float* wc = wr + ci * 9;
#pragma unroll
    for (int ky = 0; ky < 3; ++ky) {
      int iy = y + ky - pad;
      if ((unsigned)iy >= (unsigned)Hi) continue;
#pragma unroll
      for (int kx = 0; kx < 3; ++kx) {
        int ix = x + kx - pad;
        if ((unsigned)ix >= (unsigned)Wi) continue;
        a = fmaf(wc[ky * 3 + kx], ic[iy * Wi + ix], a);
      }
    }
  }
  if (relu) a = fmaxf(a, 0.f);
  out[((size_t)b * Cout + co) * HW + p] = a;
}

// ---------------------------------------------------------------------------
// head conv 3x3 pad1 over 256 in-channels, scatter into (B, NPTOT, 117).
__global__ __launch_bounds__(256) void k_head(
    const float* __restrict__ u, const float* __restrict__ w,
    const float* __restrict__ bias, float* __restrict__ out,
    int H, int W, int pbase, int featDim, int featOff, int doTanh) {
  int p = blockIdx.x * 256 + threadIdx.x;
  int co = blockIdx.y, b = blockIdx.z;
  int HW = H * W;
  if (p >= HW) return;
  int y = p / W, x = p - y * W;
  float a = bias[co];
  const float* ib = u + (size_t)b * 256 * HW;
  const float* wr = w + (size_t)co * 256 * 9;
  for (int ci = 0; ci < 256; ++ci) {
    const float* ic = ib + (size_t)ci * HW;
    const float* wc = wr + ci * 9;
#pragma unroll
    for (int ky = 0; ky < 3; ++ky) {
      int iy = y + ky - 1;
      if ((unsigned)iy >= (unsigned)H) continue;
#pragma unroll
      for (int kx = 0; kx < 3; ++kx) {
        int ix = x + kx - 1;
        if ((unsigned)ix >= (unsigned)W) continue;
        a = fmaf(wc[ky * 3 + kx], ic[iy * W + ix], a);
      }
    }
  }
  if (doTanh) a = tanhf(a);
  int aIdx = co / featDim, k = co - aIdx * featDim;
  out[((size_t)b * NPTOT + pbase + (size_t)p * 3 + aIdx) * FEAT + featOff + k] = a;
}

// ---------------------------------------------------------------------------
__global__ __launch_bounds__(256) void downsample2(
    const float* __restrict__ in, float* __restrict__ out, int total, int Hi, int Wi) {
  int idx = blockIdx.x * 256 + threadIdx.x;
  if (idx >= total) return;
  int Wo = Wi / 2, Ho = Hi / 2;
  int x = idx % Wo; int t = idx / Wo;
  int y = t % Ho; t /= Ho;                       // t = b*C + c
  out[idx] = in[((size_t)t * Hi + 2 * y) * Wi + 2 * x];
}

// ---------------------------------------------------------------------------
__global__ __launch_bounds__(256) void priors_kernel(float* __restrict__ pr) {
  int pi = blockIdx.x * 256 + threadIdx.x;
  if (pi >= NPTOT) return;
  const int sizes[5] = {67, 33, 16, 8, 4};
  int idx = pi, H = 4;
#pragma unroll
  for (int L = 0; L < 5; ++L) {
    int cnt = sizes[L] * sizes[L] * 3;
    if (idx < cnt) { H = sizes[L]; break; }
    idx -= cnt;
  }
  int a = idx % 3; int cell = idx / 3;
  int x = cell % H; int y = cell / H;
  const float ars[3] = {1.0f, 0.5f, 2.0f};
  float cx = (x + 0.5f) / (float)H;
  float cy = (y + 0.5f) / (float)H;
  float pw = 3.0f * ars[a] / (float)H;
  float ph = 3.0f / ars[a] / (float)H;
  pr[pi * 4 + 0] = cx; pr[pi * 4 + 1] = cy; pr[pi * 4 + 2] = pw; pr[pi * 4 + 3] = ph;
}

// ---------------------------------------------------------------------------
extern "C" void kernel_launch(void* const* d_in, const int* in_sizes, int n_in,
                              void* d_out, int out_size, void* d_ws, size_t ws_size,
                              hipStream_t stream) {
  const float* c3 = (const float*)d_in[0];
  const float* c4 = (const float*)d_in[1];
  const float* c5 = (const float*)d_in[2];
  const float* lat_w5 = (const float*)d_in[3];  const float* lat_b5 = (const float*)d_in[4];
  const float* lat_w4 = (const float*)d_in[5];  const float* lat_b4 = (const float*)d_in[6];
  const float* lat_w3 = (const float*)d_in[7];  const float* lat_b3 = (const float*)d_in[8];
  const float* pred_w0 = (const float*)d_in[9];  const float* pred_b0 = (const float*)d_in[10];
  const float* pred_w1 = (const float*)d_in[11]; const float* pred_b1 = (const float*)d_in[12];
  const float* pred_w2 = (const float*)d_in[13]; const float* pred_b2 = (const float*)d_in[14];
  const float* up_w = (const float*)d_in[15];  const float* up_b = (const float*)d_in[16];
  const float* bbox_w = (const float*)d_in[17]; const float* bbox_b = (const float*)d_in[18];
  const float* conf_w = (const float*)d_in[19]; const float* conf_b = (const float*)d_in[20];
  const float* mask_w = (const float*)d_in[21]; const float* mask_b = (const float*)d_in[22];

  float* out = (float*)d_out;
  float* priors = out + (size_t)8 * NPTOT * FEAT;   // 16,606,512

  // workspace layout (floats) — sizes CORRECTED this round:
  //   8*256*4489 = 9,193,472 (was wrongly 9,191,936 -> p6 overlapped p3 tail)
  float* ws = (float*)d_ws;
  float* x5 = ws;                    // 8*256*324  =   663552  -> end   663552
  float* x4 = ws + 663552;           // 8*256*1225 =  2508800  -> end  3172352
  float* x3 = ws + 3172352;          // 8*256*4761 =  9750528  -> end 12922880
  float* p5 = ws + 12922880;         // 8*256*256  =   524288  -> end 13447168
  float* p4 = ws + 13447168;         // 8*256*1089 =  2230272  -> end 15677440
  float* p3 = ws + 15677440;         // 8*256*4489 =  9193472  -> end 24870912
  float* p6 = ws + 24870912;         // 8*256*64   =   131072  -> end 25001984
  float* p7 = ws + 25001984;         // 8*256*16   =    32768  -> end 25034752
  const size_t NEED_ALIAS = 25034752ull * 4ull;          // 100.14 MB
  const size_t NEED_FULL  = (25034752ull + 9193472ull) * 4ull;   // 136.9 MB
  float* u;
  if (ws_size >= NEED_FULL)       u = ws + 25034752;     // unaliased
  else if (ws_size >= NEED_ALIAS) u = x3;                // x3 dead after p3; 9,750,528 >= 9,193,472
  else {
    // ws too small to run: emit priors only -> absmax ~81 is the diagnostic
    priors_kernel<<<dim3((NPTOT + 255) / 256), dim3(256), 0, stream>>>(priors);
    return;
  }

  dim3 blk(256);

  // ---- FPN ----
  k_conv1x1<<<dim3(2, 256, 8), blk, 0, stream>>>(c5, lat_w5, lat_b5, x5, 2048, 324);
  k_conv3x3<<<dim3(1, 256, 8), blk, 0, stream>>>(x5, pred_w0, pred_b0, p5, 256, 18, 18, 16, 16, 0, 1);
  k_conv1x1<<<dim3(5, 256, 8), blk, 0, stream>>>(c4, lat_w4, lat_b4, x4, 1024, 1225);
  k_resize_add<<<dim3(5, 256, 8), blk, 0, stream>>>(x5, x4, 18, 18, 35, 35);
  k_conv3x3<<<dim3(5, 256, 8), blk, 0, stream>>>(x4, pred_w1, pred_b1, p4, 256, 35, 35, 33, 33, 0, 1);
  k_conv1x1<<<dim3(19, 256, 8), blk, 0, stream>>>(c3, lat_w3, lat_b3, x3, 512, 4761);
  k_resize_add<<<dim3(19, 256, 8), blk, 0, stream>>>(x4, x3, 35, 35, 69, 69);
  k_conv3x3<<<dim3(18, 256, 8), blk, 0, stream>>>(x3, pred_w2, pred_b2, p3, 256, 69, 69, 67, 67, 0, 1);
  downsample2<<<dim3((8 * 256 * 64 + 255) / 256), blk, 0, stream>>>(p5, p6, 8 * 256 * 64, 16, 16);
  downsample2<<<dim3((8 * 256 * 16 + 255) / 256), blk, 0, stream>>>(p6, p7, 8 * 256 * 16, 8, 8);

  // ---- heads over 5 levels ----
  struct Lv { const float* src; int H; int pbase; };
  Lv lv[5] = {{p3, 67, 0}, {p4, 33, 13467}, {p5, 16, 16734}, {p6, 8, 17502}, {p7, 4, 17694}};
  for (int L = 0; L < 5; ++L) {
    int H = lv[L].H; int HW = H * H;
    int gx = (HW + 255) / 256;
    k_conv3x3<<<dim3(gx, 256, 8), blk, 0, stream>>>(lv[L].src, up_w, up_b, u, 256, H, H, H, H, 1, 1);
    k_head<<<dim3(gx, 12, 8), blk, 0, stream>>>(u, bbox_w, bbox_b, out, H, H, lv[L].pbase, 4, 0, 0);
    k_head<<<dim3(gx, 243, 8), blk, 0, stream>>>(u, conf_w, conf_b, out, H, H, lv[L].pbase, 81, 4, 0);
    k_head<<<dim3(gx, 96, 8), blk, 0, stream>>>(u, mask_w, mask_b, out, H, H, lv[L].pbase, 32, 85, 1);
  }

  priors_kernel<<<dim3((NPTOT + 255) / 256), blk, 0, stream>>>(priors);
}

// Round 5
// 14998.914 us; speedup vs baseline: 2.4741x; 2.4741x over previous
//
#include <hip/hip_runtime.h>
#include <cstdint>

#define NPTOT 17742     // (67^2+33^2+16^2+8^2+4^2)*3
#define FEAT 117        // 4 bbox + 81 conf + 32 mask

// ---------------------------------------------------------------------------
// Tiled GEMM-style conv. BM=128 output pixels x BN=128 output channels per
// 256-thread block; K = Cin*ntap (tap outer, ci slabs of 8 in LDS).
// Each thread computes an 8x8 register tile.
// outMode 0: plain [b][co][HW] (+optional relu)
// outMode 1: head scatter into (B, NPTOT, 117) (+optional tanh)
__global__ __launch_bounds__(256, 2) void k_gemmconv(
    const float* __restrict__ in,   // [B, Cin, Hi*Wi]
    const float* __restrict__ w,    // [Cout, Cin, ntap]
    const float* __restrict__ wt,   // [ntap, Cin, Cout] (transposed) or ==w
    const float* __restrict__ bias, // [Cout]
    float* __restrict__ out,
    int Cin, int Hi, int Wi, int Ho, int Wo, int pad, int ntap,
    int Cout, int useWT, int relu,
    int outMode, int pbase, int featDim, int featOff, int doTanh)
{
  __shared__ float A_s[8][128];
  __shared__ float B_s[8][128];

  const int tid = threadIdx.x;
  const int b   = blockIdx.z;
  const int HW  = Ho * Wo;
  const int pm0 = blockIdx.x * 128;
  const int n0  = blockIdx.y * 128;

  const int tx = tid & 15;        // pixel octet selector
  const int ty = tid >> 4;        // channel octet selector
  const int sc = tid & 127;       // staging column
  const int sr = (tid >> 7) * 4;  // staging row base (0 or 4)

  // staged pixel for A (fixed per thread)
  const int sp  = pm0 + sc;
  const bool spv = sp < HW;
  const int syy = spv ? sp / Wo : 0;
  const int sxx = spv ? sp - syy * Wo : 0;

  float acc[8][8];
#pragma unroll
  for (int i = 0; i < 8; ++i)
#pragma unroll
    for (int j = 0; j < 8; ++j) acc[i][j] = 0.f;

  const int HiWi = Hi * Wi;
  const size_t inB = (size_t)b * Cin * HiWi;
  const int nstage = n0 + sc;     // staged output channel for B

  for (int tap = 0; tap < ntap; ++tap) {
    const int ky = tap / 3, kx = tap - ky * 3;   // ntap==1 -> (0,0)
    const int iy = syy + ky - pad, ix = sxx + kx - pad;
    const bool v = spv && (unsigned)iy < (unsigned)Hi && (unsigned)ix < (unsigned)Wi;
    const long voff = v ? ((long)iy * Wi + ix) : 0;
    const float* inp = in + inB + voff;

    for (int ci0 = 0; ci0 < Cin; ci0 += 8) {
      __syncthreads();
      // ---- stage A: A_s[r][pixel] ----
#pragma unroll
      for (int i = 0; i < 4; ++i) {
        int r = sr + i;
        A_s[r][sc] = v ? inp[(size_t)(ci0 + r) * HiWi] : 0.f;
      }
      // ---- stage B: B_s[r][channel] ----
      if (useWT) {
        const float* wp = wt + ((size_t)tap * Cin + ci0) * Cout + nstage;
#pragma unroll
        for (int i = 0; i < 4; ++i) {
          int r = sr + i;
          B_s[r][sc] = (nstage < Cout) ? wp[(size_t)r * Cout] : 0.f;
        }
      } else {
        const float* wp = w + ((size_t)nstage * Cin + ci0) * ntap + tap;
#pragma unroll
        for (int i = 0; i < 4; ++i) {
          int r = sr + i;
          B_s[r][sc] = (nstage < Cout) ? wp[(size_t)r * ntap] : 0.f;
        }
      }
      __syncthreads();
      // ---- compute: 8 ci x (8 pix x 8 ch) ----
#pragma unroll
      for (int r = 0; r < 8; ++r) {
        float4 a01 = *(const float4*)&A_s[r][tx * 8];
        float4 a23 = *(const float4*)&A_s[r][tx * 8 + 4];
        float4 b01 = *(const float4*)&B_s[r][ty * 8];
        float4 b23 = *(const float4*)&B_s[r][ty * 8 + 4];
        float av[8] = {a01.x, a01.y, a01.z, a01.w, a23.x, a23.y, a23.z, a23.w};
        float bv[8] = {b01.x, b01.y, b01.z, b01.w, b23.x, b23.y, b23.z, b23.w};
#pragma unroll
        for (int i = 0; i < 8; ++i)
#pragma unroll
          for (int j = 0; j < 8; ++j)
            acc[i][j] = fmaf(av[i], bv[j], acc[i][j]);
      }
    }
  }

  // ---- epilogue ----
  const int p0 = pm0 + tx * 8;
  if (outMode == 0) {
#pragma unroll
    for (int j = 0; j < 8; ++j) {
      int co = n0 + ty * 8 + j;
      if (co < Cout) {
        float bb = bias[co];
        size_t ob = ((size_t)b * Cout + co) * HW;
#pragma unroll
        for (int i = 0; i < 8; ++i) {
          int p = p0 + i;
          if (p < HW) {
            float vv = acc[i][j] + bb;
            if (relu) vv = fmaxf(vv, 0.f);
            out[ob + p] = vv;
          }
        }
      }
    }
  } else {
#pragma unroll
    for (int j = 0; j < 8; ++j) {
      int co = n0 + ty * 8 + j;
      if (co < Cout) {
        float bb = bias[co];
        int aIdx = co / featDim, k = co - aIdx * featDim;
#pragma unroll
        for (int i = 0; i < 8; ++i) {
          int p = p0 + i;
          if (p < HW) {
            float vv = acc[i][j] + bb;
            if (doTanh) vv = tanhf(vv);
            out[((size_t)b * NPTOT + pbase + (size_t)p * 3 + aIdx) * FEAT + featOff + k] = vv;
          }
        }
      }
    }
  }
}

// ---------------------------------------------------------------------------
// one-time weight transpose: wt[tap][ci][co] = w[co][ci][tap]
__global__ __launch_bounds__(256) void k_wtrans(
    const float* __restrict__ w, float* __restrict__ wt, int Cout, int Cin, int ntap) {
  int co = blockIdx.x * 256 + threadIdx.x;
  int ci = blockIdx.y;
  int tap = blockIdx.z;
  if (co >= Cout) return;
  wt[((size_t)tap * Cin + ci) * Cout + co] = w[((size_t)co * Cin + ci) * ntap + tap];
}

// ---------------------------------------------------------------------------
// jax-exact bilinear resize, accumulated: out += resize(in).  C = 256.
__global__ __launch_bounds__(256) void k_resize_add(
    const float* __restrict__ in, float* __restrict__ out,
    int Hi, int Wi, int Ho, int Wo) {
  int p = blockIdx.x * 256 + threadIdx.x;
  int c = blockIdx.y, b = blockIdx.z;
  int HW = Ho * Wo;
  if (p >= HW) return;
  int y = p / Wo, x = p - y * Wo;
  float sy = (y + 0.5f) * (float)Hi / (float)Ho - 0.5f;
  float sx = (x + 0.5f) * (float)Wi / (float)Wo - 0.5f;
  int iy0 = (int)floorf(sy), ix0 = (int)floorf(sx);
  float wy1 = sy - (float)iy0, wy0 = 1.f - wy1;
  float wx1 = sx - (float)ix0, wx0 = 1.f - wx1;
  if (iy0 < 0 || iy0 >= Hi) wy0 = 0.f;
  if (iy0 + 1 < 0 || iy0 + 1 >= Hi) wy1 = 0.f;
  if (ix0 < 0 || ix0 >= Wi) wx0 = 0.f;
  if (ix0 + 1 < 0 || ix0 + 1 >= Wi) wx1 = 0.f;
  float ty_ = wy0 + wy1, tx_ = wx0 + wx1;
  wy0 /= ty_; wy1 /= ty_; wx0 /= tx_; wx1 /= tx_;
  int y0 = min(max(iy0, 0), Hi - 1), y1 = min(max(iy0 + 1, 0), Hi - 1);
  int x0 = min(max(ix0, 0), Wi - 1), x1 = min(max(ix0 + 1, 0), Wi - 1);
  const float* ib = in + ((size_t)b * 256 + c) * Hi * Wi;
  float v = wy0 * (wx0 * ib[y0 * Wi + x0] + wx1 * ib[y0 * Wi + x1]) +
            wy1 * (wx0 * ib[y1 * Wi + x0] + wx1 * ib[y1 * Wi + x1]);
  out[((size_t)b * 256 + c) * HW + p] += v;
}

// ---------------------------------------------------------------------------
__global__ __launch_bounds__(256) void downsample2(
    const float* __restrict__ in, float* __restrict__ out, int total, int Hi, int Wi) {
  int idx = blockIdx.x * 256 + threadIdx.x;
  if (idx >= total) return;
  int Wo = Wi / 2, Ho = Hi / 2;
  int x = idx % Wo; int t = idx / Wo;
  int y = t % Ho; t /= Ho;
  out[idx] = in[((size_t)t * Hi + 2 * y) * Wi + 2 * x];
}

// ---------------------------------------------------------------------------
__global__ __launch_bounds__(256) void priors_kernel(float* __restrict__ pr) {
  int pi = blockIdx.x * 256 + threadIdx.x;
  if (pi >= NPTOT) return;
  const int sizes[5] = {67, 33, 16, 8, 4};
  int idx = pi, H = 4;
#pragma unroll
  for (int L = 0; L < 5; ++L) {
    int cnt = sizes[L] * sizes[L] * 3;
    if (idx < cnt) { H = sizes[L]; break; }
    idx -= cnt;
  }
  int a = idx % 3; int cell = idx / 3;
  int x = cell % H; int y = cell / H;
  const float ars[3] = {1.0f, 0.5f, 2.0f};
  pr[pi * 4 + 0] = (x + 0.5f) / (float)H;
  pr[pi * 4 + 1] = (y + 0.5f) / (float)H;
  pr[pi * 4 + 2] = 3.0f * ars[a] / (float)H;
  pr[pi * 4 + 3] = 3.0f / ars[a] / (float)H;
}

// ---------------------------------------------------------------------------
extern "C" void kernel_launch(void* const* d_in, const int* in_sizes, int n_in,
                              void* d_out, int out_size, void* d_ws, size_t ws_size,
                              hipStream_t stream) {
  const float* c3 = (const float*)d_in[0];
  const float* c4 = (const float*)d_in[1];
  const float* c5 = (const float*)d_in[2];
  const float* lat_w5 = (const float*)d_in[3];  const float* lat_b5 = (const float*)d_in[4];
  const float* lat_w4 = (const float*)d_in[5];  const float* lat_b4 = (const float*)d_in[6];
  const float* lat_w3 = (const float*)d_in[7];  const float* lat_b3 = (const float*)d_in[8];
  const float* pred_w0 = (const float*)d_in[9];  const float* pred_b0 = (const float*)d_in[10];
  const float* pred_w1 = (const float*)d_in[11]; const float* pred_b1 = (const float*)d_in[12];
  const float* pred_w2 = (const float*)d_in[13]; const float* pred_b2 = (const float*)d_in[14];
  const float* up_w = (const float*)d_in[15];  const float* up_b = (const float*)d_in[16];
  const float* bbox_w = (const float*)d_in[17]; const float* bbox_b = (const float*)d_in[18];
  const float* conf_w = (const float*)d_in[19]; const float* conf_b = (const float*)d_in[20];
  const float* mask_w = (const float*)d_in[21]; const float* mask_b = (const float*)d_in[22];

  float* out = (float*)d_out;
  float* priors = out + (size_t)8 * NPTOT * FEAT;

  // workspace layout (floats)
  float* ws = (float*)d_ws;
  float* x5 = ws;                    // 663552
  float* x4 = ws + 663552;           // -> 3172352
  float* x3 = ws + 3172352;          // -> 12922880
  float* p5 = ws + 12922880;         // -> 13447168
  float* p4 = ws + 13447168;         // -> 15677440
  float* p3 = ws + 15677440;         // -> 24870912  (8*256*4489 = 9,193,472)
  float* p6 = ws + 24870912;         // -> 25001984
  float* p7 = ws + 25001984;         // -> 25034752
  const size_t BASE = 25034752ull;   // floats
  const size_t USZ  = 9193472ull;    // u (8*256*4489)
  const size_t WTSZ = 4085504ull;    // all transposed weights

  float* u = nullptr; float* wtBase = nullptr;
  if (ws_size >= (BASE + USZ + WTSZ) * 4) { u = ws + BASE; wtBase = ws + BASE + USZ; }
  else if (ws_size >= (BASE + WTSZ) * 4)  { u = x3; wtBase = ws + BASE; }
  else if (ws_size >= BASE * 4)           { u = x3; }
  else {
    priors_kernel<<<dim3((NPTOT + 255) / 256), dim3(256), 0, stream>>>(priors);
    return;
  }

  // transposed-weight pointers
  float *wt_lat5 = nullptr, *wt_lat4 = nullptr, *wt_lat3 = nullptr,
        *wt_pred0 = nullptr, *wt_pred1 = nullptr, *wt_pred2 = nullptr,
        *wt_up = nullptr, *wt_conf = nullptr, *wt_mask = nullptr, *wt_bbox = nullptr;
  if (wtBase) {
    float* q = wtBase;
    wt_lat5 = q;  q += 2048 * 256;
    wt_lat4 = q;  q += 1024 * 256;
    wt_lat3 = q;  q += 512 * 256;
    wt_pred0 = q; q += 9 * 256 * 256;
    wt_pred1 = q; q += 9 * 256 * 256;
    wt_pred2 = q; q += 9 * 256 * 256;
    wt_up = q;    q += 9 * 256 * 256;
    wt_conf = q;  q += 9 * 256 * 243;
    wt_mask = q;  q += 9 * 256 * 96;
    wt_bbox = q;  q += 9 * 256 * 12;
    auto tr = [&](const float* w_, float* wt_, int Cout, int Cin, int ntap) {
      k_wtrans<<<dim3((Cout + 255) / 256, Cin, ntap), dim3(256), 0, stream>>>(w_, wt_, Cout, Cin, ntap);
    };
    tr(lat_w5, wt_lat5, 256, 2048, 1);
    tr(lat_w4, wt_lat4, 256, 1024, 1);
    tr(lat_w3, wt_lat3, 256, 512, 1);
    tr(pred_w0, wt_pred0, 256, 256, 9);
    tr(pred_w1, wt_pred1, 256, 256, 9);
    tr(pred_w2, wt_pred2, 256, 256, 9);
    tr(up_w, wt_up, 256, 256, 9);
    tr(conf_w, wt_conf, 243, 256, 9);
    tr(mask_w, wt_mask, 96, 256, 9);
    tr(bbox_w, wt_bbox, 12, 256, 9);
  }

  auto conv = [&](const float* in_, const float* w_, const float* wt_, const float* b_,
                  float* out_, int Cin, int Hi, int Wi, int Ho, int Wo, int pad, int ntap,
                  int Cout, int relu, int outMode, int pbase, int fd, int fo, int th) {
    int HW = Ho * Wo;
    dim3 g((HW + 127) / 128, (Cout + 127) / 128, 8);
    k_gemmconv<<<g, dim3(256), 0, stream>>>(in_, w_, wt_ ? wt_ : w_, b_, out_,
        Cin, Hi, Wi, Ho, Wo, pad, ntap, Cout, wt_ ? 1 : 0, relu,
        outMode, pbase, fd, fo, th);
  };

  dim3 blk(256);

  // ---- FPN ----
  conv(c5, lat_w5, wt_lat5, lat_b5, x5, 2048, 18, 18, 18, 18, 0, 1, 256, 0, 0, 0, 1, 0, 0);
  conv(x5, pred_w0, wt_pred0, pred_b0, p5, 256, 18, 18, 16, 16, 0, 9, 256, 1, 0, 0, 1, 0, 0);
  conv(c4, lat_w4, wt_lat4, lat_b4, x4, 1024, 35, 35, 35, 35, 0, 1, 256, 0, 0, 0, 1, 0, 0);
  k_resize_add<<<dim3(5, 256, 8), blk, 0, stream>>>(x5, x4, 18, 18, 35, 35);
  conv(x4, pred_w1, wt_pred1, pred_b1, p4, 256, 35, 35, 33, 33, 0, 9, 256, 1, 0, 0, 1, 0, 0);
  conv(c3, lat_w3, wt_lat3, lat_b3, x3, 512, 69, 69, 69, 69, 0, 1, 256, 0, 0, 0, 1, 0, 0);
  k_resize_add<<<dim3(19, 256, 8), blk, 0, stream>>>(x4, x3, 35, 35, 69, 69);
  conv(x3, pred_w2, wt_pred2, pred_b2, p3, 256, 69, 69, 67, 67, 0, 9, 256, 1, 0, 0, 1, 0, 0);
  downsample2<<<dim3((8 * 256 * 64 + 255) / 256), blk, 0, stream>>>(p5, p6, 8 * 256 * 64, 16, 16);
  downsample2<<<dim3((8 * 256 * 16 + 255) / 256), blk, 0, stream>>>(p6, p7, 8 * 256 * 16, 8, 8);

  // ---- heads over 5 levels ----
  struct Lv { const float* src; int H; int pbase; };
  Lv lv[5] = {{p3, 67, 0}, {p4, 33, 13467}, {p5, 16, 16734}, {p6, 8, 17502}, {p7, 4, 17694}};
  for (int L = 0; L < 5; ++L) {
    int H = lv[L].H;
    conv(lv[L].src, up_w, wt_up, up_b, u, 256, H, H, H, H, 1, 9, 256, 1, 0, 0, 1, 0, 0);
    conv(u, bbox_w, wt_bbox, bbox_b, out, 256, H, H, H, H, 1, 9, 12, 0, 1, lv[L].pbase, 4, 0, 0);
    conv(u, conf_w, wt_conf, conf_b, out, 256, H, H, H, H, 1, 9, 243, 0, 1, lv[L].pbase, 81, 4, 0);
    conv(u, mask_w, wt_mask, mask_b, out, 256, H, H, H, H, 1, 9, 96, 0, 1, lv[L].pbase, 32, 85, 1);
  }

  priors_kernel<<<dim3((NPTOT + 255) / 256), blk, 0, stream>>>(priors);
}

// Round 6
// 2146.729 us; speedup vs baseline: 17.2865x; 6.9869x over previous
//
#include <hip/hip_runtime.h>
#include <cstdint>

#define NPTOT 17742     // (67^2+33^2+16^2+8^2+4^2)*3
#define FEAT 117        // 4 bbox + 81 conf + 32 mask

typedef __bf16 bf16x8 __attribute__((ext_vector_type(8)));
typedef unsigned short u16x8 __attribute__((ext_vector_type(8)));
typedef float f32x4 __attribute__((ext_vector_type(4)));

__device__ __forceinline__ unsigned short f2bf(float f) {   // RNE fp32->bf16
  unsigned int u = __float_as_uint(f);
  u += 0x7fffu + ((u >> 16) & 1u);
  return (unsigned short)(u >> 16);
}

// ---------------------------------------------------------------------------
// MFMA implicit-GEMM conv.  Block tile: 64 pixels (M) x 128 out-channels (N).
// 4 waves in 2x2: wave computes 32px x 64ch = 2x4 fragments of 16x16.
// K = Cin per tap (taps outer). A staged fp32->bf16 on the fly; B from
// pre-converted bf16 weights w2[tap][co][ci].
// outMode 0: out[b][co][HW] (+relu) ; outMode 1: scatter (B,NPTOT,117) (+tanh)
__global__ __launch_bounds__(256) void k_mfmaconv(
    const float* __restrict__ in, const unsigned short* __restrict__ w2,
    const float* __restrict__ bias, float* __restrict__ out,
    int Cin, int Hi, int Wi, int Ho, int Wo, int pad, int ntap, int Cout,
    int relu, int outMode, int pbase, int featDim, int featOff, int doTanh)
{
  __shared__ unsigned short A_s[64][40];    // 32 k + 8 pad (80B rows, bank-uniform)
  __shared__ unsigned short B_s[128][40];

  const int tid  = threadIdx.x;
  const int lane = tid & 63;
  const int wave = tid >> 6;
  const int wr = wave >> 1, wc = wave & 1;
  const int b   = blockIdx.z;
  const int HW  = Ho * Wo;
  const int pm0 = blockIdx.x * 64;
  const int n0  = blockIdx.y * 128;

  // A staging: thread owns pixel ap, k-chunk ak0 (8 ci values)
  const int ap  = tid & 63;
  const int ak0 = (tid >> 6) * 8;
  const int sp  = pm0 + ap;
  const bool spv = sp < HW;
  const int sy = spv ? sp / Wo : 0;
  const int sx = spv ? sp - sy * Wo : 0;

  // B staging: thread owns channel bch, k-chunk bk0 (16 ci values)
  const int bch = tid >> 1;
  const int bk0 = (tid & 1) * 16;
  const int bco = n0 + bch;

  const int HiWi = Hi * Wi;
  const float* inb = in + (size_t)b * Cin * HiWi;

  f32x4 acc[2][4];
#pragma unroll
  for (int m = 0; m < 2; ++m)
#pragma unroll
    for (int n = 0; n < 4; ++n) acc[m][n] = (f32x4)0.0f;

  const int frow = lane & 15;
  const int fk   = (lane >> 4) * 8;

  for (int tap = 0; tap < ntap; ++tap) {
    const int ky = tap / 3, kx = tap - ky * 3;
    const int iy = sy + ky - pad, ix = sx + kx - pad;
    const bool av = spv && ((unsigned)iy < (unsigned)Hi) && ((unsigned)ix < (unsigned)Wi);
    const float* ainp = inb + ((long)iy * Wi + ix);
    const unsigned short* wt = w2 + (size_t)tap * Cout * Cin;

    for (int ci0 = 0; ci0 < Cin; ci0 += 32) {
      __syncthreads();
      // ---- stage A (64px x 32k): 8 coalesced scalar loads + cvt + b128 write
      u16x8 apk;
#pragma unroll
      for (int i = 0; i < 8; ++i) {
        float v = av ? ainp[(size_t)(ci0 + ak0 + i) * HiWi] : 0.f;
        apk[i] = f2bf(v);
      }
      *(u16x8*)&A_s[ap][ak0] = apk;
      // ---- stage B (128ch x 32k): 2 x 16B bf16 loads + 2 b128 writes
      u16x8 b0 = (u16x8)0, b1 = (u16x8)0;
      if (bco < Cout) {
        const unsigned short* wp = wt + (size_t)bco * Cin + ci0 + bk0;
        b0 = *(const u16x8*)wp;
        b1 = *(const u16x8*)(wp + 8);
      }
      *(u16x8*)&B_s[bch][bk0]     = b0;
      *(u16x8*)&B_s[bch][bk0 + 8] = b1;
      __syncthreads();
      // ---- fragments + 8 MFMA
      bf16x8 afr[2], bfr[4];
#pragma unroll
      for (int m = 0; m < 2; ++m)
        afr[m] = *(const bf16x8*)&A_s[wr * 32 + m * 16 + frow][fk];
#pragma unroll
      for (int n = 0; n < 4; ++n)
        bfr[n] = *(const bf16x8*)&B_s[wc * 64 + n * 16 + frow][fk];
#pragma unroll
      for (int m = 0; m < 2; ++m)
#pragma unroll
        for (int n = 0; n < 4; ++n)
          acc[m][n] = __builtin_amdgcn_mfma_f32_16x16x32_bf16(afr[m], bfr[n], acc[m][n], 0, 0, 0);
    }
  }

  // ---- epilogue: D lane map col=lane&15 (channel), row=(lane>>4)*4+r (pixel)
  const int row0 = (lane >> 4) * 4;
  const int coll = lane & 15;
#pragma unroll
  for (int m = 0; m < 2; ++m) {
    const int prow = pm0 + wr * 32 + m * 16 + row0;
#pragma unroll
    for (int n = 0; n < 4; ++n) {
      const int co = n0 + wc * 64 + n * 16 + coll;
      if (co >= Cout) continue;
      const float bb = bias[co];
      if (outMode == 0) {
        const size_t ob = ((size_t)b * Cout + co) * HW;
        if (prow + 3 < HW) {
          float4 st;
          st.x = acc[m][n][0] + bb; st.y = acc[m][n][1] + bb;
          st.z = acc[m][n][2] + bb; st.w = acc[m][n][3] + bb;
          if (relu) {
            st.x = fmaxf(st.x, 0.f); st.y = fmaxf(st.y, 0.f);
            st.z = fmaxf(st.z, 0.f); st.w = fmaxf(st.w, 0.f);
          }
          *(float4*)&out[ob + prow] = st;
        } else {
#pragma unroll
          for (int r = 0; r < 4; ++r) {
            int p = prow + r;
            if (p < HW) {
              float vv = acc[m][n][r] + bb;
              if (relu) vv = fmaxf(vv, 0.f);
              out[ob + p] = vv;
            }
          }
        }
      } else {
        const int aIdx = co / featDim, k = co - aIdx * featDim;
#pragma unroll
        for (int r = 0; r < 4; ++r) {
          int p = prow + r;
          if (p < HW) {
            float vv = acc[m][n][r] + bb;
            if (doTanh) vv = tanhf(vv);
            out[((size_t)b * NPTOT + pbase + (size_t)p * 3 + aIdx) * FEAT + featOff + k] = vv;
          }
        }
      }
    }
  }
}

// ---------------------------------------------------------------------------
// weight convert+transpose: w2[tap][co][ci] (bf16) = w[co][ci][tap] (fp32)
__global__ __launch_bounds__(256) void k_wconv(
    const float* __restrict__ w, unsigned short* __restrict__ w2,
    int Cout, int Cin, int ntap) {
  int i = blockIdx.x * 256 + threadIdx.x;
  int total = Cout * Cin * ntap;
  if (i >= total) return;
  int co = i / (Cin * ntap);
  int rem = i - co * (Cin * ntap);
  int ci = rem / ntap;
  int tap = rem - ci * ntap;
  w2[((size_t)tap * Cout + co) * Cin + ci] = f2bf(w[i]);
}

// ---------------------------------------------------------------------------
// jax-exact bilinear resize, accumulated: out += resize(in).  C = 256.
__global__ __launch_bounds__(256) void k_resize_add(
    const float* __restrict__ in, float* __restrict__ out,
    int Hi, int Wi, int Ho, int Wo) {
  int p = blockIdx.x * 256 + threadIdx.x;
  int c = blockIdx.y, b = blockIdx.z;
  int HW = Ho * Wo;
  if (p >= HW) return;
  int y = p / Wo, x = p - y * Wo;
  float sy = (y + 0.5f) * (float)Hi / (float)Ho - 0.5f;
  float sx = (x + 0.5f) * (float)Wi / (float)Wo - 0.5f;
  int iy0 = (int)floorf(sy), ix0 = (int)floorf(sx);
  float wy1 = sy - (float)iy0, wy0 = 1.f - wy1;
  float wx1 = sx - (float)ix0, wx0 = 1.f - wx1;
  if (iy0 < 0 || iy0 >= Hi) wy0 = 0.f;
  if (iy0 + 1 < 0 || iy0 + 1 >= Hi) wy1 = 0.f;
  if (ix0 < 0 || ix0 >= Wi) wx0 = 0.f;
  if (ix0 + 1 < 0 || ix0 + 1 >= Wi) wx1 = 0.f;
  float ty_ = wy0 + wy1, tx_ = wx0 + wx1;
  wy0 /= ty_; wy1 /= ty_; wx0 /= tx_; wx1 /= tx_;
  int y0 = min(max(iy0, 0), Hi - 1), y1 = min(max(iy0 + 1, 0), Hi - 1);
  int x0 = min(max(ix0, 0), Wi - 1), x1 = min(max(ix0 + 1, 0), Wi - 1);
  const float* ib = in + ((size_t)b * 256 + c) * Hi * Wi;
  float v = wy0 * (wx0 * ib[y0 * Wi + x0] + wx1 * ib[y0 * Wi + x1]) +
            wy1 * (wx0 * ib[y1 * Wi + x0] + wx1 * ib[y1 * Wi + x1]);
  out[((size_t)b * 256 + c) * HW + p] += v;
}

// ---------------------------------------------------------------------------
__global__ __launch_bounds__(256) void downsample2(
    const float* __restrict__ in, float* __restrict__ out, int total, int Hi, int Wi) {
  int idx = blockIdx.x * 256 + threadIdx.x;
  if (idx >= total) return;
  int Wo = Wi / 2, Ho = Hi / 2;
  int x = idx % Wo; int t = idx / Wo;
  int y = t % Ho; t /= Ho;
  out[idx] = in[((size_t)t * Hi + 2 * y) * Wi + 2 * x];
}

// ---------------------------------------------------------------------------
__global__ __launch_bounds__(256) void priors_kernel(float* __restrict__ pr) {
  int pi = blockIdx.x * 256 + threadIdx.x;
  if (pi >= NPTOT) return;
  const int sizes[5] = {67, 33, 16, 8, 4};
  int idx = pi, H = 4;
#pragma unroll
  for (int L = 0; L < 5; ++L) {
    int cnt = sizes[L] * sizes[L] * 3;
    if (idx < cnt) { H = sizes[L]; break; }
    idx -= cnt;
  }
  int a = idx % 3; int cell = idx / 3;
  int x = cell % H; int y = cell / H;
  const float ars[3] = {1.0f, 0.5f, 2.0f};
  pr[pi * 4 + 0] = (x + 0.5f) / (float)H;
  pr[pi * 4 + 1] = (y + 0.5f) / (float)H;
  pr[pi * 4 + 2] = 3.0f * ars[a] / (float)H;
  pr[pi * 4 + 3] = 3.0f / ars[a] / (float)H;
}

// ---------------------------------------------------------------------------
extern "C" void kernel_launch(void* const* d_in, const int* in_sizes, int n_in,
                              void* d_out, int out_size, void* d_ws, size_t ws_size,
                              hipStream_t stream) {
  const float* c3 = (const float*)d_in[0];
  const float* c4 = (const float*)d_in[1];
  const float* c5 = (const float*)d_in[2];
  const float* lat_w5 = (const float*)d_in[3];  const float* lat_b5 = (const float*)d_in[4];
  const float* lat_w4 = (const float*)d_in[5];  const float* lat_b4 = (const float*)d_in[6];
  const float* lat_w3 = (const float*)d_in[7];  const float* lat_b3 = (const float*)d_in[8];
  const float* pred_w0 = (const float*)d_in[9];  const float* pred_b0 = (const float*)d_in[10];
  const float* pred_w1 = (const float*)d_in[11]; const float* pred_b1 = (const float*)d_in[12];
  const float* pred_w2 = (const float*)d_in[13]; const float* pred_b2 = (const float*)d_in[14];
  const float* up_w = (const float*)d_in[15];  const float* up_b = (const float*)d_in[16];
  const float* bbox_w = (const float*)d_in[17]; const float* bbox_b = (const float*)d_in[18];
  const float* conf_w = (const float*)d_in[19]; const float* conf_b = (const float*)d_in[20];
  const float* mask_w = (const float*)d_in[21]; const float* mask_b = (const float*)d_in[22];

  float* out = (float*)d_out;
  float* priors = out + (size_t)8 * NPTOT * FEAT;

  // workspace layout (floats) — total stays at proven BASE = 100.14 MB.
  float* ws = (float*)d_ws;
  float* x5 = ws;                    //   663552
  float* x4 = ws + 663552;           // ->  3172352
  float* x3 = ws + 3172352;          // -> 12922880
  float* p5 = ws + 12922880;         // -> 13447168
  float* p4 = ws + 13447168;         // -> 15677440
  float* p3 = ws + 15677440;         // -> 24870912  (8*256*4489 = 9,193,472)
  float* p6 = ws + 24870912;         // -> 25001984
  float* p7 = ws + 25001984;         // -> 25034752
  const size_t BASE = 25034752ull;
  if (ws_size < BASE * 4) {          // diagnostic: priors only
    priors_kernel<<<dim3((NPTOT + 255) / 256), dim3(256), 0, stream>>>(priors);
    return;
  }
  float* u = x3;                     // x3 dead once p3 is computed

  // bf16 weight regions, TIME-SHARED with dead fp32 buffers:
  //  w2a (FPN part 1: lat5,pred0,lat4,pred1) lives in x3 region (x3 written later)
  //  w2b (lat3,pred2) lives in x5 region (x5 dead after resize x5->x4)
  //  w2h (up,conf,mask,bbox) lives in x5+x4 region (both dead post-FPN)
  unsigned short* w2a = (unsigned short*)(ws + 3172352);
  unsigned short* w2b = (unsigned short*)ws;
  unsigned short* w2h = (unsigned short*)ws;
  unsigned short* w2_lat5  = w2a;                // 524288 bf16
  unsigned short* w2_pred0 = w2a + 524288;       // 589824
  unsigned short* w2_lat4  = w2a + 1114112;      // 262144
  unsigned short* w2_pred1 = w2a + 1376256;      // 589824 (end 1,966,080)
  unsigned short* w2_lat3  = w2b;                // 131072
  unsigned short* w2_pred2 = w2b + 131072;       // 589824 (end 720,896 <= x5 1,327,104 bf16)
  unsigned short* w2_up    = w2h;                // 589824
  unsigned short* w2_conf  = w2h + 589824;       // 559872
  unsigned short* w2_mask  = w2h + 1149696;      // 221184
  unsigned short* w2_bbox  = w2h + 1370880;      // 27648 (end 1,398,528 <= x5+x4)

  auto wc = [&](const float* w_, unsigned short* w2_, int Cout, int Cin, int ntap) {
    int total = Cout * Cin * ntap;
    k_wconv<<<dim3((total + 255) / 256), dim3(256), 0, stream>>>(w_, w2_, Cout, Cin, ntap);
  };
  auto mf = [&](const float* in_, const unsigned short* w2_, const float* b_, float* out_,
                int Cin, int Hi, int Wi, int Ho, int Wo, int pad, int ntap, int Cout,
                int relu, int outMode, int pbase, int fd, int fo, int th) {
    dim3 g((Ho * Wo + 63) / 64, (Cout + 127) / 128, 8);
    k_mfmaconv<<<g, dim3(256), 0, stream>>>(in_, w2_, b_, out_, Cin, Hi, Wi, Ho, Wo,
                                            pad, ntap, Cout, relu, outMode, pbase, fd, fo, th);
  };

  dim3 blk(256);

  // ---- FPN part 1 (weights in x3 region) ----
  wc(lat_w5, w2_lat5, 256, 2048, 1);
  wc(pred_w0, w2_pred0, 256, 256, 9);
  wc(lat_w4, w2_lat4, 256, 1024, 1);
  wc(pred_w1, w2_pred1, 256, 256, 9);
  mf(c5, w2_lat5, lat_b5, x5, 2048, 18, 18, 18, 18, 0, 1, 256, 0, 0, 0, 1, 0, 0);
  mf(x5, w2_pred0, pred_b0, p5, 256, 18, 18, 16, 16, 0, 9, 256, 1, 0, 0, 1, 0, 0);
  mf(c4, w2_lat4, lat_b4, x4, 1024, 35, 35, 35, 35, 0, 1, 256, 0, 0, 0, 1, 0, 0);
  k_resize_add<<<dim3(5, 256, 8), blk, 0, stream>>>(x5, x4, 18, 18, 35, 35);   // x5 dead
  mf(x4, w2_pred1, pred_b1, p4, 256, 35, 35, 33, 33, 0, 9, 256, 1, 0, 0, 1, 0, 0);

  // ---- FPN part 2 (weights in dead x5 region; conv lat3 overwrites dead w2a) ----
  wc(lat_w3, w2_lat3, 256, 512, 1);
  wc(pred_w2, w2_pred2, 256, 256, 9);
  mf(c3, w2_lat3, lat_b3, x3, 512, 69, 69, 69, 69, 0, 1, 256, 0, 0, 0, 1, 0, 0);
  k_resize_add<<<dim3(19, 256, 8), blk, 0, stream>>>(x4, x3, 35, 35, 69, 69);  // x4 dead
  mf(x3, w2_pred2, pred_b2, p3, 256, 69, 69, 67, 67, 0, 9, 256, 1, 0, 0, 1, 0, 0);
  downsample2<<<dim3((8 * 256 * 64 + 255) / 256), blk, 0, stream>>>(p5, p6, 8 * 256 * 64, 16, 16);
  downsample2<<<dim3((8 * 256 * 16 + 255) / 256), blk, 0, stream>>>(p6, p7, 8 * 256 * 16, 8, 8);

  // ---- heads (weights in dead x5+x4 region; u aliases dead x3) ----
  wc(up_w, w2_up, 256, 256, 9);
  wc(conf_w, w2_conf, 243, 256, 9);
  wc(mask_w, w2_mask, 96, 256, 9);
  wc(bbox_w, w2_bbox, 12, 256, 9);
  struct Lv { const float* src; int H; int pbase; };
  Lv lv[5] = {{p3, 67, 0}, {p4, 33, 13467}, {p5, 16, 16734}, {p6, 8, 17502}, {p7, 4, 17694}};
  for (int L = 0; L < 5; ++L) {
    int H = lv[L].H;
    mf(lv[L].src, w2_up, up_b, u, 256, H, H, H, H, 1, 9, 256, 1, 0, 0, 1, 0, 0);
    mf(u, w2_bbox, bbox_b, out, 256, H, H, H, H, 1, 9, 12, 0, 1, lv[L].pbase, 4, 0, 0);
    mf(u, w2_conf, conf_b, out, 256, H, H, H, H, 1, 9, 243, 0, 1, lv[L].pbase, 81, 4, 0);
    mf(u, w2_mask, mask_b, out, 256, H, H, H, H, 1, 9, 96, 0, 1, lv[L].pbase, 32, 85, 1);
  }

  priors_kernel<<<dim3((NPTOT + 255) / 256), blk, 0, stream>>>(priors);
}

// Round 7
// 1448.445 us; speedup vs baseline: 25.6201x; 1.4821x over previous
//
#include <hip/hip_runtime.h>
#include <cstdint>

#define NPTOT 17742     // (67^2+33^2+16^2+8^2+4^2)*3
#define FEAT 117        // 4 bbox + 81 conf + 32 mask

typedef __bf16 bf16x8 __attribute__((ext_vector_type(8)));
typedef unsigned short u16x8 __attribute__((ext_vector_type(8)));
typedef float f32x4 __attribute__((ext_vector_type(4)));

__device__ __forceinline__ unsigned short f2bf(float f) {   // RNE fp32->bf16
  unsigned int u = __float_as_uint(f);
  u += 0x7fffu + ((u >> 16) & 1u);
  return (unsigned short)(u >> 16);
}
__device__ __forceinline__ float bf2f(unsigned short s) {
  return __uint_as_float(((unsigned int)s) << 16);
}

// ---------------------------------------------------------------------------
// MFMA implicit-GEMM conv, bf16 NHWC activations.
// Block: 128 px (M) x 128 out-ch (N), BK=64, 512 threads = 8 waves (2x4).
// Wave tile 64px x 32ch = 4x2 fragments; 16 MFMA per K-step per wave.
// Swapped operands: mfma(B,A) -> D[row=channel][col=pixel].
// outMode 0: bf16 NHWC out[b][p][ch] (stride Cout==256), +relu
// outMode 1: fp32 scatter (B,NPTOT,117), +tanh for mask
__global__ __launch_bounds__(512) void k_conv(
    const unsigned short* __restrict__ in,  // bf16 NHWC [B][Hi*Wi][Cin]
    const unsigned short* __restrict__ w2,  // bf16 [tap][co][ci]
    const float* __restrict__ bias, void* __restrict__ outp,
    int Cin, int Hi, int Wi, int Ho, int Wo, int pad, int ntap, int Cout,
    int relu, int outMode, int pbase, int featDim, int featOff, int doTanh)
{
  __shared__ unsigned short A_s[128][72];   // 64 k + 8 pad (144B rows)
  __shared__ unsigned short B_s[128][72];

  const int tid  = threadIdx.x;
  const int lane = tid & 63;
  const int wave = tid >> 6;
  const int wm = wave >> 2, wn = wave & 3;
  const int b   = blockIdx.z;
  const int HW  = Ho * Wo;
  const int pm0 = blockIdx.x * 128;
  const int n0  = blockIdx.y * 128;

  // A staging: thread -> (pixel, 16-ch chunk)
  const int apx = tid >> 2;
  const int ach = (tid & 3) * 16;
  const int sp  = pm0 + apx;
  const bool spv = sp < HW;
  const int sy = spv ? sp / Wo : 0;
  const int sx = spv ? sp - sy * Wo : 0;
  // B staging: thread -> (co, 16-ci chunk)
  const int bco = tid >> 2;
  const int bci = (tid & 3) * 16;
  const bool bcv = (n0 + bco) < Cout;

  f32x4 acc[4][2];
#pragma unroll
  for (int m = 0; m < 4; ++m)
#pragma unroll
    for (int n = 0; n < 2; ++n) acc[m][n] = (f32x4)0.0f;

  const long long inB = (long long)b * Hi * Wi;

  for (int tap = 0; tap < ntap; ++tap) {
    const int ky = tap / 3, kx = tap - ky * 3;   // ntap==1 -> (0,0)
    const int iy = sy + ky - pad, ix = sx + kx - pad;
    const bool av = spv && ((unsigned)iy < (unsigned)Hi) && ((unsigned)ix < (unsigned)Wi);
    const unsigned short* ap_ = in + (inB + (long long)iy * Wi + ix) * Cin + ach;
    const unsigned short* bp_ = w2 + ((size_t)tap * Cout + (n0 + bco)) * Cin + bci;

    for (int ci0 = 0; ci0 < Cin; ci0 += 64) {
      __syncthreads();
      u16x8 a0 = (u16x8)0, a1 = (u16x8)0, b0 = (u16x8)0, b1 = (u16x8)0;
      if (av)  { a0 = *(const u16x8*)(ap_ + ci0); a1 = *(const u16x8*)(ap_ + ci0 + 8); }
      if (bcv) { b0 = *(const u16x8*)(bp_ + ci0); b1 = *(const u16x8*)(bp_ + ci0 + 8); }
      *(u16x8*)&A_s[apx][ach]     = a0;
      *(u16x8*)&A_s[apx][ach + 8] = a1;
      *(u16x8*)&B_s[bco][bci]     = b0;
      *(u16x8*)&B_s[bco][bci + 8] = b1;
      __syncthreads();

      const int fl = lane & 15;
      const int fk = (lane >> 4) * 8;
#pragma unroll
      for (int kk = 0; kk < 2; ++kk) {
        bf16x8 bfr[2], afr[4];
#pragma unroll
        for (int n = 0; n < 2; ++n)
          bfr[n] = *(const bf16x8*)&B_s[wn * 32 + n * 16 + fl][kk * 32 + fk];
#pragma unroll
        for (int m = 0; m < 4; ++m)
          afr[m] = *(const bf16x8*)&A_s[wm * 64 + m * 16 + fl][kk * 32 + fk];
#pragma unroll
        for (int m = 0; m < 4; ++m)
#pragma unroll
          for (int n = 0; n < 2; ++n)
            acc[m][n] = __builtin_amdgcn_mfma_f32_16x16x32_bf16(bfr[n], afr[m], acc[m][n], 0, 0, 0);
      }
    }
  }

  // epilogue: D row = channel = base + (lane>>4)*4 + r, col = pixel = base + (lane&15)
  const int px_l = lane & 15;
  const int chq  = (lane >> 4) * 4;
  if (outMode == 0) {
    unsigned short* outb = (unsigned short*)outp;
#pragma unroll
    for (int m = 0; m < 4; ++m) {
      const int p = pm0 + wm * 64 + m * 16 + px_l;
      if (p >= HW) continue;
#pragma unroll
      for (int n = 0; n < 2; ++n) {
        const int ch = n0 + wn * 32 + n * 16 + chq;
        float4 bb = *(const float4*)&bias[ch];
        float v0 = acc[m][n][0] + bb.x, v1 = acc[m][n][1] + bb.y;
        float v2 = acc[m][n][2] + bb.z, v3 = acc[m][n][3] + bb.w;
        if (relu) {
          v0 = fmaxf(v0, 0.f); v1 = fmaxf(v1, 0.f);
          v2 = fmaxf(v2, 0.f); v3 = fmaxf(v3, 0.f);
        }
        ushort4 st = {f2bf(v0), f2bf(v1), f2bf(v2), f2bf(v3)};
        *(ushort4*)&outb[((size_t)b * HW + p) * 256 + ch] = st;
      }
    }
  } else {
    float* outf = (float*)outp;
#pragma unroll
    for (int m = 0; m < 4; ++m) {
      const int p = pm0 + wm * 64 + m * 16 + px_l;
      if (p >= HW) continue;
#pragma unroll
      for (int n = 0; n < 2; ++n) {
#pragma unroll
        for (int r = 0; r < 4; ++r) {
          const int co = n0 + wn * 32 + n * 16 + chq + r;
          if (co >= Cout) continue;
          float vv = acc[m][n][r] + bias[co];
          if (doTanh) vv = tanhf(vv);
          const int aIdx = co / featDim, k = co - aIdx * featDim;
          outf[((size_t)b * NPTOT + pbase + (size_t)p * 3 + aIdx) * FEAT + featOff + k] = vv;
        }
      }
    }
  }
}

// ---------------------------------------------------------------------------
// fp32 NCHW -> bf16 NHWC tiled transpose (64px x 64ch per block via LDS)
__global__ __launch_bounds__(256) void k_tobf16nhwc(
    const float* __restrict__ in, unsigned short* __restrict__ out, int C, int HW) {
  __shared__ float t[64][65];
  const int p0 = blockIdx.x * 64, c0 = blockIdx.y * 64, b = blockIdx.z;
  const int tid = threadIdx.x;
  const float* ib = in + ((size_t)b * C + c0) * HW;
#pragma unroll 4
  for (int r = 0; r < 16; ++r) {
    int ch = r * 4 + (tid >> 6);
    int px = tid & 63;
    t[ch][px] = (p0 + px < HW) ? ib[(size_t)ch * HW + p0 + px] : 0.f;
  }
  __syncthreads();
#pragma unroll 4
  for (int r = 0; r < 16; ++r) {
    int px = r * 4 + (tid >> 6);
    int ch = tid & 63;
    if (p0 + px < HW)
      out[((size_t)b * HW + p0 + px) * C + c0 + ch] = f2bf(t[ch][px]);
  }
}

// ---------------------------------------------------------------------------
// weight convert+transpose: w2[tap][co][ci] (bf16) = w[co][ci][tap] (fp32)
__global__ __launch_bounds__(256) void k_wconv(
    const float* __restrict__ w, unsigned short* __restrict__ w2,
    int Cout, int Cin, int ntap) {
  int i = blockIdx.x * 256 + threadIdx.x;
  int total = Cout * Cin * ntap;
  if (i >= total) return;
  int co = i / (Cin * ntap);
  int rem = i - co * (Cin * ntap);
  int ci = rem / ntap;
  int tap = rem - ci * ntap;
  w2[((size_t)tap * Cout + co) * Cin + ci] = f2bf(w[i]);
}

// ---------------------------------------------------------------------------
// jax-exact bilinear resize add, bf16 NHWC, C=256. thread = 8ch of one out px.
__global__ __launch_bounds__(256) void k_resize_add_nhwc(
    const unsigned short* __restrict__ in, unsigned short* __restrict__ out,
    int Hi, int Wi, int Ho, int Wo) {
  int idx = blockIdx.x * 256 + threadIdx.x;
  int HW = Ho * Wo;
  if (idx >= HW * 32) return;
  int b = blockIdx.z;
  int c0 = (idx & 31) * 8;
  int p = idx >> 5;
  int y = p / Wo, x = p - y * Wo;
  float sy = (y + 0.5f) * (float)Hi / (float)Ho - 0.5f;
  float sx = (x + 0.5f) * (float)Wi / (float)Wo - 0.5f;
  int iy0 = (int)floorf(sy), ix0 = (int)floorf(sx);
  float wy1 = sy - (float)iy0, wy0 = 1.f - wy1;
  float wx1 = sx - (float)ix0, wx0 = 1.f - wx1;
  if (iy0 < 0 || iy0 >= Hi) wy0 = 0.f;
  if (iy0 + 1 < 0 || iy0 + 1 >= Hi) wy1 = 0.f;
  if (ix0 < 0 || ix0 >= Wi) wx0 = 0.f;
  if (ix0 + 1 < 0 || ix0 + 1 >= Wi) wx1 = 0.f;
  float ty_ = wy0 + wy1, tx_ = wx0 + wx1;
  wy0 /= ty_; wy1 /= ty_; wx0 /= tx_; wx1 /= tx_;
  int y0 = min(max(iy0, 0), Hi - 1), y1 = min(max(iy0 + 1, 0), Hi - 1);
  int x0 = min(max(ix0, 0), Wi - 1), x1 = min(max(ix0 + 1, 0), Wi - 1);
  const unsigned short* ib = in + (size_t)b * Hi * Wi * 256;
  u16x8 v00 = *(const u16x8*)&ib[((size_t)y0 * Wi + x0) * 256 + c0];
  u16x8 v01 = *(const u16x8*)&ib[((size_t)y0 * Wi + x1) * 256 + c0];
  u16x8 v10 = *(const u16x8*)&ib[((size_t)y1 * Wi + x0) * 256 + c0];
  u16x8 v11 = *(const u16x8*)&ib[((size_t)y1 * Wi + x1) * 256 + c0];
  unsigned short* ob = out + ((size_t)b * HW + p) * 256 + c0;
  u16x8 cur = *(u16x8*)ob, res;
#pragma unroll
  for (int i = 0; i < 8; ++i) {
    float bl = wy0 * (wx0 * bf2f(v00[i]) + wx1 * bf2f(v01[i])) +
               wy1 * (wx0 * bf2f(v10[i]) + wx1 * bf2f(v11[i]));
    res[i] = f2bf(bf2f(cur[i]) + bl);
  }
  *(u16x8*)ob = res;
}

// ---------------------------------------------------------------------------
__global__ __launch_bounds__(256) void k_down_nhwc(
    const unsigned short* __restrict__ in, unsigned short* __restrict__ out,
    int Hi, int Wi) {
  int Ho = Hi / 2, Wo = Wi / 2, HW = Ho * Wo;
  int idx = blockIdx.x * 256 + threadIdx.x;
  if (idx >= HW * 32) return;
  int b = blockIdx.z;
  int c0 = (idx & 31) * 8;
  int p = idx >> 5;
  int y = p / Wo, x = p - y * Wo;
  *(u16x8*)&out[((size_t)b * HW + p) * 256 + c0] =
      *(const u16x8*)&in[((size_t)b * Hi * Wi + (size_t)(2 * y) * Wi + 2 * x) * 256 + c0];
}

// ---------------------------------------------------------------------------
__global__ __launch_bounds__(256) void priors_kernel(float* __restrict__ pr) {
  int pi = blockIdx.x * 256 + threadIdx.x;
  if (pi >= NPTOT) return;
  const int sizes[5] = {67, 33, 16, 8, 4};
  int idx = pi, H = 4;
#pragma unroll
  for (int L = 0; L < 5; ++L) {
    int cnt = sizes[L] * sizes[L] * 3;
    if (idx < cnt) { H = sizes[L]; break; }
    idx -= cnt;
  }
  int a = idx % 3; int cell = idx / 3;
  int x = cell % H; int y = cell / H;
  const float ars[3] = {1.0f, 0.5f, 2.0f};
  pr[pi * 4 + 0] = (x + 0.5f) / (float)H;
  pr[pi * 4 + 1] = (y + 0.5f) / (float)H;
  pr[pi * 4 + 2] = 3.0f * ars[a] / (float)H;
  pr[pi * 4 + 3] = 3.0f / ars[a] / (float)H;
}

// ---------------------------------------------------------------------------
extern "C" void kernel_launch(void* const* d_in, const int* in_sizes, int n_in,
                              void* d_out, int out_size, void* d_ws, size_t ws_size,
                              hipStream_t stream) {
  const float* c3 = (const float*)d_in[0];
  const float* c4 = (const float*)d_in[1];
  const float* c5 = (const float*)d_in[2];
  const float* lat_w5 = (const float*)d_in[3];  const float* lat_b5 = (const float*)d_in[4];
  const float* lat_w4 = (const float*)d_in[5];  const float* lat_b4 = (const float*)d_in[6];
  const float* lat_w3 = (const float*)d_in[7];  const float* lat_b3 = (const float*)d_in[8];
  const float* pred_w0 = (const float*)d_in[9];  const float* pred_b0 = (const float*)d_in[10];
  const float* pred_w1 = (const float*)d_in[11]; const float* pred_b1 = (const float*)d_in[12];
  const float* pred_w2 = (const float*)d_in[13]; const float* pred_b2 = (const float*)d_in[14];
  const float* up_w = (const float*)d_in[15];  const float* up_b = (const float*)d_in[16];
  const float* bbox_w = (const float*)d_in[17]; const float* bbox_b = (const float*)d_in[18];
  const float* conf_w = (const float*)d_in[19]; const float* conf_b = (const float*)d_in[20];
  const float* mask_w = (const float*)d_in[21]; const float* mask_b = (const float*)d_in[22];

  float* out = (float*)d_out;
  float* priors = out + (size_t)8 * NPTOT * FEAT;

  // workspace layout (bf16 element offsets); peak 48,621,312 elem = 97.24 MB
  unsigned short* B0 = (unsigned short*)d_ws;
  unsigned short* w2_lat5  = B0 + 0;         // 524288
  unsigned short* w2_pred0 = B0 + 524288;    // 589824
  unsigned short* w2_lat4  = B0 + 1114112;   // 262144
  unsigned short* w2_pred1 = B0 + 1376256;   // 589824
  unsigned short* w2_lat3  = B0 + 1966080;   // 131072
  unsigned short* w2_pred2 = B0 + 2097152;   // 589824
  unsigned short* w2_up    = B0 + 2686976;   // 589824
  unsigned short* w2_conf  = B0 + 3276800;   // 559872
  unsigned short* w2_mask  = B0 + 3836672;   // 221184
  unsigned short* w2_bbox  = B0 + 4057856;   // 27648 -> 4085504
  unsigned short* x5 = B0 + 4085504;         // 663552   -> 4749056
  unsigned short* x4 = B0 + 4749056;         // 2508800  -> 7257856
  unsigned short* x3 = B0 + 7257856;         // 9750528  -> 17008384
  unsigned short* p5 = B0 + 17008384;        // 524288   -> 17532672
  unsigned short* p4 = B0 + 17532672;        // 2230272  -> 19762944
  unsigned short* p3 = B0 + 19762944;        // 9193472  -> 28956416
  unsigned short* p6 = B0 + 28956416;        // 131072   -> 29087488
  unsigned short* p7 = B0 + 29087488;        // 32768    -> 29120256
  unsigned short* R  = B0 + 29120256;        // 19501056 -> 48621312 (c5b/c4b/c3b)
  unsigned short* u  = x3;                   // x3 dead once p3 computed

  if (ws_size < 48621312ull * 2ull) {        // diagnostic: priors only
    priors_kernel<<<dim3((NPTOT + 255) / 256), dim3(256), 0, stream>>>(priors);
    return;
  }

  auto wc = [&](const float* w_, unsigned short* w2_, int Cout, int Cin, int ntap) {
    int total = Cout * Cin * ntap;
    k_wconv<<<dim3((total + 255) / 256), dim3(256), 0, stream>>>(w_, w2_, Cout, Cin, ntap);
  };
  auto tonhwc = [&](const float* in_, unsigned short* out_, int C, int HW) {
    k_tobf16nhwc<<<dim3((HW + 63) / 64, C / 64, 8), dim3(256), 0, stream>>>(in_, out_, C, HW);
  };
  auto conv = [&](const unsigned short* in_, const unsigned short* w2_, const float* b_,
                  void* out_, int Cin, int Hi, int Wi, int Ho, int Wo, int pad, int ntap,
                  int Cout, int relu, int outMode, int pbase, int fd, int fo, int th) {
    dim3 g((Ho * Wo + 127) / 128, (Cout + 127) / 128, 8);
    k_conv<<<g, dim3(512), 0, stream>>>(in_, w2_, b_, out_, Cin, Hi, Wi, Ho, Wo,
                                        pad, ntap, Cout, relu, outMode, pbase, fd, fo, th);
  };

  // ---- weights ----
  wc(lat_w5, w2_lat5, 256, 2048, 1);
  wc(pred_w0, w2_pred0, 256, 256, 9);
  wc(lat_w4, w2_lat4, 256, 1024, 1);
  wc(pred_w1, w2_pred1, 256, 256, 9);
  wc(lat_w3, w2_lat3, 256, 512, 1);
  wc(pred_w2, w2_pred2, 256, 256, 9);
  wc(up_w, w2_up, 256, 256, 9);
  wc(conf_w, w2_conf, 243, 256, 9);
  wc(mask_w, w2_mask, 96, 256, 9);
  wc(bbox_w, w2_bbox, 12, 256, 9);

  // ---- FPN ----
  tonhwc(c5, R, 2048, 324);
  conv(R, w2_lat5, lat_b5, x5, 2048, 18, 18, 18, 18, 0, 1, 256, 0, 0, 0, 1, 0, 0);
  conv(x5, w2_pred0, pred_b0, p5, 256, 18, 18, 16, 16, 0, 9, 256, 1, 0, 0, 1, 0, 0);
  tonhwc(c4, R, 1024, 1225);
  conv(R, w2_lat4, lat_b4, x4, 1024, 35, 35, 35, 35, 0, 1, 256, 0, 0, 0, 1, 0, 0);
  k_resize_add_nhwc<<<dim3((1225 * 32 + 255) / 256, 1, 8), dim3(256), 0, stream>>>(x5, x4, 18, 18, 35, 35);
  conv(x4, w2_pred1, pred_b1, p4, 256, 35, 35, 33, 33, 0, 9, 256, 1, 0, 0, 1, 0, 0);
  tonhwc(c3, R, 512, 4761);
  conv(R, w2_lat3, lat_b3, x3, 512, 69, 69, 69, 69, 0, 1, 256, 0, 0, 0, 1, 0, 0);
  k_resize_add_nhwc<<<dim3((4761 * 32 + 255) / 256, 1, 8), dim3(256), 0, stream>>>(x4, x3, 35, 35, 69, 69);
  conv(x3, w2_pred2, pred_b2, p3, 256, 69, 69, 67, 67, 0, 9, 256, 1, 0, 0, 1, 0, 0);
  k_down_nhwc<<<dim3((64 * 32 + 255) / 256, 1, 8), dim3(256), 0, stream>>>(p5, p6, 16, 16);
  k_down_nhwc<<<dim3((16 * 32 + 255) / 256, 1, 8), dim3(256), 0, stream>>>(p6, p7, 8, 8);

  // ---- heads over 5 levels ----
  struct Lv { const unsigned short* src; int H; int pbase; };
  Lv lv[5] = {{p3, 67, 0}, {p4, 33, 13467}, {p5, 16, 16734}, {p6, 8, 17502}, {p7, 4, 17694}};
  for (int L = 0; L < 5; ++L) {
    int H = lv[L].H;
    conv(lv[L].src, w2_up, up_b, u, 256, H, H, H, H, 1, 9, 256, 1, 0, 0, 1, 0, 0);
    conv(u, w2_bbox, bbox_b, out, 256, H, H, H, H, 1, 9, 12, 0, 1, lv[L].pbase, 4, 0, 0);
    conv(u, w2_conf, conf_b, out, 256, H, H, H, H, 1, 9, 243, 0, 1, lv[L].pbase, 81, 4, 0);
    conv(u, w2_mask, mask_b, out, 256, H, H, H, H, 1, 9, 96, 0, 1, lv[L].pbase, 32, 85, 1);
  }

  priors_kernel<<<dim3((NPTOT + 255) / 256), dim3(256), 0, stream>>>(priors);
}

// Round 8
// 1122.054 us; speedup vs baseline: 33.0727x; 1.2909x over previous
//
#include <hip/hip_runtime.h>
#include <cstdint>

#define NPTOT 17742     // (67^2+33^2+16^2+8^2+4^2)*3
#define FEAT 117        // 4 bbox + 81 conf + 32 mask
#define HCOUT 351       // fused head channels: 12 bbox + 243 conf + 96 mask

typedef __bf16 bf16x8 __attribute__((ext_vector_type(8)));
typedef unsigned short u16x8 __attribute__((ext_vector_type(8)));
typedef float f32x4 __attribute__((ext_vector_type(4)));

__device__ __forceinline__ unsigned short f2bf(float f) {   // RNE fp32->bf16
  unsigned int u = __float_as_uint(f);
  u += 0x7fffu + ((u >> 16) & 1u);
  return (unsigned short)(u >> 16);
}
__device__ __forceinline__ float bf2f(unsigned short s) {
  return __uint_as_float(((unsigned int)s) << 16);
}
// LDS index (in shorts) with XOR swizzle: row*64 + (slot^(row&7))*8
__device__ __forceinline__ int swz(int row, int slot) {
  return row * 64 + ((slot ^ (row & 7)) << 3);
}

// ---------------------------------------------------------------------------
// MFMA implicit-GEMM conv, bf16 NHWC. Block 128px x 128ch, 256 thr = 4 waves
// (2m x 2n), wave tile 64x64 = 4x4 fragments -> 16 MFMA per 8 ds_read_b128.
// BK=64, taps outer. XOR-swizzled LDS (no padding, 32KB total).
// outMode 0: bf16 NHWC out[b][p][256] + relu
// outMode 1: fused head scatter fp32 (B,NPTOT,117); decode co->(bbox|conf|mask)
__global__ __launch_bounds__(256, 2) void k_conv(
    const unsigned short* __restrict__ in,  // bf16 NHWC [B][Hi*Wi][Cin]
    const unsigned short* __restrict__ w2,  // bf16 [tap][co][ci]
    const float* __restrict__ bias, void* __restrict__ outp,
    int Cin, int Hi, int Wi, int Ho, int Wo, int pad, int ntap, int Cout,
    int relu, int outMode, int pbase)
{
  __shared__ unsigned short A_s[128 * 64];
  __shared__ unsigned short B_s[128 * 64];

  const int tid  = threadIdx.x;
  const int lane = tid & 63;
  const int wave = tid >> 6;
  const int wm = wave >> 1, wn = wave & 1;
  const int b   = blockIdx.z;
  const int HW  = Ho * Wo;
  const int pm0 = blockIdx.x * 128;
  const int n0  = blockIdx.y * 128;

  // A staging: thread -> (pixel row, 4 slots of 8ch)
  const int arow = tid >> 1;
  const int as0  = (tid & 1) * 4;
  const int sp   = pm0 + arow;
  const bool spv = sp < HW;
  const int sy = spv ? sp / Wo : 0;
  const int sx = spv ? sp - sy * Wo : 0;
  // B staging: thread -> (co row, 4 slots)
  const int brow = tid >> 1;
  const int bs0  = (tid & 1) * 4;
  const bool bcv = (n0 + brow) < Cout;

  f32x4 acc[4][4];
#pragma unroll
  for (int m = 0; m < 4; ++m)
#pragma unroll
    for (int n = 0; n < 4; ++n) acc[m][n] = (f32x4)0.0f;

  const long long inB = (long long)b * Hi * Wi;
  const int fl = lane & 15, fq = lane >> 4;

  for (int tap = 0; tap < ntap; ++tap) {
    const int ky = tap / 3, kx = tap - ky * 3;   // ntap==1 -> (0,0)
    const int iy = sy + ky - pad, ix = sx + kx - pad;
    const bool av = spv && ((unsigned)iy < (unsigned)Hi) && ((unsigned)ix < (unsigned)Wi);
    const unsigned short* ap_ = in + (inB + (long long)iy * Wi + ix) * Cin;
    const unsigned short* bp_ = w2 + ((size_t)tap * Cout + (n0 + brow)) * Cin;

    for (int ci0 = 0; ci0 < Cin; ci0 += 64) {
      __syncthreads();
      u16x8 avv[4], bvv[4];
#pragma unroll
      for (int i = 0; i < 4; ++i) {
        avv[i] = av  ? *(const u16x8*)(ap_ + ci0 + (as0 + i) * 8) : (u16x8)0;
        bvv[i] = bcv ? *(const u16x8*)(bp_ + ci0 + (bs0 + i) * 8) : (u16x8)0;
      }
#pragma unroll
      for (int i = 0; i < 4; ++i) {
        *(u16x8*)&A_s[swz(arow, as0 + i)] = avv[i];
        *(u16x8*)&B_s[swz(brow, bs0 + i)] = bvv[i];
      }
      __syncthreads();
#pragma unroll
      for (int kk = 0; kk < 2; ++kk) {
        bf16x8 afr[4], bfr[4];
#pragma unroll
        for (int m = 0; m < 4; ++m)
          afr[m] = *(const bf16x8*)&A_s[swz(wm * 64 + m * 16 + fl, kk * 4 + fq)];
#pragma unroll
        for (int n = 0; n < 4; ++n)
          bfr[n] = *(const bf16x8*)&B_s[swz(wn * 64 + n * 16 + fl, kk * 4 + fq)];
#pragma unroll
        for (int m = 0; m < 4; ++m)
#pragma unroll
          for (int n = 0; n < 4; ++n)
            acc[m][n] = __builtin_amdgcn_mfma_f32_16x16x32_bf16(bfr[n], afr[m], acc[m][n], 0, 0, 0);
      }
    }
  }

  // epilogue: D col = pixel = lane&15, row = channel = (lane>>4)*4 + r
  const int px_l = lane & 15;
  const int chq  = (lane >> 4) * 4;
  if (outMode == 0) {
    unsigned short* outb = (unsigned short*)outp;
#pragma unroll
    for (int m = 0; m < 4; ++m) {
      const int p = pm0 + wm * 64 + m * 16 + px_l;
      if (p >= HW) continue;
#pragma unroll
      for (int n = 0; n < 4; ++n) {
        const int ch = n0 + wn * 64 + n * 16 + chq;
        float4 bb = *(const float4*)&bias[ch];
        float v0 = acc[m][n][0] + bb.x, v1 = acc[m][n][1] + bb.y;
        float v2 = acc[m][n][2] + bb.z, v3 = acc[m][n][3] + bb.w;
        if (relu) {
          v0 = fmaxf(v0, 0.f); v1 = fmaxf(v1, 0.f);
          v2 = fmaxf(v2, 0.f); v3 = fmaxf(v3, 0.f);
        }
        ushort4 st = {f2bf(v0), f2bf(v1), f2bf(v2), f2bf(v3)};
        *(ushort4*)&outb[((size_t)b * HW + p) * 256 + ch] = st;
      }
    }
  } else {
    float* outf = (float*)outp;
#pragma unroll
    for (int m = 0; m < 4; ++m) {
      const int p = pm0 + wm * 64 + m * 16 + px_l;
      if (p >= HW) continue;
      const size_t pb_ = ((size_t)b * NPTOT + pbase + (size_t)p * 3);
#pragma unroll
      for (int n = 0; n < 4; ++n) {
#pragma unroll
        for (int r = 0; r < 4; ++r) {
          const int co = n0 + wn * 64 + n * 16 + chq + r;
          if (co >= HCOUT) continue;
          float vv = acc[m][n][r] + bias[co];
          int aIdx, k, off;
          if (co < 12)       { aIdx = co >> 2; k = co & 3; off = 0; }
          else if (co < 255) { int c = co - 12; aIdx = (c >= 162) ? 2 : (c >= 81 ? 1 : 0);
                               k = c - aIdx * 81; off = 4; }
          else               { int c = co - 255; aIdx = c >> 5; k = c & 31; off = 85;
                               vv = tanhf(vv); }
          outf[(pb_ + aIdx) * FEAT + off + k] = vv;
        }
      }
    }
  }
}

// ---------------------------------------------------------------------------
// fp32 NCHW -> bf16 NHWC tiled transpose (64px x 64ch per block via LDS)
__global__ __launch_bounds__(256) void k_tobf16nhwc(
    const float* __restrict__ in, unsigned short* __restrict__ out, int C, int HW) {
  __shared__ float t[64][65];
  const int p0 = blockIdx.x * 64, c0 = blockIdx.y * 64, b = blockIdx.z;
  const int tid = threadIdx.x;
  const float* ib = in + ((size_t)b * C + c0) * HW;
#pragma unroll 4
  for (int r = 0; r < 16; ++r) {
    int ch = r * 4 + (tid >> 6);
    int px = tid & 63;
    t[ch][px] = (p0 + px < HW) ? ib[(size_t)ch * HW + p0 + px] : 0.f;
  }
  __syncthreads();
#pragma unroll 4
  for (int r = 0; r < 16; ++r) {
    int px = r * 4 + (tid >> 6);
    int ch = tid & 63;
    if (p0 + px < HW)
      out[((size_t)b * HW + p0 + px) * C + c0 + ch] = f2bf(t[ch][px]);
  }
}

// ---------------------------------------------------------------------------
// weight convert+transpose: w2[tap][rowOff+co][ci] = w[co][ci][tap] (fp32->bf16)
__global__ __launch_bounds__(256) void k_wconv(
    const float* __restrict__ w, unsigned short* __restrict__ w2,
    int Cout, int Cin, int ntap, int rowStride, int rowOff) {
  int i = blockIdx.x * 256 + threadIdx.x;
  int total = Cout * Cin * ntap;
  if (i >= total) return;
  int co = i / (Cin * ntap);
  int rem = i - co * (Cin * ntap);
  int ci = rem / ntap;
  int tap = rem - ci * ntap;
  w2[((size_t)tap * rowStride + rowOff + co) * Cin + ci] = f2bf(w[i]);
}

// ---------------------------------------------------------------------------
__global__ __launch_bounds__(384) void k_bias_head(
    const float* __restrict__ bbox_b, const float* __restrict__ conf_b,
    const float* __restrict__ mask_b, float* __restrict__ bh) {
  int co = threadIdx.x;
  float v = 0.f;
  if (co < 12) v = bbox_b[co];
  else if (co < 255) v = conf_b[co - 12];
  else if (co < HCOUT) v = mask_b[co - 255];
  bh[co] = v;
}

// ---------------------------------------------------------------------------
// jax-exact bilinear resize add, bf16 NHWC, C=256. thread = 8ch of one out px.
__global__ __launch_bounds__(256) void k_resize_add_nhwc(
    const unsigned short* __restrict__ in, unsigned short* __restrict__ out,
    int Hi, int Wi, int Ho, int Wo) {
  int idx = blockIdx.x * 256 + threadIdx.x;
  int HW = Ho * Wo;
  if (idx >= HW * 32) return;
  int b = blockIdx.z;
  int c0 = (idx & 31) * 8;
  int p = idx >> 5;
  int y = p / Wo, x = p - y * Wo;
  float sy = (y + 0.5f) * (float)Hi / (float)Ho - 0.5f;
  float sx = (x + 0.5f) * (float)Wi / (float)Wo - 0.5f;
  int iy0 = (int)floorf(sy), ix0 = (int)floorf(sx);
  float wy1 = sy - (float)iy0, wy0 = 1.f - wy1;
  float wx1 = sx - (float)ix0, wx0 = 1.f - wx1;
  if (iy0 < 0 || iy0 >= Hi) wy0 = 0.f;
  if (iy0 + 1 < 0 || iy0 + 1 >= Hi) wy1 = 0.f;
  if (ix0 < 0 || ix0 >= Wi) wx0 = 0.f;
  if (ix0 + 1 < 0 || ix0 + 1 >= Wi) wx1 = 0.f;
  float ty_ = wy0 + wy1, tx_ = wx0 + wx1;
  wy0 /= ty_; wy1 /= ty_; wx0 /= tx_; wx1 /= tx_;
  int y0 = min(max(iy0, 0), Hi - 1), y1 = min(max(iy0 + 1, 0), Hi - 1);
  int x0 = min(max(ix0, 0), Wi - 1), x1 = min(max(ix0 + 1, 0), Wi - 1);
  const unsigned short* ib = in + (size_t)b * Hi * Wi * 256;
  u16x8 v00 = *(const u16x8*)&ib[((size_t)y0 * Wi + x0) * 256 + c0];
  u16x8 v01 = *(const u16x8*)&ib[((size_t)y0 * Wi + x1) * 256 + c0];
  u16x8 v10 = *(const u16x8*)&ib[((size_t)y1 * Wi + x0) * 256 + c0];
  u16x8 v11 = *(const u16x8*)&ib[((size_t)y1 * Wi + x1) * 256 + c0];
  unsigned short* ob = out + ((size_t)b * HW + p) * 256 + c0;
  u16x8 cur = *(u16x8*)ob, res;
#pragma unroll
  for (int i = 0; i < 8; ++i) {
    float bl = wy0 * (wx0 * bf2f(v00[i]) + wx1 * bf2f(v01[i])) +
               wy1 * (wx0 * bf2f(v10[i]) + wx1 * bf2f(v11[i]));
    res[i] = f2bf(bf2f(cur[i]) + bl);
  }
  *(u16x8*)ob = res;
}

// ---------------------------------------------------------------------------
__global__ __launch_bounds__(256) void k_down_nhwc(
    const unsigned short* __restrict__ in, unsigned short* __restrict__ out,
    int Hi, int Wi) {
  int Ho = Hi / 2, Wo = Wi / 2, HW = Ho * Wo;
  int idx = blockIdx.x * 256 + threadIdx.x;
  if (idx >= HW * 32) return;
  int b = blockIdx.z;
  int c0 = (idx & 31) * 8;
  int p = idx >> 5;
  int y = p / Wo, x = p - y * Wo;
  *(u16x8*)&out[((size_t)b * HW + p) * 256 + c0] =
      *(const u16x8*)&in[((size_t)b * Hi * Wi + (size_t)(2 * y) * Wi + 2 * x) * 256 + c0];
}

// ---------------------------------------------------------------------------
__global__ __launch_bounds__(256) void priors_kernel(float* __restrict__ pr) {
  int pi = blockIdx.x * 256 + threadIdx.x;
  if (pi >= NPTOT) return;
  const int sizes[5] = {67, 33, 16, 8, 4};
  int idx = pi, H = 4;
#pragma unroll
  for (int L = 0; L < 5; ++L) {
    int cnt = sizes[L] * sizes[L] * 3;
    if (idx < cnt) { H = sizes[L]; break; }
    idx -= cnt;
  }
  int a = idx % 3; int cell = idx / 3;
  int x = cell % H; int y = cell / H;
  const float ars[3] = {1.0f, 0.5f, 2.0f};
  pr[pi * 4 + 0] = (x + 0.5f) / (float)H;
  pr[pi * 4 + 1] = (y + 0.5f) / (float)H;
  pr[pi * 4 + 2] = 3.0f * ars[a] / (float)H;
  pr[pi * 4 + 3] = 3.0f / ars[a] / (float)H;
}

// ---------------------------------------------------------------------------
extern "C" void kernel_launch(void* const* d_in, const int* in_sizes, int n_in,
                              void* d_out, int out_size, void* d_ws, size_t ws_size,
                              hipStream_t stream) {
  const float* c3 = (const float*)d_in[0];
  const float* c4 = (const float*)d_in[1];
  const float* c5 = (const float*)d_in[2];
  const float* lat_w5 = (const float*)d_in[3];  const float* lat_b5 = (const float*)d_in[4];
  const float* lat_w4 = (const float*)d_in[5];  const float* lat_b4 = (const float*)d_in[6];
  const float* lat_w3 = (const float*)d_in[7];  const float* lat_b3 = (const float*)d_in[8];
  const float* pred_w0 = (const float*)d_in[9];  const float* pred_b0 = (const float*)d_in[10];
  const float* pred_w1 = (const float*)d_in[11]; const float* pred_b1 = (const float*)d_in[12];
  const float* pred_w2 = (const float*)d_in[13]; const float* pred_b2 = (const float*)d_in[14];
  const float* up_w = (const float*)d_in[15];  const float* up_b = (const float*)d_in[16];
  const float* bbox_w = (const float*)d_in[17]; const float* bbox_b = (const float*)d_in[18];
  const float* conf_w = (const float*)d_in[19]; const float* conf_b = (const float*)d_in[20];
  const float* mask_w = (const float*)d_in[21]; const float* mask_b = (const float*)d_in[22];

  float* out = (float*)d_out;
  float* priors = out + (size_t)8 * NPTOT * FEAT;

  // workspace layout (bf16 element offsets); peak 48,622,080 elem = 97.25 MB
  unsigned short* B0 = (unsigned short*)d_ws;
  unsigned short* w2_lat5  = B0 + 0;         // 524288
  unsigned short* w2_pred0 = B0 + 524288;    // 589824
  unsigned short* w2_lat4  = B0 + 1114112;   // 262144
  unsigned short* w2_pred1 = B0 + 1376256;   // 589824
  unsigned short* w2_lat3  = B0 + 1966080;   // 131072
  unsigned short* w2_pred2 = B0 + 2097152;   // 589824
  unsigned short* w2_up    = B0 + 2686976;   // 589824
  unsigned short* w2_head  = B0 + 3276800;   // 9*351*256 = 808704 -> 4085504
  unsigned short* x5 = B0 + 4085504;         // 663552   -> 4749056
  unsigned short* x4 = B0 + 4749056;         // 2508800  -> 7257856
  unsigned short* x3 = B0 + 7257856;         // 9750528  -> 17008384
  unsigned short* p5 = B0 + 17008384;        // 524288   -> 17532672
  unsigned short* p4 = B0 + 17532672;        // 2230272  -> 19762944
  unsigned short* p3 = B0 + 19762944;        // 9193472  -> 28956416
  unsigned short* p6 = B0 + 28956416;        // 131072   -> 29087488
  unsigned short* p7 = B0 + 29087488;        // 32768    -> 29120256
  unsigned short* R  = B0 + 29120256;        // 19501056 -> 48621312 (c5b/c4b/c3b)
  float* bias_h = (float*)(B0 + 48621312);   // 384 f32 = 768 shorts -> 48622080
  unsigned short* u  = x3;                   // x3 dead once p3 computed

  if (ws_size < 48622080ull * 2ull) {        // diagnostic: priors only
    priors_kernel<<<dim3((NPTOT + 255) / 256), dim3(256), 0, stream>>>(priors);
    return;
  }

  auto wc = [&](const float* w_, unsigned short* w2_, int Cout, int Cin, int ntap,
                int rs, int ro) {
    int total = Cout * Cin * ntap;
    k_wconv<<<dim3((total + 255) / 256), dim3(256), 0, stream>>>(w_, w2_, Cout, Cin, ntap, rs, ro);
  };
  auto tonhwc = [&](const float* in_, unsigned short* out_, int C, int HW) {
    k_tobf16nhwc<<<dim3((HW + 63) / 64, C / 64, 8), dim3(256), 0, stream>>>(in_, out_, C, HW);
  };
  auto conv = [&](const unsigned short* in_, const unsigned short* w2_, const float* b_,
                  void* out_, int Cin, int Hi, int Wi, int Ho, int Wo, int pad, int ntap,
                  int Cout, int relu, int outMode, int pbase) {
    dim3 g((Ho * Wo + 127) / 128, (Cout + 127) / 128, 8);
    k_conv<<<g, dim3(256), 0, stream>>>(in_, w2_, b_, out_, Cin, Hi, Wi, Ho, Wo,
                                        pad, ntap, Cout, relu, outMode, pbase);
  };

  // ---- weights (bf16 repack) ----
  wc(lat_w5, w2_lat5, 256, 2048, 1, 256, 0);
  wc(pred_w0, w2_pred0, 256, 256, 9, 256, 0);
  wc(lat_w4, w2_lat4, 256, 1024, 1, 256, 0);
  wc(pred_w1, w2_pred1, 256, 256, 9, 256, 0);
  wc(lat_w3, w2_lat3, 256, 512, 1, 256, 0);
  wc(pred_w2, w2_pred2, 256, 256, 9, 256, 0);
  wc(up_w, w2_up, 256, 256, 9, 256, 0);
  wc(bbox_w, w2_head, 12, 256, 9, HCOUT, 0);
  wc(conf_w, w2_head, 243, 256, 9, HCOUT, 12);
  wc(mask_w, w2_head, 96, 256, 9, HCOUT, 255);
  k_bias_head<<<dim3(1), dim3(384), 0, stream>>>(bbox_b, conf_b, mask_b, bias_h);

  // ---- FPN ----
  tonhwc(c5, R, 2048, 324);
  conv(R, w2_lat5, lat_b5, x5, 2048, 18, 18, 18, 18, 0, 1, 256, 0, 0, 0);
  conv(x5, w2_pred0, pred_b0, p5, 256, 18, 18, 16, 16, 0, 9, 256, 1, 0, 0);
  tonhwc(c4, R, 1024, 1225);
  conv(R, w2_lat4, lat_b4, x4, 1024, 35, 35, 35, 35, 0, 1, 256, 0, 0, 0);
  k_resize_add_nhwc<<<dim3((1225 * 32 + 255) / 256, 1, 8), dim3(256), 0, stream>>>(x5, x4, 18, 18, 35, 35);
  conv(x4, w2_pred1, pred_b1, p4, 256, 35, 35, 33, 33, 0, 9, 256, 1, 0, 0);
  tonhwc(c3, R, 512, 4761);
  conv(R, w2_lat3, lat_b3, x3, 512, 69, 69, 69, 69, 0, 1, 256, 0, 0, 0);
  k_resize_add_nhwc<<<dim3((4761 * 32 + 255) / 256, 1, 8), dim3(256), 0, stream>>>(x4, x3, 35, 35, 69, 69);
  conv(x3, w2_pred2, pred_b2, p3, 256, 69, 69, 67, 67, 0, 9, 256, 1, 0, 0);
  k_down_nhwc<<<dim3((64 * 32 + 255) / 256, 1, 8), dim3(256), 0, stream>>>(p5, p6, 16, 16);
  k_down_nhwc<<<dim3((16 * 32 + 255) / 256, 1, 8), dim3(256), 0, stream>>>(p6, p7, 8, 8);

  // ---- heads over 5 levels: up-conv + ONE fused head conv ----
  struct Lv { const unsigned short* src; int H; int pbase; };
  Lv lv[5] = {{p3, 67, 0}, {p4, 33, 13467}, {p5, 16, 16734}, {p6, 8, 17502}, {p7, 4, 17694}};
  for (int L = 0; L < 5; ++L) {
    int H = lv[L].H;
    conv(lv[L].src, w2_up, up_b, u, 256, H, H, H, H, 1, 9, 256, 1, 0, 0);
    conv(u, w2_head, bias_h, out, 256, H, H, H, H, 1, 9, HCOUT, 0, 1, lv[L].pbase);
  }

  priors_kernel<<<dim3((NPTOT + 255) / 256), dim3(256), 0, stream>>>(priors);
}

// Round 9
// 1109.686 us; speedup vs baseline: 33.4413x; 1.0111x over previous
//
#include <hip/hip_runtime.h>
#include <cstdint>

#define NPTOT 17742     // (67^2+33^2+16^2+8^2+4^2)*3
#define FEAT 117        // 4 bbox + 81 conf + 32 mask
#define HCOUT 351       // fused head channels: 12 bbox + 243 conf + 96 mask

typedef __bf16 bf16x8 __attribute__((ext_vector_type(8)));
typedef unsigned short u16x8 __attribute__((ext_vector_type(8)));
typedef float f32x4 __attribute__((ext_vector_type(4)));

__device__ __forceinline__ unsigned short f2bf(float f) {   // RNE fp32->bf16
  unsigned int u = __float_as_uint(f);
  u += 0x7fffu + ((u >> 16) & 1u);
  return (unsigned short)(u >> 16);
}
__device__ __forceinline__ float bf2f(unsigned short s) {
  return __uint_as_float(((unsigned int)s) << 16);
}
// async global->LDS, 16B per lane; LDS dest = wave-uniform base + lane*16
__device__ __forceinline__ void gload16(const void* g, void* l) {
  __builtin_amdgcn_global_load_lds(
      (const __attribute__((address_space(1))) unsigned int*)g,
      (__attribute__((address_space(3))) unsigned int*)l, 16, 0, 0);
}

// ---------------------------------------------------------------------------
// MFMA implicit-GEMM conv, bf16 NHWC, m97-style pipeline:
// 128px x 128ch block, 4 waves (2x2), wave tile 64x64 = 4x4 frags, BK=32.
// global_load_lds (w=16) staging, double-buffered LDS, ONE barrier per K-step:
//   stage(k+1 -> buf^1); ds_read+16 MFMA on buf; __syncthreads; swap.
// Invalid lanes (OOB pixel/tap/Cout-tail) read a zeroed global buffer.
// outMode 0: bf16 NHWC out[b][p][256] + relu
// outMode 1: fused head scatter fp32 (B,NPTOT,117); decode co->(bbox|conf|mask)
__global__ __launch_bounds__(256, 4) void k_conv(
    const unsigned short* __restrict__ in,  // bf16 NHWC [B][Hi*Wi][Cin]
    const unsigned short* __restrict__ w2,  // bf16 [tap][co][ci]
    const float* __restrict__ bias, void* __restrict__ outp,
    const float* __restrict__ zerobuf,
    int Cin, int csl2, int Hi, int Wi, int Ho, int Wo, int pad, int ntap,
    int Cout, int relu, int outMode, int pbase)
{
  __shared__ __align__(16) unsigned short A_s[2][128 * 32];  // 8KB per buf
  __shared__ __align__(16) unsigned short B_s[2][128 * 32];

  const int tid  = threadIdx.x;
  const int lane = tid & 63;
  const int wave = tid >> 6;
  const int wm = wave >> 1, wn = wave & 1;
  const int b   = blockIdx.z;
  const int HW  = Ho * Wo;
  const int pm0 = blockIdx.x * 128;
  const int n0  = blockIdx.y * 128;

  // staging geometry: issue q = wave*2+i covers rows q*16..q*16+15;
  // lane l -> row q*16 + (l>>2), 8-ch chunk (l&3)
  const int q0 = wave * 2;
  const int lr = lane >> 2;
  const int lc = (lane & 3) * 8;

  int ay[2], ax[2], brn[2];
  bool apv[2], bv[2];
#pragma unroll
  for (int i = 0; i < 2; ++i) {
    const int row = (q0 + i) * 16 + lr;
    const int p = pm0 + row;
    apv[i] = p < HW;
    const int pp = apv[i] ? p : 0;
    ay[i] = pp / Wo; ax[i] = pp - ay[i] * Wo;
    brn[i] = n0 + row;
    bv[i] = brn[i] < Cout;
  }

  const long long inB = (long long)b * Hi * Wi;
  const int nk = ntap << csl2;
  const int cmask = (1 << csl2) - 1;

  f32x4 acc[4][4];
#pragma unroll
  for (int m = 0; m < 4; ++m)
#pragma unroll
    for (int n = 0; n < 4; ++n) acc[m][n] = (f32x4)0.0f;

  auto stage = [&](int k, int bufSel) {
    const int tap = k >> csl2, cs = k & cmask;
    const int ky = tap / 3, kx = tap - ky * 3;   // ntap==1 -> (0,0)
#pragma unroll
    for (int i = 0; i < 2; ++i) {
      const int iy = ay[i] + ky - pad, ix = ax[i] + kx - pad;
      const bool v = apv[i] && ((unsigned)iy < (unsigned)Hi) && ((unsigned)ix < (unsigned)Wi);
      const void* ga = v
          ? (const void*)(in + (inB + (long long)iy * Wi + ix) * Cin + (cs << 5) + lc)
          : (const void*)zerobuf;
      gload16(ga, (void*)&A_s[bufSel][(q0 + i) * 512]);
      const void* gb = bv[i]
          ? (const void*)(w2 + ((size_t)tap * Cout + brn[i]) * Cin + (cs << 5) + lc)
          : (const void*)zerobuf;
      gload16(gb, (void*)&B_s[bufSel][(q0 + i) * 512]);
    }
  };

  stage(0, 0);
  __syncthreads();                    // drains vmcnt(0): buf0 ready
  int cur = 0;
  const int fl = lane & 15, fq = lane >> 4;

  for (int k = 0; k < nk; ++k) {
    if (k + 1 < nk) stage(k + 1, cur ^ 1);   // in flight during MFMA below
    bf16x8 afr[4], bfr[4];
#pragma unroll
    for (int m = 0; m < 4; ++m)
      afr[m] = *(const bf16x8*)&A_s[cur][(wm * 64 + m * 16 + fl) * 32 + fq * 8];
#pragma unroll
    for (int n = 0; n < 4; ++n)
      bfr[n] = *(const bf16x8*)&B_s[cur][(wn * 64 + n * 16 + fl) * 32 + fq * 8];
#pragma unroll
    for (int m = 0; m < 4; ++m)
#pragma unroll
      for (int n = 0; n < 4; ++n)
        acc[m][n] = __builtin_amdgcn_mfma_f32_16x16x32_bf16(bfr[n], afr[m], acc[m][n], 0, 0, 0);
    __syncthreads();                  // drains prefetch vmcnt + lgkm, then barrier
    cur ^= 1;
  }

  // epilogue: D col = pixel = lane&15, row = channel = (lane>>4)*4 + r
  const int px_l = lane & 15;
  const int chq  = (lane >> 4) * 4;
  if (outMode == 0) {
    unsigned short* outb = (unsigned short*)outp;
#pragma unroll
    for (int m = 0; m < 4; ++m) {
      const int p = pm0 + wm * 64 + m * 16 + px_l;
      if (p >= HW) continue;
#pragma unroll
      for (int n = 0; n < 4; ++n) {
        const int ch = n0 + wn * 64 + n * 16 + chq;
        float4 bb = *(const float4*)&bias[ch];
        float v0 = acc[m][n][0] + bb.x, v1 = acc[m][n][1] + bb.y;
        float v2 = acc[m][n][2] + bb.z, v3 = acc[m][n][3] + bb.w;
        if (relu) {
          v0 = fmaxf(v0, 0.f); v1 = fmaxf(v1, 0.f);
          v2 = fmaxf(v2, 0.f); v3 = fmaxf(v3, 0.f);
        }
        ushort4 st = {f2bf(v0), f2bf(v1), f2bf(v2), f2bf(v3)};
        *(ushort4*)&outb[((size_t)b * HW + p) * 256 + ch] = st;
      }
    }
  } else {
    float* outf = (float*)outp;
#pragma unroll
    for (int m = 0; m < 4; ++m) {
      const int p = pm0 + wm * 64 + m * 16 + px_l;
      if (p >= HW) continue;
      const size_t pb_ = ((size_t)b * NPTOT + pbase + (size_t)p * 3);
#pragma unroll
      for (int n = 0; n < 4; ++n) {
#pragma unroll
        for (int r = 0; r < 4; ++r) {
          const int co = n0 + wn * 64 + n * 16 + chq + r;
          if (co >= HCOUT) continue;
          float vv = acc[m][n][r] + bias[co];
          int aIdx, k2, off;
          if (co < 12)       { aIdx = co >> 2; k2 = co & 3; off = 0; }
          else if (co < 255) { int c = co - 12; aIdx = (c >= 162) ? 2 : (c >= 81 ? 1 : 0);
                               k2 = c - aIdx * 81; off = 4; }
          else               { int c = co - 255; aIdx = c >> 5; k2 = c & 31; off = 85;
                               vv = tanhf(vv); }
          outf[(pb_ + aIdx) * FEAT + off + k2] = vv;
        }
      }
    }
  }
}

// ---------------------------------------------------------------------------
__global__ __launch_bounds__(256) void k_zero(float* __restrict__ zb) {
  zb[threadIdx.x] = 0.f;   // 1KB zero region for OOB gload_lds redirects
}

// ---------------------------------------------------------------------------
// fp32 NCHW -> bf16 NHWC tiled transpose (64px x 64ch per block via LDS)
__global__ __launch_bounds__(256) void k_tobf16nhwc(
    const float* __restrict__ in, unsigned short* __restrict__ out, int C, int HW) {
  __shared__ float t[64][65];
  const int p0 = blockIdx.x * 64, c0 = blockIdx.y * 64, b = blockIdx.z;
  const int tid = threadIdx.x;
  const float* ib = in + ((size_t)b * C + c0) * HW;
#pragma unroll 4
  for (int r = 0; r < 16; ++r) {
    int ch = r * 4 + (tid >> 6);
    int px = tid & 63;
    t[ch][px] = (p0 + px < HW) ? ib[(size_t)ch * HW + p0 + px] : 0.f;
  }
  __syncthreads();
#pragma unroll 4
  for (int r = 0; r < 16; ++r) {
    int px = r * 4 + (tid >> 6);
    int ch = tid & 63;
    if (p0 + px < HW)
      out[((size_t)b * HW + p0 + px) * C + c0 + ch] = f2bf(t[ch][px]);
  }
}

// ---------------------------------------------------------------------------
// weight convert+transpose: w2[tap][rowOff+co][ci] = w[co][ci][tap] (fp32->bf16)
__global__ __launch_bounds__(256) void k_wconv(
    const float* __restrict__ w, unsigned short* __restrict__ w2,
    int Cout, int Cin, int ntap, int rowStride, int rowOff) {
  int i = blockIdx.x * 256 + threadIdx.x;
  int total = Cout * Cin * ntap;
  if (i >= total) return;
  int co = i / (Cin * ntap);
  int rem = i - co * (Cin * ntap);
  int ci = rem / ntap;
  int tap = rem - ci * ntap;
  w2[((size_t)tap * rowStride + rowOff + co) * Cin + ci] = f2bf(w[i]);
}

// ---------------------------------------------------------------------------
__global__ __launch_bounds__(384) void k_bias_head(
    const float* __restrict__ bbox_b, const float* __restrict__ conf_b,
    const float* __restrict__ mask_b, float* __restrict__ bh) {
  int co = threadIdx.x;
  float v = 0.f;
  if (co < 12) v = bbox_b[co];
  else if (co < 255) v = conf_b[co - 12];
  else if (co < HCOUT) v = mask_b[co - 255];
  if (co < 384) bh[co] = v;
}

// ---------------------------------------------------------------------------
// jax-exact bilinear resize add, bf16 NHWC, C=256. thread = 8ch of one out px.
__global__ __launch_bounds__(256) void k_resize_add_nhwc(
    const unsigned short* __restrict__ in, unsigned short* __restrict__ out,
    int Hi, int Wi, int Ho, int Wo) {
  int idx = blockIdx.x * 256 + threadIdx.x;
  int HW = Ho * Wo;
  if (idx >= HW * 32) return;
  int b = blockIdx.z;
  int c0 = (idx & 31) * 8;
  int p = idx >> 5;
  int y = p / Wo, x = p - y * Wo;
  float sy = (y + 0.5f) * (float)Hi / (float)Ho - 0.5f;
  float sx = (x + 0.5f) * (float)Wi / (float)Wo - 0.5f;
  int iy0 = (int)floorf(sy), ix0 = (int)floorf(sx);
  float wy1 = sy - (float)iy0, wy0 = 1.f - wy1;
  float wx1 = sx - (float)ix0, wx0 = 1.f - wx1;
  if (iy0 < 0 || iy0 >= Hi) wy0 = 0.f;
  if (iy0 + 1 < 0 || iy0 + 1 >= Hi) wy1 = 0.f;
  if (ix0 < 0 || ix0 >= Wi) wx0 = 0.f;
  if (ix0 + 1 < 0 || ix0 + 1 >= Wi) wx1 = 0.f;
  float ty_ = wy0 + wy1, tx_ = wx0 + wx1;
  wy0 /= ty_; wy1 /= ty_; wx0 /= tx_; wx1 /= tx_;
  int y0 = min(max(iy0, 0), Hi - 1), y1 = min(max(iy0 + 1, 0), Hi - 1);
  int x0 = min(max(ix0, 0), Wi - 1), x1 = min(max(ix0 + 1, 0), Wi - 1);
  const unsigned short* ib = in + (size_t)b * Hi * Wi * 256;
  u16x8 v00 = *(const u16x8*)&ib[((size_t)y0 * Wi + x0) * 256 + c0];
  u16x8 v01 = *(const u16x8*)&ib[((size_t)y0 * Wi + x1) * 256 + c0];
  u16x8 v10 = *(const u16x8*)&ib[((size_t)y1 * Wi + x0) * 256 + c0];
  u16x8 v11 = *(const u16x8*)&ib[((size_t)y1 * Wi + x1) * 256 + c0];
  unsigned short* ob = out + ((size_t)b * HW + p) * 256 + c0;
  u16x8 cur = *(u16x8*)ob, res;
#pragma unroll
  for (int i = 0; i < 8; ++i) {
    float bl = wy0 * (wx0 * bf2f(v00[i]) + wx1 * bf2f(v01[i])) +
               wy1 * (wx0 * bf2f(v10[i]) + wx1 * bf2f(v11[i]));
    res[i] = f2bf(bf2f(cur[i]) + bl);
  }
  *(u16x8*)ob = res;
}

// ---------------------------------------------------------------------------
__global__ __launch_bounds__(256) void k_down_nhwc(
    const unsigned short* __restrict__ in, unsigned short* __restrict__ out,
    int Hi, int Wi) {
  int Ho = Hi / 2, Wo = Wi / 2, HW = Ho * Wo;
  int idx = blockIdx.x * 256 + threadIdx.x;
  if (idx >= HW * 32) return;
  int b = blockIdx.z;
  int c0 = (idx & 31) * 8;
  int p = idx >> 5;
  int y = p / Wo, x = p - y * Wo;
  *(u16x8*)&out[((size_t)b * HW + p) * 256 + c0] =
      *(const u16x8*)&in[((size_t)b * Hi * Wi + (size_t)(2 * y) * Wi + 2 * x) * 256 + c0];
}

// ---------------------------------------------------------------------------
__global__ __launch_bounds__(256) void priors_kernel(float* __restrict__ pr) {
  int pi = blockIdx.x * 256 + threadIdx.x;
  if (pi >= NPTOT) return;
  const int sizes[5] = {67, 33, 16, 8, 4};
  int idx = pi, H = 4;
#pragma unroll
  for (int L = 0; L < 5; ++L) {
    int cnt = sizes[L] * sizes[L] * 3;
    if (idx < cnt) { H = sizes[L]; break; }
    idx -= cnt;
  }
  int a = idx % 3; int cell = idx / 3;
  int x = cell % H; int y = cell / H;
  const float ars[3] = {1.0f, 0.5f, 2.0f};
  pr[pi * 4 + 0] = (x + 0.5f) / (float)H;
  pr[pi * 4 + 1] = (y + 0.5f) / (float)H;
  pr[pi * 4 + 2] = 3.0f * ars[a] / (float)H;
  pr[pi * 4 + 3] = 3.0f / ars[a] / (float)H;
}

// ---------------------------------------------------------------------------
extern "C" void kernel_launch(void* const* d_in, const int* in_sizes, int n_in,
                              void* d_out, int out_size, void* d_ws, size_t ws_size,
                              hipStream_t stream) {
  const float* c3 = (const float*)d_in[0];
  const float* c4 = (const float*)d_in[1];
  const float* c5 = (const float*)d_in[2];
  const float* lat_w5 = (const float*)d_in[3];  const float* lat_b5 = (const float*)d_in[4];
  const float* lat_w4 = (const float*)d_in[5];  const float* lat_b4 = (const float*)d_in[6];
  const float* lat_w3 = (const float*)d_in[7];  const float* lat_b3 = (const float*)d_in[8];
  const float* pred_w0 = (const float*)d_in[9];  const float* pred_b0 = (const float*)d_in[10];
  const float* pred_w1 = (const float*)d_in[11]; const float* pred_b1 = (const float*)d_in[12];
  const float* pred_w2 = (const float*)d_in[13]; const float* pred_b2 = (const float*)d_in[14];
  const float* up_w = (const float*)d_in[15];  const float* up_b = (const float*)d_in[16];
  const float* bbox_w = (const float*)d_in[17]; const float* bbox_b = (const float*)d_in[18];
  const float* conf_w = (const float*)d_in[19]; const float* conf_b = (const float*)d_in[20];
  const float* mask_w = (const float*)d_in[21]; const float* mask_b = (const float*)d_in[22];

  float* out = (float*)d_out;
  float* priors = out + (size_t)8 * NPTOT * FEAT;

  // workspace layout (bf16 element offsets); peak 48,622,592 elem = 97.25 MB
  unsigned short* B0 = (unsigned short*)d_ws;
  unsigned short* w2_lat5  = B0 + 0;         // 524288
  unsigned short* w2_pred0 = B0 + 524288;    // 589824
  unsigned short* w2_lat4  = B0 + 1114112;   // 262144
  unsigned short* w2_pred1 = B0 + 1376256;   // 589824
  unsigned short* w2_lat3  = B0 + 1966080;   // 131072
  unsigned short* w2_pred2 = B0 + 2097152;   // 589824
  unsigned short* w2_up    = B0 + 2686976;   // 589824
  unsigned short* w2_head  = B0 + 3276800;   // 9*351*256 = 808704 -> 4085504
  unsigned short* x5 = B0 + 4085504;         // 663552   -> 4749056
  unsigned short* x4 = B0 + 4749056;         // 2508800  -> 7257856
  unsigned short* x3 = B0 + 7257856;         // 9750528  -> 17008384
  unsigned short* p5 = B0 + 17008384;        // 524288   -> 17532672
  unsigned short* p4 = B0 + 17532672;        // 2230272  -> 19762944
  unsigned short* p3 = B0 + 19762944;        // 9193472  -> 28956416
  unsigned short* p6 = B0 + 28956416;        // 131072   -> 29087488
  unsigned short* p7 = B0 + 29087488;        // 32768    -> 29120256
  unsigned short* R  = B0 + 29120256;        // 19501056 -> 48621312 (c5b/c4b/c3b)
  float* bias_h = (float*)(B0 + 48621312);   // 384 f32  -> 48622080
  float* zb     = (float*)(B0 + 48622080);   // 256 f32 (1KB zeros) -> 48622592
  unsigned short* u  = x3;                   // x3 dead once p3 computed

  if (ws_size < 48622592ull * 2ull) {        // diagnostic: priors only
    priors_kernel<<<dim3((NPTOT + 255) / 256), dim3(256), 0, stream>>>(priors);
    return;
  }

  auto wc = [&](const float* w_, unsigned short* w2_, int Cout, int Cin, int ntap,
                int rs, int ro) {
    int total = Cout * Cin * ntap;
    k_wconv<<<dim3((total + 255) / 256), dim3(256), 0, stream>>>(w_, w2_, Cout, Cin, ntap, rs, ro);
  };
  auto tonhwc = [&](const float* in_, unsigned short* out_, int C, int HW) {
    k_tobf16nhwc<<<dim3((HW + 63) / 64, C / 64, 8), dim3(256), 0, stream>>>(in_, out_, C, HW);
  };
  auto conv = [&](const unsigned short* in_, const unsigned short* w2_, const float* b_,
                  void* out_, int Cin, int Hi, int Wi, int Ho, int Wo, int pad, int ntap,
                  int Cout, int relu, int outMode, int pbase) {
    int csl2 = __builtin_ctz(Cin >> 5);
    dim3 g((Ho * Wo + 127) / 128, (Cout + 127) / 128, 8);
    k_conv<<<g, dim3(256), 0, stream>>>(in_, w2_, b_, out_, zb, Cin, csl2, Hi, Wi, Ho, Wo,
                                        pad, ntap, Cout, relu, outMode, pbase);
  };

  // ---- zero region + weights (bf16 repack) ----
  k_zero<<<dim3(1), dim3(256), 0, stream>>>(zb);
  wc(lat_w5, w2_lat5, 256, 2048, 1, 256, 0);
  wc(pred_w0, w2_pred0, 256, 256, 9, 256, 0);
  wc(lat_w4, w2_lat4, 256, 1024, 1, 256, 0);
  wc(pred_w1, w2_pred1, 256, 256, 9, 256, 0);
  wc(lat_w3, w2_lat3, 256, 512, 1, 256, 0);
  wc(pred_w2, w2_pred2, 256, 256, 9, 256, 0);
  wc(up_w, w2_up, 256, 256, 9, 256, 0);
  wc(bbox_w, w2_head, 12, 256, 9, HCOUT, 0);
  wc(conf_w, w2_head, 243, 256, 9, HCOUT, 12);
  wc(mask_w, w2_head, 96, 256, 9, HCOUT, 255);
  k_bias_head<<<dim3(1), dim3(384), 0, stream>>>(bbox_b, conf_b, mask_b, bias_h);

  // ---- FPN ----
  tonhwc(c5, R, 2048, 324);
  conv(R, w2_lat5, lat_b5, x5, 2048, 18, 18, 18, 18, 0, 1, 256, 0, 0, 0);
  conv(x5, w2_pred0, pred_b0, p5, 256, 18, 18, 16, 16, 0, 9, 256, 1, 0, 0);
  tonhwc(c4, R, 1024, 1225);
  conv(R, w2_lat4, lat_b4, x4, 1024, 35, 35, 35, 35, 0, 1, 256, 0, 0, 0);
  k_resize_add_nhwc<<<dim3((1225 * 32 + 255) / 256, 1, 8), dim3(256), 0, stream>>>(x5, x4, 18, 18, 35, 35);
  conv(x4, w2_pred1, pred_b1, p4, 256, 35, 35, 33, 33, 0, 9, 256, 1, 0, 0);
  tonhwc(c3, R, 512, 4761);
  conv(R, w2_lat3, lat_b3, x3, 512, 69, 69, 69, 69, 0, 1, 256, 0, 0, 0);
  k_resize_add_nhwc<<<dim3((4761 * 32 + 255) / 256, 1, 8), dim3(256), 0, stream>>>(x4, x3, 35, 35, 69, 69);
  conv(x3, w2_pred2, pred_b2, p3, 256, 69, 69, 67, 67, 0, 9, 256, 1, 0, 0);
  k_down_nhwc<<<dim3((64 * 32 + 255) / 256, 1, 8), dim3(256), 0, stream>>>(p5, p6, 16, 16);
  k_down_nhwc<<<dim3((16 * 32 + 255) / 256, 1, 8), dim3(256), 0, stream>>>(p6, p7, 8, 8);

  // ---- heads over 5 levels: up-conv + ONE fused head conv ----
  struct Lv { const unsigned short* src; int H; int pbase; };
  Lv lv[5] = {{p3, 67, 0}, {p4, 33, 13467}, {p5, 16, 16734}, {p6, 8, 17502}, {p7, 4, 17694}};
  for (int L = 0; L < 5; ++L) {
    int H = lv[L].H;
    conv(lv[L].src, w2_up, up_b, u, 256, H, H, H, H, 1, 9, 256, 1, 0, 0);
    conv(u, w2_head, bias_h, out, 256, H, H, H, H, 1, 9, HCOUT, 0, 1, lv[L].pbase);
  }

  priors_kernel<<<dim3((NPTOT + 255) / 256), dim3(256), 0, stream>>>(priors);
}

// Round 10
// 757.645 us; speedup vs baseline: 48.9798x; 1.4647x over previous
//
#include <hip/hip_runtime.h>
#include <cstdint>

#define NPTOT 17742     // (67^2+33^2+16^2+8^2+4^2)*3
#define FEAT 117        // 4 bbox + 81 conf + 32 mask
#define HCOUT 351       // fused head channels: 12 bbox + 243 conf + 96 mask

typedef __bf16 bf16x8 __attribute__((ext_vector_type(8)));
typedef unsigned short u16x8 __attribute__((ext_vector_type(8)));
typedef float f32x4 __attribute__((ext_vector_type(4)));

__device__ __forceinline__ unsigned short f2bf(float f) {   // RNE fp32->bf16
  unsigned int u = __float_as_uint(f);
  u += 0x7fffu + ((u >> 16) & 1u);
  return (unsigned short)(u >> 16);
}
__device__ __forceinline__ float bf2f(unsigned short s) {
  return __uint_as_float(((unsigned int)s) << 16);
}
// async global->LDS, 16B per lane; LDS dest = wave-uniform base + lane*16
__device__ __forceinline__ void gload16(const void* g, void* l) {
  __builtin_amdgcn_global_load_lds(
      (const __attribute__((address_space(1))) unsigned int*)g,
      (__attribute__((address_space(3))) unsigned int*)l, 16, 0, 0);
}

// level table: up to 5 levels in one launch (single-level calls use [0])
struct LvTab {
  int pre[6];                      // block-x prefix per level (pre[5]=sentinel)
  int pxIn[5], pxOut[5];           // pixel-base offsets into in/out buffers
  int Hi[5], Wi[5], Ho[5], Wo[5];
  int pbase[5];                    // prior base (outMode 1)
};

// ---------------------------------------------------------------------------
// MFMA implicit-GEMM conv, bf16 NHWC, counted-vmcnt 3-buffer pipeline:
// 128px x 128ch tile, 4 waves (2x2), wave tile 64x64 = 4x4 frags, BK=32.
// Per K-step: vmcnt(4) -> s_barrier -> stage(k+2) -> ds_read buf[k] + 16 MFMA.
// LDS chunk-swizzle: logical chunk c of row r at slot c^((r>>1)&3), applied via
// pre-swizzled per-lane GLOBAL source (gload_lds dest stays linear, rule #21).
__global__ __launch_bounds__(256, 3) void k_conv(
    const unsigned short* __restrict__ in,  // bf16 NHWC [.][px][Cin]
    const unsigned short* __restrict__ w2,  // bf16 [tap][co][ci]
    const float* __restrict__ bias, void* __restrict__ outp,
    const float* __restrict__ zerobuf, LvTab lv,
    int Cin, int csl2, int pad, int ntap, int Cout, int relu, int outMode)
{
  __shared__ __align__(16) unsigned short A_s[3][128 * 32];  // 8KB per buf
  __shared__ __align__(16) unsigned short B_s[3][128 * 32];

  const int tid  = threadIdx.x;
  const int lane = tid & 63;
  const int wave = tid >> 6;
  const int wm = wave >> 1, wn = wave & 1;
  const int b   = blockIdx.z;

  // level decode (wave-uniform)
  int L = 0, bx = blockIdx.x;
  while (bx >= lv.pre[L + 1]) ++L;
  const int Hi = lv.Hi[L], Wi = lv.Wi[L], Ho = lv.Ho[L], Wo = lv.Wo[L];
  const int HW = Ho * Wo;
  const int pm0 = (bx - lv.pre[L]) * 128;
  const int n0  = blockIdx.y * 128;
  const long long pxInB  = (long long)lv.pxIn[L]  + (long long)b * Hi * Wi;
  const long long pxOutB = (long long)lv.pxOut[L] + (long long)b * HW;
  const int pbase = lv.pbase[L];

  // staging geometry: issue q = wave*2+i covers rows q*16..q*16+15;
  // lane l -> row q*16 + (l>>2); source chunk c = (l&3) ^ ((l>>3)&3)  [swizzle]
  const int q0 = wave * 2;
  const int lr = lane >> 2;
  const int cmap = (((lane & 3) ^ ((lane >> 3) & 3)) << 3);  // shorts

  int ay[2], ax[2], brn[2];
  bool apv[2], bv[2];
#pragma unroll
  for (int i = 0; i < 2; ++i) {
    const int row = (q0 + i) * 16 + lr;
    const int p = pm0 + row;
    apv[i] = p < HW;
    const int pp = apv[i] ? p : 0;
    ay[i] = pp / Wo; ax[i] = pp - ay[i] * Wo;
    brn[i] = n0 + row;
    bv[i] = brn[i] < Cout;
  }

  const int nk = ntap << csl2;
  const int cmask = (1 << csl2) - 1;

  f32x4 acc[4][4];
#pragma unroll
  for (int m = 0; m < 4; ++m)
#pragma unroll
    for (int n = 0; n < 4; ++n) acc[m][n] = (f32x4)0.0f;

  // swizzled fragment read offsets (shorts, within one 4096-short buffer)
  const int fl = lane & 15, fq = lane >> 4;
  int offA[4], offB[4];
#pragma unroll
  for (int m = 0; m < 4; ++m) {
    const int rA = wm * 64 + m * 16 + fl;
    offA[m] = rA * 32 + ((fq ^ ((rA >> 1) & 3)) << 3);
    const int rB = wn * 64 + m * 16 + fl;
    offB[m] = rB * 32 + ((fq ^ ((rB >> 1) & 3)) << 3);
  }

  auto stage = [&](int k, int bufSel) {
    const int tap = k >> csl2, cs = k & cmask;
    const int ky = (tap >= 6) ? 2 : (tap >= 3 ? 1 : 0);
    const int kx = tap - ky * 3;
#pragma unroll
    for (int i = 0; i < 2; ++i) {
      const int iy = ay[i] + ky - pad, ix = ax[i] + kx - pad;
      const bool v = apv[i] && ((unsigned)iy < (unsigned)Hi) && ((unsigned)ix < (unsigned)Wi);
      const void* ga = v
          ? (const void*)(in + (pxInB + (long long)iy * Wi + ix) * Cin + (cs << 5) + cmap)
          : (const void*)zerobuf;
      gload16(ga, (void*)&A_s[bufSel][(q0 + i) * 512]);
      const void* gb = bv[i]
          ? (const void*)(w2 + ((size_t)tap * Cout + brn[i]) * Cin + (cs << 5) + cmap)
          : (const void*)zerobuf;
      gload16(gb, (void*)&B_s[bufSel][(q0 + i) * 512]);
    }
  };

  stage(0, 0);
  stage(1, 1);                       // 8 loads outstanding per wave
  int cur = 0;

  for (int k = 0; k < nk; ++k) {
    if (k + 1 < nk) asm volatile("s_waitcnt vmcnt(4)" ::: "memory");
    else            asm volatile("s_waitcnt vmcnt(0)" ::: "memory");
    __builtin_amdgcn_s_barrier();    // all waves' step-k data in LDS;
                                     // all reads of buf[k-1] retired
    if (k + 2 < nk) {
      int tgt = cur + 2; if (tgt >= 3) tgt -= 3;
      stage(k + 2, tgt);             // overwrite buf[k-1], stays in flight
    }
    const unsigned short* Ab = A_s[cur];
    const unsigned short* Bb = B_s[cur];
    bf16x8 afr[4], bfr[4];
#pragma unroll
    for (int m = 0; m < 4; ++m) afr[m] = *(const bf16x8*)&Ab[offA[m]];
#pragma unroll
    for (int n = 0; n < 4; ++n) bfr[n] = *(const bf16x8*)&Bb[offB[n]];
#pragma unroll
    for (int m = 0; m < 4; ++m)
#pragma unroll
      for (int n = 0; n < 4; ++n)
        acc[m][n] = __builtin_amdgcn_mfma_f32_16x16x32_bf16(bfr[n], afr[m], acc[m][n], 0, 0, 0);
    cur = (cur == 2) ? 0 : cur + 1;
  }

  // epilogue: D col = pixel = lane&15, row = channel = (lane>>4)*4 + r
  const int px_l = lane & 15;
  const int chq  = (lane >> 4) * 4;
  if (outMode == 0) {
    unsigned short* outb = (unsigned short*)outp;
#pragma unroll
    for (int m = 0; m < 4; ++m) {
      const int p = pm0 + wm * 64 + m * 16 + px_l;
      if (p >= HW) continue;
#pragma unroll
      for (int n = 0; n < 4; ++n) {
        const int ch = n0 + wn * 64 + n * 16 + chq;
        float4 bb = *(const float4*)&bias[ch];
        float v0 = acc[m][n][0] + bb.x, v1 = acc[m][n][1] + bb.y;
        float v2 = acc[m][n][2] + bb.z, v3 = acc[m][n][3] + bb.w;
        if (relu) {
          v0 = fmaxf(v0, 0.f); v1 = fmaxf(v1, 0.f);
          v2 = fmaxf(v2, 0.f); v3 = fmaxf(v3, 0.f);
        }
        ushort4 st = {f2bf(v0), f2bf(v1), f2bf(v2), f2bf(v3)};
        *(ushort4*)&outb[(pxOutB + p) * 256 + ch] = st;
      }
    }
  } else {
    float* outf = (float*)outp;
#pragma unroll
    for (int m = 0; m < 4; ++m) {
      const int p = pm0 + wm * 64 + m * 16 + px_l;
      if (p >= HW) continue;
      const size_t pb_ = ((size_t)b * NPTOT + pbase + (size_t)p * 3);
#pragma unroll
      for (int n = 0; n < 4; ++n) {
#pragma unroll
        for (int r = 0; r < 4; ++r) {
          const int co = n0 + wn * 64 + n * 16 + chq + r;
          if (co >= HCOUT) continue;
          float vv = acc[m][n][r] + bias[co];
          int aIdx, k2, off;
          if (co < 12)       { aIdx = co >> 2; k2 = co & 3; off = 0; }
          else if (co < 255) { int c = co - 12; aIdx = (c >= 162) ? 2 : (c >= 81 ? 1 : 0);
                               k2 = c - aIdx * 81; off = 4; }
          else               { int c = co - 255; aIdx = c >> 5; k2 = c & 31; off = 85;
                               vv = tanhf(vv); }
          outf[(pb_ + aIdx) * FEAT + off + k2] = vv;
        }
      }
    }
  }
}

// ---------------------------------------------------------------------------
__global__ __launch_bounds__(256) void k_zero(float* __restrict__ zb) {
  zb[threadIdx.x] = 0.f;
}

// ---------------------------------------------------------------------------
// fp32 NCHW -> bf16 NHWC tiled transpose (64px x 64ch per block via LDS)
__global__ __launch_bounds__(256) void k_tobf16nhwc(
    const float* __restrict__ in, unsigned short* __restrict__ out, int C, int HW) {
  __shared__ float t[64][65];
  const int p0 = blockIdx.x * 64, c0 = blockIdx.y * 64, b = blockIdx.z;
  const int tid = threadIdx.x;
  const float* ib = in + ((size_t)b * C + c0) * HW;
#pragma unroll 4
  for (int r = 0; r < 16; ++r) {
    int ch = r * 4 + (tid >> 6);
    int px = tid & 63;
    t[ch][px] = (p0 + px < HW) ? ib[(size_t)ch * HW + p0 + px] : 0.f;
  }
  __syncthreads();
#pragma unroll 4
  for (int r = 0; r < 16; ++r) {
    int px = r * 4 + (tid >> 6);
    int ch = tid & 63;
    if (p0 + px < HW)
      out[((size_t)b * HW + p0 + px) * C + c0 + ch] = f2bf(t[ch][px]);
  }
}

// ---------------------------------------------------------------------------
// weight convert+transpose: w2[tap][rowOff+co][ci] = w[co][ci][tap] (fp32->bf16)
__global__ __launch_bounds__(256) void k_wconv(
    const float* __restrict__ w, unsigned short* __restrict__ w2,
    int Cout, int Cin, int ntap, int rowStride, int rowOff) {
  int i = blockIdx.x * 256 + threadIdx.x;
  int total = Cout * Cin * ntap;
  if (i >= total) return;
  int co = i / (Cin * ntap);
  int rem = i - co * (Cin * ntap);
  int ci = rem / ntap;
  int tap = rem - ci * ntap;
  w2[((size_t)tap * rowStride + rowOff + co) * Cin + ci] = f2bf(w[i]);
}

// ---------------------------------------------------------------------------
__global__ __launch_bounds__(384) void k_bias_head(
    const float* __restrict__ bbox_b, const float* __restrict__ conf_b,
    const float* __restrict__ mask_b, float* __restrict__ bh) {
  int co = threadIdx.x;
  float v = 0.f;
  if (co < 12) v = bbox_b[co];
  else if (co < 255) v = conf_b[co - 12];
  else if (co < HCOUT) v = mask_b[co - 255];
  if (co < 384) bh[co] = v;
}

// ---------------------------------------------------------------------------
// jax-exact bilinear resize add, bf16 NHWC, C=256. thread = 8ch of one out px.
__global__ __launch_bounds__(256) void k_resize_add_nhwc(
    const unsigned short* __restrict__ in, unsigned short* __restrict__ out,
    int Hi, int Wi, int Ho, int Wo) {
  int idx = blockIdx.x * 256 + threadIdx.x;
  int HW = Ho * Wo;
  if (idx >= HW * 32) return;
  int b = blockIdx.z;
  int c0 = (idx & 31) * 8;
  int p = idx >> 5;
  int y = p / Wo, x = p - y * Wo;
  float sy = (y + 0.5f) * (float)Hi / (float)Ho - 0.5f;
  float sx = (x + 0.5f) * (float)Wi / (float)Wo - 0.5f;
  int iy0 = (int)floorf(sy), ix0 = (int)floorf(sx);
  float wy1 = sy - (float)iy0, wy0 = 1.f - wy1;
  float wx1 = sx - (float)ix0, wx0 = 1.f - wx1;
  if (iy0 < 0 || iy0 >= Hi) wy0 = 0.f;
  if (iy0 + 1 < 0 || iy0 + 1 >= Hi) wy1 = 0.f;
  if (ix0 < 0 || ix0 >= Wi) wx0 = 0.f;
  if (ix0 + 1 < 0 || ix0 + 1 >= Wi) wx1 = 0.f;
  float ty_ = wy0 + wy1, tx_ = wx0 + wx1;
  wy0 /= ty_; wy1 /= ty_; wx0 /= tx_; wx1 /= tx_;
  int y0 = min(max(iy0, 0), Hi - 1), y1 = min(max(iy0 + 1, 0), Hi - 1);
  int x0 = min(max(ix0, 0), Wi - 1), x1 = min(max(ix0 + 1, 0), Wi - 1);
  const unsigned short* ib = in + (size_t)b * Hi * Wi * 256;
  u16x8 v00 = *(const u16x8*)&ib[((size_t)y0 * Wi + x0) * 256 + c0];
  u16x8 v01 = *(const u16x8*)&ib[((size_t)y0 * Wi + x1) * 256 + c0];
  u16x8 v10 = *(const u16x8*)&ib[((size_t)y1 * Wi + x0) * 256 + c0];
  u16x8 v11 = *(const u16x8*)&ib[((size_t)y1 * Wi + x1) * 256 + c0];
  unsigned short* ob = out + ((size_t)b * HW + p) * 256 + c0;
  u16x8 cur = *(u16x8*)ob, res;
#pragma unroll
  for (int i = 0; i < 8; ++i) {
    float bl = wy0 * (wx0 * bf2f(v00[i]) + wx1 * bf2f(v01[i])) +
               wy1 * (wx0 * bf2f(v10[i]) + wx1 * bf2f(v11[i]));
    res[i] = f2bf(bf2f(cur[i]) + bl);
  }
  *(u16x8*)ob = res;
}

// ---------------------------------------------------------------------------
__global__ __launch_bounds__(256) void k_down_nhwc(
    const unsigned short* __restrict__ in, unsigned short* __restrict__ out,
    int Hi, int Wi) {
  int Ho = Hi / 2, Wo = Wi / 2, HW = Ho * Wo;
  int idx = blockIdx.x * 256 + threadIdx.x;
  if (idx >= HW * 32) return;
  int b = blockIdx.z;
  int c0 = (idx & 31) * 8;
  int p = idx >> 5;
  int y = p / Wo, x = p - y * Wo;
  *(u16x8*)&out[((size_t)b * HW + p) * 256 + c0] =
      *(const u16x8*)&in[((size_t)b * Hi * Wi + (size_t)(2 * y) * Wi + 2 * x) * 256 + c0];
}

// ---------------------------------------------------------------------------
__global__ __launch_bounds__(256) void priors_kernel(float* __restrict__ pr) {
  int pi = blockIdx.x * 256 + threadIdx.x;
  if (pi >= NPTOT) return;
  const int sizes[5] = {67, 33, 16, 8, 4};
  int idx = pi, H = 4;
#pragma unroll
  for (int L = 0; L < 5; ++L) {
    int cnt = sizes[L] * sizes[L] * 3;
    if (idx < cnt) { H = sizes[L]; break; }
    idx -= cnt;
  }
  int a = idx % 3; int cell = idx / 3;
  int x = cell % H; int y = cell / H;
  const float ars[3] = {1.0f, 0.5f, 2.0f};
  pr[pi * 4 + 0] = (x + 0.5f) / (float)H;
  pr[pi * 4 + 1] = (y + 0.5f) / (float)H;
  pr[pi * 4 + 2] = 3.0f * ars[a] / (float)H;
  pr[pi * 4 + 3] = 3.0f / ars[a] / (float)H;
}

// ---------------------------------------------------------------------------
extern "C" void kernel_launch(void* const* d_in, const int* in_sizes, int n_in,
                              void* d_out, int out_size, void* d_ws, size_t ws_size,
                              hipStream_t stream) {
  const float* c3 = (const float*)d_in[0];
  const float* c4 = (const float*)d_in[1];
  const float* c5 = (const float*)d_in[2];
  const float* lat_w5 = (const float*)d_in[3];  const float* lat_b5 = (const float*)d_in[4];
  const float* lat_w4 = (const float*)d_in[5];  const float* lat_b4 = (const float*)d_in[6];
  const float* lat_w3 = (const float*)d_in[7];  const float* lat_b3 = (const float*)d_in[8];
  const float* pred_w0 = (const float*)d_in[9];  const float* pred_b0 = (const float*)d_in[10];
  const float* pred_w1 = (const float*)d_in[11]; const float* pred_b1 = (const float*)d_in[12];
  const float* pred_w2 = (const float*)d_in[13]; const float* pred_b2 = (const float*)d_in[14];
  const float* up_w = (const float*)d_in[15];  const float* up_b = (const float*)d_in[16];
  const float* bbox_w = (const float*)d_in[17]; const float* bbox_b = (const float*)d_in[18];
  const float* conf_w = (const float*)d_in[19]; const float* conf_b = (const float*)d_in[20];
  const float* mask_w = (const float*)d_in[21]; const float* mask_b = (const float*)d_in[22];

  float* out = (float*)d_out;
  float* priors = out + (size_t)8 * NPTOT * FEAT;

  // workspace layout (bf16 element offsets); peak 48,622,592 elem = 97.25 MB
  unsigned short* B0 = (unsigned short*)d_ws;
  unsigned short* w2_lat5  = B0 + 0;         // 524288
  unsigned short* w2_pred0 = B0 + 524288;    // 589824
  unsigned short* w2_lat4  = B0 + 1114112;   // 262144
  unsigned short* w2_pred1 = B0 + 1376256;   // 589824
  unsigned short* w2_lat3  = B0 + 1966080;   // 131072
  unsigned short* w2_pred2 = B0 + 2097152;   // 589824
  unsigned short* w2_up    = B0 + 2686976;   // 589824
  unsigned short* w2_head  = B0 + 3276800;   // 808704 -> 4085504
  unsigned short* x5 = B0 + 4085504;         // 663552   -> 4749056
  unsigned short* x4 = B0 + 4749056;         // 2508800  -> 7257856
  unsigned short* x3 = B0 + 7257856;         // 9750528  -> 17008384
  unsigned short* P  = B0 + 17008384;        // 12111872 -> 29120256 (p3..p7 concat)
  unsigned short* R  = B0 + 29120256;        // 19501056 -> 48621312 (c5b/c4b/c3b; U later)
  float* bias_h = (float*)(B0 + 48621312);   // 384 f32  -> 48622080
  float* zb     = (float*)(B0 + 48622080);   // 256 f32  -> 48622592
  // P level pixel offsets (px, per level, batch-major inside level)
  const int pxP[5] = {0, 35912, 44624, 46672, 47184};   // p3,p4,p5,p6,p7
  unsigned short* p3 = P;
  unsigned short* p4 = P + (size_t)pxP[1] * 256;
  unsigned short* p5 = P + (size_t)pxP[2] * 256;
  unsigned short* p6 = P + (size_t)pxP[3] * 256;
  unsigned short* p7 = P + (size_t)pxP[4] * 256;
  unsigned short* U  = R;                    // R dead after FPN; 12.1M <= 19.5M

  if (ws_size < 48622592ull * 2ull) {        // diagnostic: priors only
    priors_kernel<<<dim3((NPTOT + 255) / 256), dim3(256), 0, stream>>>(priors);
    return;
  }

  auto wc = [&](const float* w_, unsigned short* w2_, int Cout, int Cin, int ntap,
                int rs, int ro) {
    int total = Cout * Cin * ntap;
    k_wconv<<<dim3((total + 255) / 256), dim3(256), 0, stream>>>(w_, w2_, Cout, Cin, ntap, rs, ro);
  };
  auto tonhwc = [&](const float* in_, unsigned short* out_, int C, int HW) {
    k_tobf16nhwc<<<dim3((HW + 63) / 64, C / 64, 8), dim3(256), 0, stream>>>(in_, out_, C, HW);
  };
  // single-level conv
  auto conv1 = [&](const unsigned short* in_, const unsigned short* w2_, const float* b_,
                   void* out_, int Cin, int Hi, int Wi, int Ho, int Wo, int pad, int ntap,
                   int Cout, int relu, int outMode, int pbase) {
    LvTab lv{};
    int nb = (Ho * Wo + 127) / 128;
    lv.pre[0] = 0; for (int i = 1; i < 6; ++i) lv.pre[i] = nb + (i - 1) * 1000000;
    lv.pxIn[0] = 0; lv.pxOut[0] = 0;
    lv.Hi[0] = Hi; lv.Wi[0] = Wi; lv.Ho[0] = Ho; lv.Wo[0] = Wo; lv.pbase[0] = pbase;
    int csl2 = __builtin_ctz(Cin >> 5);
    dim3 g(nb, (Cout + 127) / 128, 8);
    k_conv<<<g, dim3(256), 0, stream>>>(in_, w2_, b_, out_, zb, lv,
                                        Cin, csl2, pad, ntap, Cout, relu, outMode);
  };
  // 5-level batched conv (Cin=256, ntap=9, pad=1, same-size)
  const int Hl[5] = {67, 33, 16, 8, 4};
  const int pbl[5] = {0, 13467, 16734, 17502, 17694};
  auto conv5 = [&](const unsigned short* in_, const unsigned short* w2_, const float* b_,
                   void* out_, int Cout, int relu, int outMode) {
    LvTab lv{};
    int acc_ = 0;
    for (int i = 0; i < 5; ++i) {
      lv.pre[i] = acc_;
      acc_ += (Hl[i] * Hl[i] + 127) / 128;
      lv.pxIn[i] = pxP[i]; lv.pxOut[i] = pxP[i];
      lv.Hi[i] = Hl[i]; lv.Wi[i] = Hl[i]; lv.Ho[i] = Hl[i]; lv.Wo[i] = Hl[i];
      lv.pbase[i] = pbl[i];
    }
    lv.pre[5] = acc_;
    dim3 g(acc_, (Cout + 127) / 128, 8);
    k_conv<<<g, dim3(256), 0, stream>>>(in_, w2_, b_, out_, zb, lv,
                                        256, 3, 1, 9, Cout, relu, outMode);
  };

  // ---- zero region + weights (bf16 repack) ----
  k_zero<<<dim3(1), dim3(256), 0, stream>>>(zb);
  wc(lat_w5, w2_lat5, 256, 2048, 1, 256, 0);
  wc(pred_w0, w2_pred0, 256, 256, 9, 256, 0);
  wc(lat_w4, w2_lat4, 256, 1024, 1, 256, 0);
  wc(pred_w1, w2_pred1, 256, 256, 9, 256, 0);
  wc(lat_w3, w2_lat3, 256, 512, 1, 256, 0);
  wc(pred_w2, w2_pred2, 256, 256, 9, 256, 0);
  wc(up_w, w2_up, 256, 256, 9, 256, 0);
  wc(bbox_w, w2_head, 12, 256, 9, HCOUT, 0);
  wc(conf_w, w2_head, 243, 256, 9, HCOUT, 12);
  wc(mask_w, w2_head, 96, 256, 9, HCOUT, 255);
  k_bias_head<<<dim3(1), dim3(384), 0, stream>>>(bbox_b, conf_b, mask_b, bias_h);

  // ---- FPN ----
  tonhwc(c5, R, 2048, 324);
  conv1(R, w2_lat5, lat_b5, x5, 2048, 18, 18, 18, 18, 0, 1, 256, 0, 0, 0);
  conv1(x5, w2_pred0, pred_b0, p5, 256, 18, 18, 16, 16, 0, 9, 256, 1, 0, 0);
  tonhwc(c4, R, 1024, 1225);
  conv1(R, w2_lat4, lat_b4, x4, 1024, 35, 35, 35, 35, 0, 1, 256, 0, 0, 0);
  k_resize_add_nhwc<<<dim3((1225 * 32 + 255) / 256, 1, 8), dim3(256), 0, stream>>>(x5, x4, 18, 18, 35, 35);
  conv1(x4, w2_pred1, pred_b1, p4, 256, 35, 35, 33, 33, 0, 9, 256, 1, 0, 0);
  tonhwc(c3, R, 512, 4761);
  conv1(R, w2_lat3, lat_b3, x3, 512, 69, 69, 69, 69, 0, 1, 256, 0, 0, 0);
  k_resize_add_nhwc<<<dim3((4761 * 32 + 255) / 256, 1, 8), dim3(256), 0, stream>>>(x4, x3, 35, 35, 69, 69);
  conv1(x3, w2_pred2, pred_b2, p3, 256, 69, 69, 67, 67, 0, 9, 256, 1, 0, 0);
  k_down_nhwc<<<dim3((64 * 32 + 255) / 256, 1, 8), dim3(256), 0, stream>>>(p5, p6, 16, 16);
  k_down_nhwc<<<dim3((16 * 32 + 255) / 256, 1, 8), dim3(256), 0, stream>>>(p6, p7, 8, 8);

  // ---- heads: ONE batched up-conv + ONE batched fused head conv ----
  conv5(P, w2_up, up_b, U, 256, 1, 0);
  conv5(U, w2_head, bias_h, out, HCOUT, 0, 1);

  priors_kernel<<<dim3((NPTOT + 255) / 256), dim3(256), 0, stream>>>(priors);
}

// Round 11
// 710.861 us; speedup vs baseline: 52.2033x; 1.0658x over previous
//
#include <hip/hip_runtime.h>
#include <cstdint>

#define NPTOT 17742     // (67^2+33^2+16^2+8^2+4^2)*3
#define FEAT 117        // 4 bbox + 81 conf + 32 mask
#define HCOUT 351       // fused head channels: 12 bbox + 243 conf + 96 mask

typedef __bf16 bf16x8 __attribute__((ext_vector_type(8)));
typedef unsigned short u16x8 __attribute__((ext_vector_type(8)));
typedef float f32x4 __attribute__((ext_vector_type(4)));

__device__ __forceinline__ unsigned short f2bf(float f) {   // RNE fp32->bf16
  unsigned int u = __float_as_uint(f);
  u += 0x7fffu + ((u >> 16) & 1u);
  return (unsigned short)(u >> 16);
}
__device__ __forceinline__ float bf2f(unsigned short s) {
  return __uint_as_float(((unsigned int)s) << 16);
}
// async global->LDS, 16B per lane; LDS dest = wave-uniform base + lane*16
__device__ __forceinline__ void gload16(const void* g, void* l) {
  __builtin_amdgcn_global_load_lds(
      (const __attribute__((address_space(1))) unsigned int*)g,
      (__attribute__((address_space(3))) unsigned int*)l, 16, 0, 0);
}

// level table: up to 5 levels in one launch (single-level calls use [0])
struct LvTab {
  int pre[6];                      // block-x prefix per level (pre[5]=sentinel)
  int pxIn[5], pxOut[5];           // pixel-base offsets into in/out buffers
  int Hi[5], Wi[5], Ho[5], Wo[5];
  int pbase[5];                    // prior base (outMode 1)
};

// ---------------------------------------------------------------------------
// MFMA implicit-GEMM conv, bf16 NHWC, counted-vmcnt 3-buffer pipeline.
// K-order: ci-slab OUTER, tap INNER (s = cs*NTAP + tap) -> consecutive K-steps
// re-read the same 32ch slab at row-shifted pixels => L1/L2 hits, not HBM.
// 128px x 128ch tile, 4 waves (2x2), wave tile 64x64 = 4x4 frags, BK=32.
// Per K-step: vmcnt(4) -> s_barrier -> stage(k+2) -> ds_read buf[k] + 16 MFMA.
// LDS chunk-swizzle via pre-swizzled per-lane GLOBAL source (rule #21).
template<int NTAP>
__global__ __launch_bounds__(256, 3) void k_conv(
    const unsigned short* __restrict__ in,  // bf16 NHWC [.][px][Cin]
    const unsigned short* __restrict__ w2,  // bf16 [tap][co][ci]
    const float* __restrict__ bias, void* __restrict__ outp,
    const float* __restrict__ zerobuf, LvTab lv,
    int Cin, int pad, int Cout, int relu, int outMode)
{
  __shared__ __align__(16) unsigned short A_s[3][128 * 32];  // 8KB per buf
  __shared__ __align__(16) unsigned short B_s[3][128 * 32];

  const int tid  = threadIdx.x;
  const int lane = tid & 63;
  const int wave = tid >> 6;
  const int wm = wave >> 1, wn = wave & 1;
  const int b   = blockIdx.z;

  // level decode (wave-uniform)
  int L = 0, bx = blockIdx.x;
  while (bx >= lv.pre[L + 1]) ++L;
  const int Hi = lv.Hi[L], Wi = lv.Wi[L], Ho = lv.Ho[L], Wo = lv.Wo[L];
  const int HW = Ho * Wo;
  const int pm0 = (bx - lv.pre[L]) * 128;
  const int n0  = blockIdx.y * 128;
  const long long pxInB  = (long long)lv.pxIn[L]  + (long long)b * Hi * Wi;
  const long long pxOutB = (long long)lv.pxOut[L] + (long long)b * HW;
  const int pbase = lv.pbase[L];

  // staging geometry: issue q = wave*2+i covers rows q*16..q*16+15;
  // lane l -> row q*16 + (l>>2); source chunk c = (l&3) ^ ((l>>3)&3)  [swizzle]
  const int q0 = wave * 2;
  const int lr = lane >> 2;
  const int cmap = (((lane & 3) ^ ((lane >> 3) & 3)) << 3);  // shorts

  int ay[2], ax[2], brn[2];
  bool apv[2], bv[2];
#pragma unroll
  for (int i = 0; i < 2; ++i) {
    const int row = (q0 + i) * 16 + lr;
    const int p = pm0 + row;
    apv[i] = p < HW;
    const int pp = apv[i] ? p : 0;
    ay[i] = pp / Wo; ax[i] = pp - ay[i] * Wo;
    brn[i] = n0 + row;
    bv[i] = brn[i] < Cout;
  }

  const int nk = NTAP * (Cin >> 5);

  f32x4 acc[4][4];
#pragma unroll
  for (int m = 0; m < 4; ++m)
#pragma unroll
    for (int n = 0; n < 4; ++n) acc[m][n] = (f32x4)0.0f;

  // swizzled fragment read offsets (shorts, within one 4096-short buffer)
  const int fl = lane & 15, fq = lane >> 4;
  int offA[4], offB[4];
#pragma unroll
  for (int m = 0; m < 4; ++m) {
    const int rA = wm * 64 + m * 16 + fl;
    offA[m] = rA * 32 + ((fq ^ ((rA >> 1) & 3)) << 3);
    const int rB = wn * 64 + m * 16 + fl;
    offB[m] = rB * 32 + ((fq ^ ((rB >> 1) & 3)) << 3);
  }

  auto stage = [&](int s, int bufSel) {
    const int cs  = s / NTAP;            // compile-time divisor (1 or 9)
    const int tap = s - cs * NTAP;
    const int ky = (NTAP == 1) ? 0 : ((tap >= 6) ? 2 : (tap >= 3 ? 1 : 0));
    const int kx = (NTAP == 1) ? 0 : (tap - ky * 3);
#pragma unroll
    for (int i = 0; i < 2; ++i) {
      const int iy = ay[i] + ky - pad, ix = ax[i] + kx - pad;
      const bool v = apv[i] && ((unsigned)iy < (unsigned)Hi) && ((unsigned)ix < (unsigned)Wi);
      const void* ga = v
          ? (const void*)(in + (pxInB + (long long)iy * Wi + ix) * Cin + (cs << 5) + cmap)
          : (const void*)zerobuf;
      gload16(ga, (void*)&A_s[bufSel][(q0 + i) * 512]);
      const void* gb = bv[i]
          ? (const void*)(w2 + ((size_t)tap * Cout + brn[i]) * Cin + (cs << 5) + cmap)
          : (const void*)zerobuf;
      gload16(gb, (void*)&B_s[bufSel][(q0 + i) * 512]);
    }
  };

  stage(0, 0);
  stage(1, 1);                       // 8 loads outstanding per wave
  int cur = 0;

  for (int k = 0; k < nk; ++k) {
    if (k + 1 < nk) asm volatile("s_waitcnt vmcnt(4)" ::: "memory");
    else            asm volatile("s_waitcnt vmcnt(0)" ::: "memory");
    __builtin_amdgcn_s_barrier();    // all waves' step-k data in LDS;
                                     // all reads of buf[k-1] retired
    if (k + 2 < nk) {
      int tgt = cur + 2; if (tgt >= 3) tgt -= 3;
      stage(k + 2, tgt);             // overwrite buf[k-1], stays in flight
    }
    const unsigned short* Ab = A_s[cur];
    const unsigned short* Bb = B_s[cur];
    bf16x8 afr[4], bfr[4];
#pragma unroll
    for (int m = 0; m < 4; ++m) afr[m] = *(const bf16x8*)&Ab[offA[m]];
#pragma unroll
    for (int n = 0; n < 4; ++n) bfr[n] = *(const bf16x8*)&Bb[offB[n]];
#pragma unroll
    for (int m = 0; m < 4; ++m)
#pragma unroll
      for (int n = 0; n < 4; ++n)
        acc[m][n] = __builtin_amdgcn_mfma_f32_16x16x32_bf16(bfr[n], afr[m], acc[m][n], 0, 0, 0);
    cur = (cur == 2) ? 0 : cur + 1;
  }

  // epilogue: D col = pixel = lane&15, row = channel = (lane>>4)*4 + r
  const int px_l = lane & 15;
  const int chq  = (lane >> 4) * 4;
  if (outMode == 0) {
    unsigned short* outb = (unsigned short*)outp;
#pragma unroll
    for (int m = 0; m < 4; ++m) {
      const int p = pm0 + wm * 64 + m * 16 + px_l;
      if (p >= HW) continue;
#pragma unroll
      for (int n = 0; n < 4; ++n) {
        const int ch = n0 + wn * 64 + n * 16 + chq;
        float4 bb = *(const float4*)&bias[ch];
        float v0 = acc[m][n][0] + bb.x, v1 = acc[m][n][1] + bb.y;
        float v2 = acc[m][n][2] + bb.z, v3 = acc[m][n][3] + bb.w;
        if (relu) {
          v0 = fmaxf(v0, 0.f); v1 = fmaxf(v1, 0.f);
          v2 = fmaxf(v2, 0.f); v3 = fmaxf(v3, 0.f);
        }
        ushort4 st = {f2bf(v0), f2bf(v1), f2bf(v2), f2bf(v3)};
        *(ushort4*)&outb[(pxOutB + p) * 256 + ch] = st;
      }
    }
  } else {
    float* outf = (float*)outp;
#pragma unroll
    for (int m = 0; m < 4; ++m) {
      const int p = pm0 + wm * 64 + m * 16 + px_l;
      if (p >= HW) continue;
      const size_t pb_ = ((size_t)b * NPTOT + pbase + (size_t)p * 3);
#pragma unroll
      for (int n = 0; n < 4; ++n) {
#pragma unroll
        for (int r = 0; r < 4; ++r) {
          const int co = n0 + wn * 64 + n * 16 + chq + r;
          if (co >= HCOUT) continue;
          float vv = acc[m][n][r] + bias[co];
          int aIdx, k2, off;
          if (co < 12)       { aIdx = co >> 2; k2 = co & 3; off = 0; }
          else if (co < 255) { int c = co - 12; aIdx = (c >= 162) ? 2 : (c >= 81 ? 1 : 0);
                               k2 = c - aIdx * 81; off = 4; }
          else               { int c = co - 255; aIdx = c >> 5; k2 = c & 31; off = 85;
                               vv = tanhf(vv); }
          outf[(pb_ + aIdx) * FEAT + off + k2] = vv;
        }
      }
    }
  }
}

// ---------------------------------------------------------------------------
__global__ __launch_bounds__(256) void k_zero(float* __restrict__ zb) {
  zb[threadIdx.x] = 0.f;
}

// ---------------------------------------------------------------------------
// fp32 NCHW -> bf16 NHWC tiled transpose (64px x 64ch per block via LDS)
__global__ __launch_bounds__(256) void k_tobf16nhwc(
    const float* __restrict__ in, unsigned short* __restrict__ out, int C, int HW) {
  __shared__ float t[64][65];
  const int p0 = blockIdx.x * 64, c0 = blockIdx.y * 64, b = blockIdx.z;
  const int tid = threadIdx.x;
  const float* ib = in + ((size_t)b * C + c0) * HW;
#pragma unroll 4
  for (int r = 0; r < 16; ++r) {
    int ch = r * 4 + (tid >> 6);
    int px = tid & 63;
    t[ch][px] = (p0 + px < HW) ? ib[(size_t)ch * HW + p0 + px] : 0.f;
  }
  __syncthreads();
#pragma unroll 4
  for (int r = 0; r < 16; ++r) {
    int px = r * 4 + (tid >> 6);
    int ch = tid & 63;
    if (p0 + px < HW)
      out[((size_t)b * HW + p0 + px) * C + c0 + ch] = f2bf(t[ch][px]);
  }
}

// ---------------------------------------------------------------------------
// weight convert+transpose: w2[tap][rowOff+co][ci] = w[co][ci][tap] (fp32->bf16)
__global__ __launch_bounds__(256) void k_wconv(
    const float* __restrict__ w, unsigned short* __restrict__ w2,
    int Cout, int Cin, int ntap, int rowStride, int rowOff) {
  int i = blockIdx.x * 256 + threadIdx.x;
  int total = Cout * Cin * ntap;
  if (i >= total) return;
  int co = i / (Cin * ntap);
  int rem = i - co * (Cin * ntap);
  int ci = rem / ntap;
  int tap = rem - ci * ntap;
  w2[((size_t)tap * rowStride + rowOff + co) * Cin + ci] = f2bf(w[i]);
}

// ---------------------------------------------------------------------------
__global__ __launch_bounds__(384) void k_bias_head(
    const float* __restrict__ bbox_b, const float* __restrict__ conf_b,
    const float* __restrict__ mask_b, float* __restrict__ bh) {
  int co = threadIdx.x;
  float v = 0.f;
  if (co < 12) v = bbox_b[co];
  else if (co < 255) v = conf_b[co - 12];
  else if (co < HCOUT) v = mask_b[co - 255];
  if (co < 384) bh[co] = v;
}

// ---------------------------------------------------------------------------
// jax-exact bilinear resize add, bf16 NHWC, C=256. thread = 8ch of one out px.
__global__ __launch_bounds__(256) void k_resize_add_nhwc(
    const unsigned short* __restrict__ in, unsigned short* __restrict__ out,
    int Hi, int Wi, int Ho, int Wo) {
  int idx = blockIdx.x * 256 + threadIdx.x;
  int HW = Ho * Wo;
  if (idx >= HW * 32) return;
  int b = blockIdx.z;
  int c0 = (idx & 31) * 8;
  int p = idx >> 5;
  int y = p / Wo, x = p - y * Wo;
  float sy = (y + 0.5f) * (float)Hi / (float)Ho - 0.5f;
  float sx = (x + 0.5f) * (float)Wi / (float)Wo - 0.5f;
  int iy0 = (int)floorf(sy), ix0 = (int)floorf(sx);
  float wy1 = sy - (float)iy0, wy0 = 1.f - wy1;
  float wx1 = sx - (float)ix0, wx0 = 1.f - wx1;
  if (iy0 < 0 || iy0 >= Hi) wy0 = 0.f;
  if (iy0 + 1 < 0 || iy0 + 1 >= Hi) wy1 = 0.f;
  if (ix0 < 0 || ix0 >= Wi) wx0 = 0.f;
  if (ix0 + 1 < 0 || ix0 + 1 >= Wi) wx1 = 0.f;
  float ty_ = wy0 + wy1, tx_ = wx0 + wx1;
  wy0 /= ty_; wy1 /= ty_; wx0 /= tx_; wx1 /= tx_;
  int y0 = min(max(iy0, 0), Hi - 1), y1 = min(max(iy0 + 1, 0), Hi - 1);
  int x0 = min(max(ix0, 0), Wi - 1), x1 = min(max(ix0 + 1, 0), Wi - 1);
  const unsigned short* ib = in + (size_t)b * Hi * Wi * 256;
  u16x8 v00 = *(const u16x8*)&ib[((size_t)y0 * Wi + x0) * 256 + c0];
  u16x8 v01 = *(const u16x8*)&ib[((size_t)y0 * Wi + x1) * 256 + c0];
  u16x8 v10 = *(const u16x8*)&ib[((size_t)y1 * Wi + x0) * 256 + c0];
  u16x8 v11 = *(const u16x8*)&ib[((size_t)y1 * Wi + x1) * 256 + c0];
  unsigned short* ob = out + ((size_t)b * HW + p) * 256 + c0;
  u16x8 cur = *(u16x8*)ob, res;
#pragma unroll
  for (int i = 0; i < 8; ++i) {
    float bl = wy0 * (wx0 * bf2f(v00[i]) + wx1 * bf2f(v01[i])) +
               wy1 * (wx0 * bf2f(v10[i]) + wx1 * bf2f(v11[i]));
    res[i] = f2bf(bf2f(cur[i]) + bl);
  }
  *(u16x8*)ob = res;
}

// ---------------------------------------------------------------------------
__global__ __launch_bounds__(256) void k_down_nhwc(
    const unsigned short* __restrict__ in, unsigned short* __restrict__ out,
    int Hi, int Wi) {
  int Ho = Hi / 2, Wo = Wi / 2, HW = Ho * Wo;
  int idx = blockIdx.x * 256 + threadIdx.x;
  if (idx >= HW * 32) return;
  int b = blockIdx.z;
  int c0 = (idx & 31) * 8;
  int p = idx >> 5;
  int y = p / Wo, x = p - y * Wo;
  *(u16x8*)&out[((size_t)b * HW + p) * 256 + c0] =
      *(const u16x8*)&in[((size_t)b * Hi * Wi + (size_t)(2 * y) * Wi + 2 * x) * 256 + c0];
}

// ---------------------------------------------------------------------------
__global__ __launch_bounds__(256) void priors_kernel(float* __restrict__ pr) {
  int pi = blockIdx.x * 256 + threadIdx.x;
  if (pi >= NPTOT) return;
  const int sizes[5] = {67, 33, 16, 8, 4};
  int idx = pi, H = 4;
#pragma unroll
  for (int L = 0; L < 5; ++L) {
    int cnt = sizes[L] * sizes[L] * 3;
    if (idx < cnt) { H = sizes[L]; break; }
    idx -= cnt;
  }
  int a = idx % 3; int cell = idx / 3;
  int x = cell % H; int y = cell / H;
  const float ars[3] = {1.0f, 0.5f, 2.0f};
  pr[pi * 4 + 0] = (x + 0.5f) / (float)H;
  pr[pi * 4 + 1] = (y + 0.5f) / (float)H;
  pr[pi * 4 + 2] = 3.0f * ars[a] / (float)H;
  pr[pi * 4 + 3] = 3.0f / ars[a] / (float)H;
}

// ---------------------------------------------------------------------------
extern "C" void kernel_launch(void* const* d_in, const int* in_sizes, int n_in,
                              void* d_out, int out_size, void* d_ws, size_t ws_size,
                              hipStream_t stream) {
  const float* c3 = (const float*)d_in[0];
  const float* c4 = (const float*)d_in[1];
  const float* c5 = (const float*)d_in[2];
  const float* lat_w5 = (const float*)d_in[3];  const float* lat_b5 = (const float*)d_in[4];
  const float* lat_w4 = (const float*)d_in[5];  const float* lat_b4 = (const float*)d_in[6];
  const float* lat_w3 = (const float*)d_in[7];  const float* lat_b3 = (const float*)d_in[8];
  const float* pred_w0 = (const float*)d_in[9];  const float* pred_b0 = (const float*)d_in[10];
  const float* pred_w1 = (const float*)d_in[11]; const float* pred_b1 = (const float*)d_in[12];
  const float* pred_w2 = (const float*)d_in[13]; const float* pred_b2 = (const float*)d_in[14];
  const float* up_w = (const float*)d_in[15];  const float* up_b = (const float*)d_in[16];
  const float* bbox_w = (const float*)d_in[17]; const float* bbox_b = (const float*)d_in[18];
  const float* conf_w = (const float*)d_in[19]; const float* conf_b = (const float*)d_in[20];
  const float* mask_w = (const float*)d_in[21]; const float* mask_b = (const float*)d_in[22];

  float* out = (float*)d_out;
  float* priors = out + (size_t)8 * NPTOT * FEAT;

  // workspace layout (bf16 element offsets); peak 48,622,592 elem = 97.25 MB
  unsigned short* B0 = (unsigned short*)d_ws;
  unsigned short* w2_lat5  = B0 + 0;         // 524288
  unsigned short* w2_pred0 = B0 + 524288;    // 589824
  unsigned short* w2_lat4  = B0 + 1114112;   // 262144
  unsigned short* w2_pred1 = B0 + 1376256;   // 589824
  unsigned short* w2_lat3  = B0 + 1966080;   // 131072
  unsigned short* w2_pred2 = B0 + 2097152;   // 589824
  unsigned short* w2_up    = B0 + 2686976;   // 589824
  unsigned short* w2_head  = B0 + 3276800;   // 808704 -> 4085504
  unsigned short* x5 = B0 + 4085504;         // 663552   -> 4749056
  unsigned short* x4 = B0 + 4749056;         // 2508800  -> 7257856
  unsigned short* x3 = B0 + 7257856;         // 9750528  -> 17008384
  unsigned short* P  = B0 + 17008384;        // 12111872 -> 29120256 (p3..p7 concat)
  unsigned short* R  = B0 + 29120256;        // 19501056 -> 48621312 (c5b/c4b/c3b; U later)
  float* bias_h = (float*)(B0 + 48621312);   // 384 f32  -> 48622080
  float* zb     = (float*)(B0 + 48622080);   // 256 f32  -> 48622592
  // P level pixel offsets (px, per level, batch-major inside level)
  const int pxP[5] = {0, 35912, 44624, 46672, 47184};   // p3,p4,p5,p6,p7
  unsigned short* p3 = P;
  unsigned short* p4 = P + (size_t)pxP[1] * 256;
  unsigned short* p5 = P + (size_t)pxP[2] * 256;
  unsigned short* p6 = P + (size_t)pxP[3] * 256;
  unsigned short* p7 = P + (size_t)pxP[4] * 256;
  unsigned short* U  = R;                    // R dead after FPN; 12.1M <= 19.5M

  if (ws_size < 48622592ull * 2ull) {        // diagnostic: priors only
    priors_kernel<<<dim3((NPTOT + 255) / 256), dim3(256), 0, stream>>>(priors);
    return;
  }

  auto wc = [&](const float* w_, unsigned short* w2_, int Cout, int Cin, int ntap,
                int rs, int ro) {
    int total = Cout * Cin * ntap;
    k_wconv<<<dim3((total + 255) / 256), dim3(256), 0, stream>>>(w_, w2_, Cout, Cin, ntap, rs, ro);
  };
  auto tonhwc = [&](const float* in_, unsigned short* out_, int C, int HW) {
    k_tobf16nhwc<<<dim3((HW + 63) / 64, C / 64, 8), dim3(256), 0, stream>>>(in_, out_, C, HW);
  };
  // single-level conv
  auto conv1 = [&](const unsigned short* in_, const unsigned short* w2_, const float* b_,
                   void* out_, int Cin, int Hi, int Wi, int Ho, int Wo, int pad, int ntap,
                   int Cout, int relu, int outMode, int pbase) {
    LvTab lv{};
    int nb = (Ho * Wo + 127) / 128;
    lv.pre[0] = 0; for (int i = 1; i < 6; ++i) lv.pre[i] = nb + (i - 1) * 1000000;
    lv.pxIn[0] = 0; lv.pxOut[0] = 0;
    lv.Hi[0] = Hi; lv.Wi[0] = Wi; lv.Ho[0] = Ho; lv.Wo[0] = Wo; lv.pbase[0] = pbase;
    dim3 g(nb, (Cout + 127) / 128, 8);
    if (ntap == 1)
      k_conv<1><<<g, dim3(256), 0, stream>>>(in_, w2_, b_, out_, zb, lv,
                                             Cin, pad, Cout, relu, outMode);
    else
      k_conv<9><<<g, dim3(256), 0, stream>>>(in_, w2_, b_, out_, zb, lv,
                                             Cin, pad, Cout, relu, outMode);
  };
  // 5-level batched conv (Cin=256, ntap=9, pad=1, same-size)
  const int Hl[5] = {67, 33, 16, 8, 4};
  const int pbl[5] = {0, 13467, 16734, 17502, 17694};
  auto conv5 = [&](const unsigned short* in_, const unsigned short* w2_, const float* b_,
                   void* out_, int Cout, int relu, int outMode) {
    LvTab lv{};
    int acc_ = 0;
    for (int i = 0; i < 5; ++i) {
      lv.pre[i] = acc_;
      acc_ += (Hl[i] * Hl[i] + 127) / 128;
      lv.pxIn[i] = pxP[i]; lv.pxOut[i] = pxP[i];
      lv.Hi[i] = Hl[i]; lv.Wi[i] = Hl[i]; lv.Ho[i] = Hl[i]; lv.Wo[i] = Hl[i];
      lv.pbase[i] = pbl[i];
    }
    lv.pre[5] = acc_;
    dim3 g(acc_, (Cout + 127) / 128, 8);
    k_conv<9><<<g, dim3(256), 0, stream>>>(in_, w2_, b_, out_, zb, lv,
                                           256, 1, Cout, relu, outMode);
  };

  // ---- zero region + weights (bf16 repack) ----
  k_zero<<<dim3(1), dim3(256), 0, stream>>>(zb);
  wc(lat_w5, w2_lat5, 256, 2048, 1, 256, 0);
  wc(pred_w0, w2_pred0, 256, 256, 9, 256, 0);
  wc(lat_w4, w2_lat4, 256, 1024, 1, 256, 0);
  wc(pred_w1, w2_pred1, 256, 256, 9, 256, 0);
  wc(lat_w3, w2_lat3, 256, 512, 1, 256, 0);
  wc(pred_w2, w2_pred2, 256, 256, 9, 256, 0);
  wc(up_w, w2_up, 256, 256, 9, 256, 0);
  wc(bbox_w, w2_head, 12, 256, 9, HCOUT, 0);
  wc(conf_w, w2_head, 243, 256, 9, HCOUT, 12);
  wc(mask_w, w2_head, 96, 256, 9, HCOUT, 255);
  k_bias_head<<<dim3(1), dim3(384), 0, stream>>>(bbox_b, conf_b, mask_b, bias_h);

  // ---- FPN ----
  tonhwc(c5, R, 2048, 324);
  conv1(R, w2_lat5, lat_b5, x5, 2048, 18, 18, 18, 18, 0, 1, 256, 0, 0, 0);
  conv1(x5, w2_pred0, pred_b0, p5, 256, 18, 18, 16, 16, 0, 9, 256, 1, 0, 0);
  tonhwc(c4, R, 1024, 1225);
  conv1(R, w2_lat4, lat_b4, x4, 1024, 35, 35, 35, 35, 0, 1, 256, 0, 0, 0);
  k_resize_add_nhwc<<<dim3((1225 * 32 + 255) / 256, 1, 8), dim3(256), 0, stream>>>(x5, x4, 18, 18, 35, 35);
  conv1(x4, w2_pred1, pred_b1, p4, 256, 35, 35, 33, 33, 0, 9, 256, 1, 0, 0);
  tonhwc(c3, R, 512, 4761);
  conv1(R, w2_lat3, lat_b3, x3, 512, 69, 69, 69, 69, 0, 1, 256, 0, 0, 0);
  k_resize_add_nhwc<<<dim3((4761 * 32 + 255) / 256, 1, 8), dim3(256), 0, stream>>>(x4, x3, 35, 35, 69, 69);
  conv1(x3, w2_pred2, pred_b2, p3, 256, 69, 69, 67, 67, 0, 9, 256, 1, 0, 0);
  k_down_nhwc<<<dim3((64 * 32 + 255) / 256, 1, 8), dim3(256), 0, stream>>>(p5, p6, 16, 16);
  k_down_nhwc<<<dim3((16 * 32 + 255) / 256, 1, 8), dim3(256), 0, stream>>>(p6, p7, 8, 8);

  // ---- heads: ONE batched up-conv + ONE batched fused head conv ----
  conv5(P, w2_up, up_b, U, 256, 1, 0);
  conv5(U, w2_head, bias_h, out, HCOUT, 0, 1);

  priors_kernel<<<dim3((NPTOT + 255) / 256), dim3(256), 0, stream>>>(priors);
}

// Round 12
// 646.961 us; speedup vs baseline: 57.3595x; 1.0988x over previous
//
#include <hip/hip_runtime.h>
#include <cstdint>

#define NPTOT 17742     // (67^2+33^2+16^2+8^2+4^2)*3
#define FEAT 117        // 4 bbox + 81 conf + 32 mask
#define HCOUT 351       // fused head channels: 12 bbox + 243 conf + 96 mask
#define HROWS 384       // padded head weight rows per tap (zero-filled tail)

typedef __bf16 bf16x8 __attribute__((ext_vector_type(8)));
typedef unsigned short u16x8 __attribute__((ext_vector_type(8)));
typedef float f32x4 __attribute__((ext_vector_type(4)));

__device__ __forceinline__ unsigned short f2bf(float f) {   // RNE fp32->bf16
  unsigned int u = __float_as_uint(f);
  u += 0x7fffu + ((u >> 16) & 1u);
  return (unsigned short)(u >> 16);
}
__device__ __forceinline__ float bf2f(unsigned short s) {
  return __uint_as_float(((unsigned int)s) << 16);
}
// async global->LDS, 16B per lane; LDS dest = wave-uniform base + lane*16
__device__ __forceinline__ void gload16(const void* g, void* l) {
  __builtin_amdgcn_global_load_lds(
      (const __attribute__((address_space(1))) unsigned int*)g,
      (__attribute__((address_space(3))) unsigned int*)l, 16, 0, 0);
}

// level table: up to 5 levels in one launch (single-level calls use [0])
struct LvTab {
  int pre[6];                      // block-x prefix per level (pre[5]=sentinel)
  int pxIn[5], pxOut[5];           // pixel-base offsets into in/out buffers
  int Hi[5], Wi[5], Ho[5], Wo[5];
  int pbase[5];                    // prior base (outMode 1)
};

// ---------------------------------------------------------------------------
// MFMA implicit-GEMM conv, bf16 NHWC, counted-vmcnt 3-buffer pipeline.
// K-order: ci-slab OUTER, tap INNER (compile-time-unrolled for NTAP==9).
// Staging address math hoisted: per-step = bfe+cndmask+add (was ~40 VALU).
// B rows padded (CoutRows) so weight staging needs no validity select.
// 128px x 128ch tile, 4 waves (2x2), wave tile 64x64 = 4x4 frags, BK=32.
// Per K-step: vmcnt(4) -> s_barrier -> stage(k+2) -> ds_read buf[k] + 16 MFMA.
// LDS chunk-swizzle via pre-swizzled per-lane GLOBAL source (rule #21).
template<int NTAP>
__global__ __launch_bounds__(256, 3) void k_conv(
    const unsigned short* __restrict__ in,  // bf16 NHWC [.][px][Cin]
    const unsigned short* __restrict__ w2,  // bf16 [tap][CoutRows][ci]
    const float* __restrict__ bias, void* __restrict__ outp,
    const float* __restrict__ zerobuf, LvTab lv,
    int Cin, int pad, int Cout, int CoutRows, int relu, int outMode)
{
  __shared__ __align__(16) unsigned short A_s[3][128 * 32];  // 8KB per buf
  __shared__ __align__(16) unsigned short B_s[3][128 * 32];

  const int tid  = threadIdx.x;
  const int lane = tid & 63;
  const int wave = tid >> 6;
  const int wm = wave >> 1, wn = wave & 1;
  const int b   = blockIdx.z;

  // level decode (wave-uniform)
  int L = 0, bx = blockIdx.x;
  while (bx >= lv.pre[L + 1]) ++L;
  const int Hi = lv.Hi[L], Wi = lv.Wi[L], Ho = lv.Ho[L], Wo = lv.Wo[L];
  const int HW = Ho * Wo;
  const int pm0 = (bx - lv.pre[L]) * 128;
  const int n0  = blockIdx.y * 128;
  const long long pxInB  = (long long)lv.pxIn[L]  + (long long)b * Hi * Wi;
  const long long pxOutB = (long long)lv.pxOut[L] + (long long)b * HW;
  const int pbase = lv.pbase[L];

  // staging geometry: issue q = wave*2+i covers rows q*16..q*16+15;
  // lane l -> row q*16 + (l>>2); source chunk c = (l&3) ^ ((l>>3)&3)  [swizzle]
  const int q0 = wave * 2;
  const int lr = lane >> 2;
  const int cmap = (((lane & 3) ^ ((lane >> 3) & 3)) << 3);  // shorts

  // ---- one-time staging precompute: base addrs + 9-bit tap validity ----
  const unsigned short* aBase[2];
  const unsigned short* bBase[2];
  unsigned vmask[2];
#pragma unroll
  for (int i = 0; i < 2; ++i) {
    const int row = (q0 + i) * 16 + lr;
    const int p = pm0 + row;
    const bool apv = p < HW;
    const int pp = apv ? p : 0;
    const int ay = pp / Wo, ax = pp - (pp / Wo) * Wo;
    aBase[i] = in + (pxInB + (long long)ay * Wi + ax) * Cin + cmap;
    bBase[i] = w2 + (size_t)(n0 + row) * Cin + cmap;   // row < CoutRows (padded)
    unsigned mb = 0;
    if (apv) {
#pragma unroll
      for (int t = 0; t < NTAP; ++t) {
        const int ky = t / 3, kx = t - (t / 3) * 3;
        const int iy = ay + ky - pad, ix = ax + kx - pad;
        if ((unsigned)iy < (unsigned)Hi && (unsigned)ix < (unsigned)Wi) mb |= (1u << t);
      }
    }
    vmask[i] = mb;
  }
  const unsigned short* zbuf16 = (const unsigned short*)zerobuf;
  const size_t tapW = (size_t)CoutRows * Cin;        // weight tap stride

  f32x4 acc[4][4];
#pragma unroll
  for (int m = 0; m < 4; ++m)
#pragma unroll
    for (int n = 0; n < 4; ++n) acc[m][n] = (f32x4)0.0f;

  // swizzled fragment read offsets (shorts, within one 4096-short buffer)
  const int fl = lane & 15, fq = lane >> 4;
  int offA[4], offB[4];
#pragma unroll
  for (int m = 0; m < 4; ++m) {
    const int rA = wm * 64 + m * 16 + fl;
    offA[m] = rA * 32 + ((fq ^ ((rA >> 1) & 3)) << 3);
    const int rB = wn * 64 + m * 16 + fl;
    offB[m] = rB * 32 + ((fq ^ ((rB >> 1) & 3)) << 3);
  }

  auto stage = [&](int cs, int tap, int buf) {
    const int ky = tap / 3, kx = tap - (tap / 3) * 3;       // folds when const
    const int dA = ((ky - pad) * Wi + (kx - pad)) * Cin;    // uniform
    const size_t wOff = (size_t)tap * tapW + (cs << 5);
    const int aOff = (cs << 5) + dA;
#pragma unroll
    for (int i = 0; i < 2; ++i) {
      const unsigned short* ga = ((vmask[i] >> tap) & 1) ? (aBase[i] + aOff) : zbuf16;
      gload16(ga, (void*)&A_s[buf][(q0 + i) * 512]);
      gload16(bBase[i] + wOff, (void*)&B_s[buf][(q0 + i) * 512]);
    }
  };

  auto compute = [&](int buf) {
    const unsigned short* Ab = A_s[buf];
    const unsigned short* Bb = B_s[buf];
    bf16x8 afr[4], bfr[4];
#pragma unroll
    for (int m = 0; m < 4; ++m) afr[m] = *(const bf16x8*)&Ab[offA[m]];
#pragma unroll
    for (int n = 0; n < 4; ++n) bfr[n] = *(const bf16x8*)&Bb[offB[n]];
    __builtin_amdgcn_s_setprio(1);
#pragma unroll
    for (int m = 0; m < 4; ++m)
#pragma unroll
      for (int n = 0; n < 4; ++n)
        acc[m][n] = __builtin_amdgcn_mfma_f32_16x16x32_bf16(bfr[n], afr[m], acc[m][n], 0, 0, 0);
    __builtin_amdgcn_s_setprio(0);
  };

  const int ncs = Cin >> 5;
  const int nk = NTAP * ncs;

  if constexpr (NTAP == 9) {
    stage(0, 0, 0);
    stage(0, 1, 1);
    for (int cs = 0; cs < ncs; ++cs) {
#pragma unroll
      for (int tap = 0; tap < 9; ++tap) {
        const int k = cs * 9 + tap;
        if (k + 1 < nk) asm volatile("s_waitcnt vmcnt(4)" ::: "memory");
        else            asm volatile("s_waitcnt vmcnt(0)" ::: "memory");
        __builtin_amdgcn_s_barrier();
        if (k + 2 < nk) {
          const int t2 = (tap + 2 >= 9) ? tap - 7 : tap + 2;   // compile-time
          const int cs2 = cs + ((tap + 2) >= 9 ? 1 : 0);
          stage(cs2, t2, (tap + 2) % 3);
        }
        compute(tap % 3);            // buffer k%3 == tap%3 (9 ≡ 0 mod 3)
      }
    }
  } else {
    stage(0, 0, 0);
    stage(1, 0, 1);
    int cur = 0;
    for (int k = 0; k < nk; ++k) {
      if (k + 1 < nk) asm volatile("s_waitcnt vmcnt(4)" ::: "memory");
      else            asm volatile("s_waitcnt vmcnt(0)" ::: "memory");
      __builtin_amdgcn_s_barrier();
      if (k + 2 < nk) {
        int tgt = cur + 2; if (tgt >= 3) tgt -= 3;
        stage(k + 2, 0, tgt);
      }
      compute(cur);
      cur = (cur == 2) ? 0 : cur + 1;
    }
  }

  // epilogue: D col = pixel = lane&15, row = channel = (lane>>4)*4 + r
  const int px_l = lane & 15;
  const int chq  = (lane >> 4) * 4;
  if (outMode == 0) {
    unsigned short* outb = (unsigned short*)outp;
#pragma unroll
    for (int m = 0; m < 4; ++m) {
      const int p = pm0 + wm * 64 + m * 16 + px_l;
      if (p >= HW) continue;
#pragma unroll
      for (int n = 0; n < 4; ++n) {
        const int ch = n0 + wn * 64 + n * 16 + chq;
        float4 bb = *(const float4*)&bias[ch];
        float v0 = acc[m][n][0] + bb.x, v1 = acc[m][n][1] + bb.y;
        float v2 = acc[m][n][2] + bb.z, v3 = acc[m][n][3] + bb.w;
        if (relu) {
          v0 = fmaxf(v0, 0.f); v1 = fmaxf(v1, 0.f);
          v2 = fmaxf(v2, 0.f); v3 = fmaxf(v3, 0.f);
        }
        ushort4 st = {f2bf(v0), f2bf(v1), f2bf(v2), f2bf(v3)};
        *(ushort4*)&outb[(pxOutB + p) * 256 + ch] = st;
      }
    }
  } else {
    float* outf = (float*)outp;
#pragma unroll
    for (int m = 0; m < 4; ++m) {
      const int p = pm0 + wm * 64 + m * 16 + px_l;
      if (p >= HW) continue;
      const size_t pb_ = ((size_t)b * NPTOT + pbase + (size_t)p * 3);
#pragma unroll
      for (int n = 0; n < 4; ++n) {
#pragma unroll
        for (int r = 0; r < 4; ++r) {
          const int co = n0 + wn * 64 + n * 16 + chq + r;
          if (co >= HCOUT) continue;
          float vv = acc[m][n][r] + bias[co];
          int aIdx, k2, off;
          if (co < 12)       { aIdx = co >> 2; k2 = co & 3; off = 0; }
          else if (co < 255) { int c = co - 12; aIdx = (c >= 162) ? 2 : (c >= 81 ? 1 : 0);
                               k2 = c - aIdx * 81; off = 4; }
          else               { int c = co - 255; aIdx = c >> 5; k2 = c & 31; off = 85;
                               vv = tanhf(vv); }
          outf[(pb_ + aIdx) * FEAT + off + k2] = vv;
        }
      }
    }
  }
}

// ---------------------------------------------------------------------------
__global__ __launch_bounds__(256) void k_zero(float* __restrict__ zb) {
  zb[threadIdx.x] = 0.f;
}

// ---------------------------------------------------------------------------
// fp32 NCHW -> bf16 NHWC tiled transpose (64px x 64ch per block via LDS)
__global__ __launch_bounds__(256) void k_tobf16nhwc(
    const float* __restrict__ in, unsigned short* __restrict__ out, int C, int HW) {
  __shared__ float t[64][65];
  const int p0 = blockIdx.x * 64, c0 = blockIdx.y * 64, b = blockIdx.z;
  const int tid = threadIdx.x;
  const float* ib = in + ((size_t)b * C + c0) * HW;
#pragma unroll 4
  for (int r = 0; r < 16; ++r) {
    int ch = r * 4 + (tid >> 6);
    int px = tid & 63;
    t[ch][px] = (p0 + px < HW) ? ib[(size_t)ch * HW + p0 + px] : 0.f;
  }
  __syncthreads();
#pragma unroll 4
  for (int r = 0; r < 16; ++r) {
    int px = r * 4 + (tid >> 6);
    int ch = tid & 63;
    if (p0 + px < HW)
      out[((size_t)b * HW + p0 + px) * C + c0 + ch] = f2bf(t[ch][px]);
  }
}

// ---------------------------------------------------------------------------
// weight convert+transpose: w2[tap][rowOff+co][ci] = w[co][ci][tap] (fp32->bf16)
__global__ __launch_bounds__(256) void k_wconv(
    const float* __restrict__ w, unsigned short* __restrict__ w2,
    int Cout, int Cin, int ntap, int rowStride, int rowOff) {
  int i = blockIdx.x * 256 + threadIdx.x;
  int total = Cout * Cin * ntap;
  if (i >= total) return;
  int co = i / (Cin * ntap);
  int rem = i - co * (Cin * ntap);
  int ci = rem / ntap;
  int tap = rem - ci * ntap;
  w2[((size_t)tap * rowStride + rowOff + co) * Cin + ci] = f2bf(w[i]);
}

// ---------------------------------------------------------------------------
__global__ __launch_bounds__(384) void k_bias_head(
    const float* __restrict__ bbox_b, const float* __restrict__ conf_b,
    const float* __restrict__ mask_b, float* __restrict__ bh) {
  int co = threadIdx.x;
  float v = 0.f;
  if (co < 12) v = bbox_b[co];
  else if (co < 255) v = conf_b[co - 12];
  else if (co < HCOUT) v = mask_b[co - 255];
  if (co < 384) bh[co] = v;
}

// ---------------------------------------------------------------------------
// jax-exact bilinear resize add, bf16 NHWC, C=256. thread = 8ch of one out px.
__global__ __launch_bounds__(256) void k_resize_add_nhwc(
    const unsigned short* __restrict__ in, unsigned short* __restrict__ out,
    int Hi, int Wi, int Ho, int Wo) {
  int idx = blockIdx.x * 256 + threadIdx.x;
  int HW = Ho * Wo;
  if (idx >= HW * 32) return;
  int b = blockIdx.z;
  int c0 = (idx & 31) * 8;
  int p = idx >> 5;
  int y = p / Wo, x = p - y * Wo;
  float sy = (y + 0.5f) * (float)Hi / (float)Ho - 0.5f;
  float sx = (x + 0.5f) * (float)Wi / (float)Wo - 0.5f;
  int iy0 = (int)floorf(sy), ix0 = (int)floorf(sx);
  float wy1 = sy - (float)iy0, wy0 = 1.f - wy1;
  float wx1 = sx - (float)ix0, wx0 = 1.f - wx1;
  if (iy0 < 0 || iy0 >= Hi) wy0 = 0.f;
  if (iy0 + 1 < 0 || iy0 + 1 >= Hi) wy1 = 0.f;
  if (ix0 < 0 || ix0 >= Wi) wx0 = 0.f;
  if (ix0 + 1 < 0 || ix0 + 1 >= Wi) wx1 = 0.f;
  float ty_ = wy0 + wy1, tx_ = wx0 + wx1;
  wy0 /= ty_; wy1 /= ty_; wx0 /= tx_; wx1 /= tx_;
  int y0 = min(max(iy0, 0), Hi - 1), y1 = min(max(iy0 + 1, 0), Hi - 1);
  int x0 = min(max(ix0, 0), Wi - 1), x1 = min(max(ix0 + 1, 0), Wi - 1);
  const unsigned short* ib = in + (size_t)b * Hi * Wi * 256;
  u16x8 v00 = *(const u16x8*)&ib[((size_t)y0 * Wi + x0) * 256 + c0];
  u16x8 v01 = *(const u16x8*)&ib[((size_t)y0 * Wi + x1) * 256 + c0];
  u16x8 v10 = *(const u16x8*)&ib[((size_t)y1 * Wi + x0) * 256 + c0];
  u16x8 v11 = *(const u16x8*)&ib[((size_t)y1 * Wi + x1) * 256 + c0];
  unsigned short* ob = out + ((size_t)b * HW + p) * 256 + c0;
  u16x8 cur = *(u16x8*)ob, res;
#pragma unroll
  for (int i = 0; i < 8; ++i) {
    float bl = wy0 * (wx0 * bf2f(v00[i]) + wx1 * bf2f(v01[i])) +
               wy1 * (wx0 * bf2f(v10[i]) + wx1 * bf2f(v11[i]));
    res[i] = f2bf(bf2f(cur[i]) + bl);
  }
  *(u16x8*)ob = res;
}

// ---------------------------------------------------------------------------
__global__ __launch_bounds__(256) void k_down_nhwc(
    const unsigned short* __restrict__ in, unsigned short* __restrict__ out,
    int Hi, int Wi) {
  int Ho = Hi / 2, Wo = Wi / 2, HW = Ho * Wo;
  int idx = blockIdx.x * 256 + threadIdx.x;
  if (idx >= HW * 32) return;
  int b = blockIdx.z;
  int c0 = (idx & 31) * 8;
  int p = idx >> 5;
  int y = p / Wo, x = p - y * Wo;
  *(u16x8*)&out[((size_t)b * HW + p) * 256 + c0] =
      *(const u16x8*)&in[((size_t)b * Hi * Wi + (size_t)(2 * y) * Wi + 2 * x) * 256 + c0];
}

// ---------------------------------------------------------------------------
__global__ __launch_bounds__(256) void priors_kernel(float* __restrict__ pr) {
  int pi = blockIdx.x * 256 + threadIdx.x;
  if (pi >= NPTOT) return;
  const int sizes[5] = {67, 33, 16, 8, 4};
  int idx = pi, H = 4;
#pragma unroll
  for (int L = 0; L < 5; ++L) {
    int cnt = sizes[L] * sizes[L] * 3;
    if (idx < cnt) { H = sizes[L]; break; }
    idx -= cnt;
  }
  int a = idx % 3; int cell = idx / 3;
  int x = cell % H; int y = cell / H;
  const float ars[3] = {1.0f, 0.5f, 2.0f};
  pr[pi * 4 + 0] = (x + 0.5f) / (float)H;
  pr[pi * 4 + 1] = (y + 0.5f) / (float)H;
  pr[pi * 4 + 2] = 3.0f * ars[a] / (float)H;
  pr[pi * 4 + 3] = 3.0f / ars[a] / (float)H;
}

// ---------------------------------------------------------------------------
extern "C" void kernel_launch(void* const* d_in, const int* in_sizes, int n_in,
                              void* d_out, int out_size, void* d_ws, size_t ws_size,
                              hipStream_t stream) {
  const float* c3 = (const float*)d_in[0];
  const float* c4 = (const float*)d_in[1];
  const float* c5 = (const float*)d_in[2];
  const float* lat_w5 = (const float*)d_in[3];  const float* lat_b5 = (const float*)d_in[4];
  const float* lat_w4 = (const float*)d_in[5];  const float* lat_b4 = (const float*)d_in[6];
  const float* lat_w3 = (const float*)d_in[7];  const float* lat_b3 = (const float*)d_in[8];
  const float* pred_w0 = (const float*)d_in[9];  const float* pred_b0 = (const float*)d_in[10];
  const float* pred_w1 = (const float*)d_in[11]; const float* pred_b1 = (const float*)d_in[12];
  const float* pred_w2 = (const float*)d_in[13]; const float* pred_b2 = (const float*)d_in[14];
  const float* up_w = (const float*)d_in[15];  const float* up_b = (const float*)d_in[16];
  const float* bbox_w = (const float*)d_in[17]; const float* bbox_b = (const float*)d_in[18];
  const float* conf_w = (const float*)d_in[19]; const float* conf_b = (const float*)d_in[20];
  const float* mask_w = (const float*)d_in[21]; const float* mask_b = (const float*)d_in[22];

  float* out = (float*)d_out;
  float* priors = out + (size_t)8 * NPTOT * FEAT;

  // workspace layout (bf16 element offsets); peak 48,698,624 elem = 97.40 MB
  unsigned short* B0 = (unsigned short*)d_ws;
  unsigned short* w2_lat5  = B0 + 0;         // 524288
  unsigned short* w2_pred0 = B0 + 524288;    // 589824
  unsigned short* w2_lat4  = B0 + 1114112;   // 262144
  unsigned short* w2_pred1 = B0 + 1376256;   // 589824
  unsigned short* w2_lat3  = B0 + 1966080;   // 131072
  unsigned short* w2_pred2 = B0 + 2097152;   // 589824
  unsigned short* w2_up    = B0 + 2686976;   // 589824
  unsigned short* w2_head  = B0 + 3276800;   // 9*384*256 = 884736 -> 4161536
  unsigned short* x5 = B0 + 4161536;         // 663552   -> 4825088
  unsigned short* x4 = B0 + 4825088;         // 2508800  -> 7333888
  unsigned short* x3 = B0 + 7333888;         // 9750528  -> 17084416
  unsigned short* P  = B0 + 17084416;        // 12111872 -> 29196288 (p3..p7 concat)
  unsigned short* R  = B0 + 29196288;        // 19501056 -> 48697344 (c5b/c4b/c3b; U later)
  float* bias_h = (float*)(B0 + 48697344);   // 384 f32  -> 48698112
  float* zb     = (float*)(B0 + 48698112);   // 256 f32  -> 48698624
  // P level pixel offsets (px, per level, batch-major inside level)
  const int pxP[5] = {0, 35912, 44624, 46672, 47184};   // p3,p4,p5,p6,p7
  unsigned short* p3 = P;
  unsigned short* p4 = P + (size_t)pxP[1] * 256;
  unsigned short* p5 = P + (size_t)pxP[2] * 256;
  unsigned short* p6 = P + (size_t)pxP[3] * 256;
  unsigned short* p7 = P + (size_t)pxP[4] * 256;
  unsigned short* U  = R;                    // R dead after FPN; 12.1M <= 19.5M

  if (ws_size < 48698624ull * 2ull) {        // diagnostic: priors only
    priors_kernel<<<dim3((NPTOT + 255) / 256), dim3(256), 0, stream>>>(priors);
    return;
  }

  auto wc = [&](const float* w_, unsigned short* w2_, int Cout, int Cin, int ntap,
                int rs, int ro) {
    int total = Cout * Cin * ntap;
    k_wconv<<<dim3((total + 255) / 256), dim3(256), 0, stream>>>(w_, w2_, Cout, Cin, ntap, rs, ro);
  };
  auto tonhwc = [&](const float* in_, unsigned short* out_, int C, int HW) {
    k_tobf16nhwc<<<dim3((HW + 63) / 64, C / 64, 8), dim3(256), 0, stream>>>(in_, out_, C, HW);
  };
  // single-level conv (Cout==CoutRows==256 for all callers)
  auto conv1 = [&](const unsigned short* in_, const unsigned short* w2_, const float* b_,
                   void* out_, int Cin, int Hi, int Wi, int Ho, int Wo, int pad, int ntap,
                   int Cout, int relu, int outMode, int pbase) {
    LvTab lv{};
    int nb = (Ho * Wo + 127) / 128;
    lv.pre[0] = 0; for (int i = 1; i < 6; ++i) lv.pre[i] = nb + (i - 1) * 1000000;
    lv.pxIn[0] = 0; lv.pxOut[0] = 0;
    lv.Hi[0] = Hi; lv.Wi[0] = Wi; lv.Ho[0] = Ho; lv.Wo[0] = Wo; lv.pbase[0] = pbase;
    dim3 g(nb, (Cout + 127) / 128, 8);
    if (ntap == 1)
      k_conv<1><<<g, dim3(256), 0, stream>>>(in_, w2_, b_, out_, zb, lv,
                                             Cin, pad, Cout, Cout, relu, outMode);
    else
      k_conv<9><<<g, dim3(256), 0, stream>>>(in_, w2_, b_, out_, zb, lv,
                                             Cin, pad, Cout, Cout, relu, outMode);
  };
  // 5-level batched conv (Cin=256, ntap=9, pad=1, same-size)
  const int Hl[5] = {67, 33, 16, 8, 4};
  const int pbl[5] = {0, 13467, 16734, 17502, 17694};
  auto conv5 = [&](const unsigned short* in_, const unsigned short* w2_, const float* b_,
                   void* out_, int Cout, int CoutRows, int relu, int outMode) {
    LvTab lv{};
    int acc_ = 0;
    for (int i = 0; i < 5; ++i) {
      lv.pre[i] = acc_;
      acc_ += (Hl[i] * Hl[i] + 127) / 128;
      lv.pxIn[i] = pxP[i]; lv.pxOut[i] = pxP[i];
      lv.Hi[i] = Hl[i]; lv.Wi[i] = Hl[i]; lv.Ho[i] = Hl[i]; lv.Wo[i] = Hl[i];
      lv.pbase[i] = pbl[i];
    }
    lv.pre[5] = acc_;
    dim3 g(acc_, (Cout + 127) / 128, 8);
    k_conv<9><<<g, dim3(256), 0, stream>>>(in_, w2_, b_, out_, zb, lv,
                                           256, 1, Cout, CoutRows, relu, outMode);
  };

  // ---- zero region + weights (bf16 repack; head rows zero-padded to 384) ----
  k_zero<<<dim3(1), dim3(256), 0, stream>>>(zb);
  hipMemsetAsync(w2_head, 0, 9ull * HROWS * 256 * 2, stream);
  wc(lat_w5, w2_lat5, 256, 2048, 1, 256, 0);
  wc(pred_w0, w2_pred0, 256, 256, 9, 256, 0);
  wc(lat_w4, w2_lat4, 256, 1024, 1, 256, 0);
  wc(pred_w1, w2_pred1, 256, 256, 9, 256, 0);
  wc(lat_w3, w2_lat3, 256, 512, 1, 256, 0);
  wc(pred_w2, w2_pred2, 256, 256, 9, 256, 0);
  wc(up_w, w2_up, 256, 256, 9, 256, 0);
  wc(bbox_w, w2_head, 12, 256, 9, HROWS, 0);
  wc(conf_w, w2_head, 243, 256, 9, HROWS, 12);
  wc(mask_w, w2_head, 96, 256, 9, HROWS, 255);
  k_bias_head<<<dim3(1), dim3(384), 0, stream>>>(bbox_b, conf_b, mask_b, bias_h);

  // ---- FPN ----
  tonhwc(c5, R, 2048, 324);
  conv1(R, w2_lat5, lat_b5, x5, 2048, 18, 18, 18, 18, 0, 1, 256, 0, 0, 0);
  conv1(x5, w2_pred0, pred_b0, p5, 256, 18, 18, 16, 16, 0, 9, 256, 1, 0, 0);
  tonhwc(c4, R, 1024, 1225);
  conv1(R, w2_lat4, lat_b4, x4, 1024, 35, 35, 35, 35, 0, 1, 256, 0, 0, 0);
  k_resize_add_nhwc<<<dim3((1225 * 32 + 255) / 256, 1, 8), dim3(256), 0, stream>>>(x5, x4, 18, 18, 35, 35);
  conv1(x4, w2_pred1, pred_b1, p4, 256, 35, 35, 33, 33, 0, 9, 256, 1, 0, 0);
  tonhwc(c3, R, 512, 4761);
  conv1(R, w2_lat3, lat_b3, x3, 512, 69, 69, 69, 69, 0, 1, 256, 0, 0, 0);
  k_resize_add_nhwc<<<dim3((4761 * 32 + 255) / 256, 1, 8), dim3(256), 0, stream>>>(x4, x3, 35, 35, 69, 69);
  conv1(x3, w2_pred2, pred_b2, p3, 256, 69, 69, 67, 67, 0, 9, 256, 1, 0, 0);
  k_down_nhwc<<<dim3((64 * 32 + 255) / 256, 1, 8), dim3(256), 0, stream>>>(p5, p6, 16, 16);
  k_down_nhwc<<<dim3((16 * 32 + 255) / 256, 1, 8), dim3(256), 0, stream>>>(p6, p7, 8, 8);

  // ---- heads: ONE batched up-conv + ONE batched fused head conv ----
  conv5(P, w2_up, up_b, U, 256, 256, 1, 0);
  conv5(U, w2_head, bias_h, out, HCOUT, HROWS, 0, 1);

  priors_kernel<<<dim3((NPTOT + 255) / 256), dim3(256), 0, stream>>>(priors);
}

// Round 13
// 585.757 us; speedup vs baseline: 63.3528x; 1.1045x over previous
//
#include <hip/hip_runtime.h>
#include <cstdint>

#define NPTOT 17742     // (67^2+33^2+16^2+8^2+4^2)*3
#define FEAT 117        // 4 bbox + 81 conf + 32 mask
#define HCOUT 351       // fused head channels: 12 bbox + 243 conf + 96 mask
#define HROWS 384       // padded head weight rows per tap (zero-filled tail)

typedef __bf16 bf16x8 __attribute__((ext_vector_type(8)));
typedef unsigned short u16x8 __attribute__((ext_vector_type(8)));
typedef float f32x4 __attribute__((ext_vector_type(4)));

__device__ __forceinline__ unsigned short f2bf(float f) {   // RNE fp32->bf16
  unsigned int u = __float_as_uint(f);
  u += 0x7fffu + ((u >> 16) & 1u);
  return (unsigned short)(u >> 16);
}
__device__ __forceinline__ float bf2f(unsigned short s) {
  return __uint_as_float(((unsigned int)s) << 16);
}
// async global->LDS, 16B per lane; LDS dest = wave-uniform base + lane*16
__device__ __forceinline__ void gload16(const void* g, void* l) {
  __builtin_amdgcn_global_load_lds(
      (const __attribute__((address_space(1))) unsigned int*)g,
      (__attribute__((address_space(3))) unsigned int*)l, 16, 0, 0);
}

// level table: up to 5 levels in one launch (single-level calls use [0])
struct LvTab {
  int pre[6];                      // block-x prefix per level (pre[5]=sentinel)
  int pxIn[5], pxOut[5];           // pixel-base offsets into in/out buffers
  int Hi[5], Wi[5], Ho[5], Wo[5];
  int pbase[5];                    // prior base (outMode 1)
  int Cin[5];                      // per-level input channels
  int bOff[5];                     // per-level bias offset
  long long wOff[5];               // per-level weight offset (elements)
};

// ---------------------------------------------------------------------------
// MFMA implicit-GEMM conv, bf16 NHWC, counted-vmcnt 3-buffer pipeline.
// K-order: ci-slab OUTER, tap INNER (compile-time-unrolled for NTAP==9).
// mfma(A=pixels, B=channels) -> D[row=pixel][col=channel]: 16 lanes write 16
// consecutive channels => coalesced stores in BOTH output modes.
// 128px x 128ch tile, 4 waves (2x2), wave tile 64x64 = 4x4 frags, BK=32.
// Per K-step: vmcnt(4) -> s_barrier -> stage(k+2) -> ds_read buf[k] + 16 MFMA.
// LDS chunk-swizzle via pre-swizzled per-lane GLOBAL source (rule #21).
template<int NTAP>
__global__ __launch_bounds__(256, 3) void k_conv(
    const unsigned short* __restrict__ in,  // bf16 NHWC [.][px][Cin]
    const unsigned short* __restrict__ w2,  // bf16 [tap][CoutRows][ci]
    const float* __restrict__ bias, void* __restrict__ outp,
    const float* __restrict__ zerobuf, LvTab lv,
    int pad, int Cout, int CoutRows, int relu, int outMode)
{
  __shared__ __align__(16) unsigned short A_s[3][128 * 32];  // 8KB per buf
  __shared__ __align__(16) unsigned short B_s[3][128 * 32];

  const int tid  = threadIdx.x;
  const int lane = tid & 63;
  const int wave = tid >> 6;
  const int wm = wave >> 1, wn = wave & 1;
  const int b   = blockIdx.z;

  // level decode (wave-uniform)
  int L = 0, bx = blockIdx.x;
  while (bx >= lv.pre[L + 1]) ++L;
  const int Hi = lv.Hi[L], Wi = lv.Wi[L], Ho = lv.Ho[L], Wo = lv.Wo[L];
  const int Cin = lv.Cin[L];
  const int HW = Ho * Wo;
  const int pm0 = (bx - lv.pre[L]) * 128;
  const int n0  = blockIdx.y * 128;
  const long long pxInB  = (long long)lv.pxIn[L]  + (long long)b * Hi * Wi;
  const long long pxOutB = (long long)lv.pxOut[L] + (long long)b * HW;
  const int pbase = lv.pbase[L];
  const float* biasL = bias + lv.bOff[L];

  // staging geometry: issue q = wave*2+i covers rows q*16..q*16+15;
  // lane l -> row q*16 + (l>>2); source chunk c = (l&3) ^ ((l>>3)&3)  [swizzle]
  const int q0 = wave * 2;
  const int lr = lane >> 2;
  const int cmap = (((lane & 3) ^ ((lane >> 3) & 3)) << 3);  // shorts

  // ---- one-time staging precompute: base addrs + 9-bit tap validity ----
  const unsigned short* aBase[2];
  const unsigned short* bBase[2];
  unsigned vmask[2];
#pragma unroll
  for (int i = 0; i < 2; ++i) {
    const int row = (q0 + i) * 16 + lr;
    const int p = pm0 + row;
    const bool apv = p < HW;
    const int pp = apv ? p : 0;
    const int ay = pp / Wo, ax = pp - (pp / Wo) * Wo;
    aBase[i] = in + (pxInB + (long long)ay * Wi + ax) * Cin + cmap;
    bBase[i] = w2 + lv.wOff[L] + (size_t)(n0 + row) * Cin + cmap;
    unsigned mb = 0;
    if (apv) {
#pragma unroll
      for (int t = 0; t < NTAP; ++t) {
        const int ky = t / 3, kx = t - (t / 3) * 3;
        const int iy = ay + ky - pad, ix = ax + kx - pad;
        if ((unsigned)iy < (unsigned)Hi && (unsigned)ix < (unsigned)Wi) mb |= (1u << t);
      }
    }
    vmask[i] = mb;
  }
  const unsigned short* zbuf16 = (const unsigned short*)zerobuf;
  const size_t tapW = (size_t)CoutRows * Cin;        // weight tap stride

  f32x4 acc[4][4];
#pragma unroll
  for (int m = 0; m < 4; ++m)
#pragma unroll
    for (int n = 0; n < 4; ++n) acc[m][n] = (f32x4)0.0f;

  // swizzled fragment read offsets (shorts, within one 4096-short buffer)
  const int fl = lane & 15, fq = lane >> 4;
  int offA[4], offB[4];
#pragma unroll
  for (int m = 0; m < 4; ++m) {
    const int rA = wm * 64 + m * 16 + fl;
    offA[m] = rA * 32 + ((fq ^ ((rA >> 1) & 3)) << 3);
    const int rB = wn * 64 + m * 16 + fl;
    offB[m] = rB * 32 + ((fq ^ ((rB >> 1) & 3)) << 3);
  }

  auto stage = [&](int cs, int tap, int buf) {
    const int ky = tap / 3, kx = tap - (tap / 3) * 3;       // folds when const
    const int dA = ((ky - pad) * Wi + (kx - pad)) * Cin;    // uniform
    const size_t wOff = (size_t)tap * tapW + (cs << 5);
    const int aOff = (cs << 5) + dA;
#pragma unroll
    for (int i = 0; i < 2; ++i) {
      const unsigned short* ga = ((vmask[i] >> tap) & 1) ? (aBase[i] + aOff) : zbuf16;
      gload16(ga, (void*)&A_s[buf][(q0 + i) * 512]);
      gload16(bBase[i] + wOff, (void*)&B_s[buf][(q0 + i) * 512]);
    }
  };

  auto compute = [&](int buf) {
    const unsigned short* Ab = A_s[buf];
    const unsigned short* Bb = B_s[buf];
    bf16x8 afr[4], bfr[4];
#pragma unroll
    for (int m = 0; m < 4; ++m) afr[m] = *(const bf16x8*)&Ab[offA[m]];
#pragma unroll
    for (int n = 0; n < 4; ++n) bfr[n] = *(const bf16x8*)&Bb[offB[n]];
    __builtin_amdgcn_s_setprio(1);
#pragma unroll
    for (int m = 0; m < 4; ++m)
#pragma unroll
      for (int n = 0; n < 4; ++n)
        acc[m][n] = __builtin_amdgcn_mfma_f32_16x16x32_bf16(afr[m], bfr[n], acc[m][n], 0, 0, 0);
    __builtin_amdgcn_s_setprio(0);
  };

  const int ncs = Cin >> 5;
  const int nk = NTAP * ncs;

  if constexpr (NTAP == 9) {
    stage(0, 0, 0);
    stage(0, 1, 1);
    for (int cs = 0; cs < ncs; ++cs) {
#pragma unroll
      for (int tap = 0; tap < 9; ++tap) {
        const int k = cs * 9 + tap;
        if (k + 1 < nk) asm volatile("s_waitcnt vmcnt(4)" ::: "memory");
        else            asm volatile("s_waitcnt vmcnt(0)" ::: "memory");
        __builtin_amdgcn_s_barrier();
        if (k + 2 < nk) {
          const int t2 = (tap + 2 >= 9) ? tap - 7 : tap + 2;   // compile-time
          const int cs2 = cs + ((tap + 2) >= 9 ? 1 : 0);
          stage(cs2, t2, (tap + 2) % 3);
        }
        compute(tap % 3);            // buffer k%3 == tap%3 (9 ≡ 0 mod 3)
      }
    }
  } else {
    stage(0, 0, 0);
    stage(1, 0, 1);
    int cur = 0;
    for (int k = 0; k < nk; ++k) {
      if (k + 1 < nk) asm volatile("s_waitcnt vmcnt(4)" ::: "memory");
      else            asm volatile("s_waitcnt vmcnt(0)" ::: "memory");
      __builtin_amdgcn_s_barrier();
      if (k + 2 < nk) {
        int tgt = cur + 2; if (tgt >= 3) tgt -= 3;
        stage(k + 2, 0, tgt);
      }
      compute(cur);
      cur = (cur == 2) ? 0 : cur + 1;
    }
  }

  // epilogue: D row = pixel = (lane>>4)*4 + r, col = channel = lane&15
  const int chl = lane & 15;
  const int pxq = (lane >> 4) * 4;
  if (outMode == 0) {
    unsigned short* outb = (unsigned short*)outp;
#pragma unroll
    for (int n = 0; n < 4; ++n) {
      const int ch = n0 + wn * 64 + n * 16 + chl;
      const float bb = biasL[ch];
#pragma unroll
      for (int m = 0; m < 4; ++m) {
        const int pxb = pm0 + wm * 64 + m * 16 + pxq;
#pragma unroll
        for (int r = 0; r < 4; ++r) {
          const int p = pxb + r;
          if (p < HW) {
            float vv = acc[m][n][r] + bb;
            if (relu) vv = fmaxf(vv, 0.f);
            outb[(pxOutB + p) * 256 + ch] = f2bf(vv);
          }
        }
      }
    }
  } else {
    float* outf = (float*)outp;
#pragma unroll
    for (int n = 0; n < 4; ++n) {
      const int co = n0 + wn * 64 + n * 16 + chl;
      if (co < HCOUT) {
        int aIdx, k2, off, isT = 0;
        if (co < 12)       { aIdx = co >> 2; k2 = co & 3; off = 0; }
        else if (co < 255) { int c = co - 12; aIdx = (c >= 162) ? 2 : (c >= 81 ? 1 : 0);
                             k2 = c - aIdx * 81; off = 4; }
        else               { int c = co - 255; aIdx = c >> 5; k2 = c & 31; off = 85; isT = 1; }
        const float bb = biasL[co];
#pragma unroll
        for (int m = 0; m < 4; ++m) {
          const int pxb = pm0 + wm * 64 + m * 16 + pxq;
#pragma unroll
          for (int r = 0; r < 4; ++r) {
            const int p = pxb + r;
            if (p < HW) {
              float vv = acc[m][n][r] + bb;
              if (isT) vv = tanhf(vv);
              outf[((size_t)b * NPTOT + pbase + (size_t)p * 3 + aIdx) * FEAT + off + k2] = vv;
            }
          }
        }
      }
    }
  }
}

// ---------------------------------------------------------------------------
__global__ __launch_bounds__(256) void k_zero(float* __restrict__ zb) {
  zb[threadIdx.x] = 0.f;
}

// ---------------------------------------------------------------------------
// fp32 NCHW -> bf16 NHWC tiled transpose (64px x 64ch per block via LDS)
__global__ __launch_bounds__(256) void k_tobf16nhwc(
    const float* __restrict__ in, unsigned short* __restrict__ out, int C, int HW) {
  __shared__ float t[64][65];
  const int p0 = blockIdx.x * 64, c0 = blockIdx.y * 64, b = blockIdx.z;
  const int tid = threadIdx.x;
  const float* ib = in + ((size_t)b * C + c0) * HW;
#pragma unroll 4
  for (int r = 0; r < 16; ++r) {
    int ch = r * 4 + (tid >> 6);
    int px = tid & 63;
    t[ch][px] = (p0 + px < HW) ? ib[(size_t)ch * HW + p0 + px] : 0.f;
  }
  __syncthreads();
#pragma unroll 4
  for (int r = 0; r < 16; ++r) {
    int px = r * 4 + (tid >> 6);
    int ch = tid & 63;
    if (p0 + px < HW)
      out[((size_t)b * HW + p0 + px) * C + c0 + ch] = f2bf(t[ch][px]);
  }
}

// ---------------------------------------------------------------------------
// weight convert+transpose: w2[tap][rowOff+co][ci] = w[co][ci][tap] (fp32->bf16)
__global__ __launch_bounds__(256) void k_wconv(
    const float* __restrict__ w, unsigned short* __restrict__ w2,
    int Cout, int Cin, int ntap, int rowStride, int rowOff) {
  int i = blockIdx.x * 256 + threadIdx.x;
  int total = Cout * Cin * ntap;
  if (i >= total) return;
  int co = i / (Cin * ntap);
  int rem = i - co * (Cin * ntap);
  int ci = rem / ntap;
  int tap = rem - ci * ntap;
  w2[((size_t)tap * rowStride + rowOff + co) * Cin + ci] = f2bf(w[i]);
}

// ---------------------------------------------------------------------------
__global__ __launch_bounds__(384) void k_bias_head(
    const float* __restrict__ bbox_b, const float* __restrict__ conf_b,
    const float* __restrict__ mask_b, float* __restrict__ bh) {
  int co = threadIdx.x;
  float v = 0.f;
  if (co < 12) v = bbox_b[co];
  else if (co < 255) v = conf_b[co - 12];
  else if (co < HCOUT) v = mask_b[co - 255];
  if (co < 384) bh[co] = v;
}

// ---------------------------------------------------------------------------
// pack three 256-entry bias vectors (level order: pred2, pred1, pred0)
__global__ __launch_bounds__(768) void k_bias3(
    const float* __restrict__ b2, const float* __restrict__ b1,
    const float* __restrict__ b0, float* __restrict__ dst) {
  int i = threadIdx.x;
  if (i < 256)      dst[i] = b2[i];
  else if (i < 512) dst[i] = b1[i - 256];
  else              dst[i] = b0[i - 512];
}

// ---------------------------------------------------------------------------
// jax-exact bilinear resize add, bf16 NHWC, C=256. thread = 8ch of one out px.
__global__ __launch_bounds__(256) void k_resize_add_nhwc(
    const unsigned short* __restrict__ in, unsigned short* __restrict__ out,
    int Hi, int Wi, int Ho, int Wo) {
  int idx = blockIdx.x * 256 + threadIdx.x;
  int HW = Ho * Wo;
  if (idx >= HW * 32) return;
  int b = blockIdx.z;
  int c0 = (idx & 31) * 8;
  int p = idx >> 5;
  int y = p / Wo, x = p - y * Wo;
  float sy = (y + 0.5f) * (float)Hi / (float)Ho - 0.5f;
  float sx = (x + 0.5f) * (float)Wi / (float)Wo - 0.5f;
  int iy0 = (int)floorf(sy), ix0 = (int)floorf(sx);
  float wy1 = sy - (float)iy0, wy0 = 1.f - wy1;
  float wx1 = sx - (float)ix0, wx0 = 1.f - wx1;
  if (iy0 < 0 || iy0 >= Hi) wy0 = 0.f;
  if (iy0 + 1 < 0 || iy0 + 1 >= Hi) wy1 = 0.f;
  if (ix0 < 0 || ix0 >= Wi) wx0 = 0.f;
  if (ix0 + 1 < 0 || ix0 + 1 >= Wi) wx1 = 0.f;
  float ty_ = wy0 + wy1, tx_ = wx0 + wx1;
  wy0 /= ty_; wy1 /= ty_; wx0 /= tx_; wx1 /= tx_;
  int y0 = min(max(iy0, 0), Hi - 1), y1 = min(max(iy0 + 1, 0), Hi - 1);
  int x0 = min(max(ix0, 0), Wi - 1), x1 = min(max(ix0 + 1, 0), Wi - 1);
  const unsigned short* ib = in + (size_t)b * Hi * Wi * 256;
  u16x8 v00 = *(const u16x8*)&ib[((size_t)y0 * Wi + x0) * 256 + c0];
  u16x8 v01 = *(const u16x8*)&ib[((size_t)y0 * Wi + x1) * 256 + c0];
  u16x8 v10 = *(const u16x8*)&ib[((size_t)y1 * Wi + x0) * 256 + c0];
  u16x8 v11 = *(const u16x8*)&ib[((size_t)y1 * Wi + x1) * 256 + c0];
  unsigned short* ob = out + ((size_t)b * HW + p) * 256 + c0;
  u16x8 cur = *(u16x8*)ob, res;
#pragma unroll
  for (int i = 0; i < 8; ++i) {
    float bl = wy0 * (wx0 * bf2f(v00[i]) + wx1 * bf2f(v01[i])) +
               wy1 * (wx0 * bf2f(v10[i]) + wx1 * bf2f(v11[i]));
    res[i] = f2bf(bf2f(cur[i]) + bl);
  }
  *(u16x8*)ob = res;
}

// ---------------------------------------------------------------------------
__global__ __launch_bounds__(256) void k_down_nhwc(
    const unsigned short* __restrict__ in, unsigned short* __restrict__ out,
    int Hi, int Wi) {
  int Ho = Hi / 2, Wo = Wi / 2, HW = Ho * Wo;
  int idx = blockIdx.x * 256 + threadIdx.x;
  if (idx >= HW * 32) return;
  int b = blockIdx.z;
  int c0 = (idx & 31) * 8;
  int p = idx >> 5;
  int y = p / Wo, x = p - y * Wo;
  *(u16x8*)&out[((size_t)b * HW + p) * 256 + c0] =
      *(const u16x8*)&in[((size_t)b * Hi * Wi + (size_t)(2 * y) * Wi + 2 * x) * 256 + c0];
}

// ---------------------------------------------------------------------------
__global__ __launch_bounds__(256) void priors_kernel(float* __restrict__ pr) {
  int pi = blockIdx.x * 256 + threadIdx.x;
  if (pi >= NPTOT) return;
  const int sizes[5] = {67, 33, 16, 8, 4};
  int idx = pi, H = 4;
#pragma unroll
  for (int L = 0; L < 5; ++L) {
    int cnt = sizes[L] * sizes[L] * 3;
    if (idx < cnt) { H = sizes[L]; break; }
    idx -= cnt;
  }
  int a = idx % 3; int cell = idx / 3;
  int x = cell % H; int y = cell / H;
  const float ars[3] = {1.0f, 0.5f, 2.0f};
  pr[pi * 4 + 0] = (x + 0.5f) / (float)H;
  pr[pi * 4 + 1] = (y + 0.5f) / (float)H;
  pr[pi * 4 + 2] = 3.0f * ars[a] / (float)H;
  pr[pi * 4 + 3] = 3.0f / ars[a] / (float)H;
}

// ---------------------------------------------------------------------------
extern "C" void kernel_launch(void* const* d_in, const int* in_sizes, int n_in,
                              void* d_out, int out_size, void* d_ws, size_t ws_size,
                              hipStream_t stream) {
  const float* c3 = (const float*)d_in[0];
  const float* c4 = (const float*)d_in[1];
  const float* c5 = (const float*)d_in[2];
  const float* lat_w5 = (const float*)d_in[3];  const float* lat_b5 = (const float*)d_in[4];
  const float* lat_w4 = (const float*)d_in[5];  const float* lat_b4 = (const float*)d_in[6];
  const float* lat_w3 = (const float*)d_in[7];  const float* lat_b3 = (const float*)d_in[8];
  const float* pred_w0 = (const float*)d_in[9];  const float* pred_b0 = (const float*)d_in[10];
  const float* pred_w1 = (const float*)d_in[11]; const float* pred_b1 = (const float*)d_in[12];
  const float* pred_w2 = (const float*)d_in[13]; const float* pred_b2 = (const float*)d_in[14];
  const float* up_w = (const float*)d_in[15];  const float* up_b = (const float*)d_in[16];
  const float* bbox_w = (const float*)d_in[17]; const float* bbox_b = (const float*)d_in[18];
  const float* conf_w = (const float*)d_in[19]; const float* conf_b = (const float*)d_in[20];
  const float* mask_w = (const float*)d_in[21]; const float* mask_b = (const float*)d_in[22];

  float* out = (float*)d_out;
  float* priors = out + (size_t)8 * NPTOT * FEAT;

  // workspace layout (bf16 element offsets); peak 48,700,160 elem = 97.40 MB
  unsigned short* B0 = (unsigned short*)d_ws;
  unsigned short* w2_lat5  = B0 + 0;         // 524288
  unsigned short* w2_pred0 = B0 + 524288;    // 589824
  unsigned short* w2_lat4  = B0 + 1114112;   // 262144
  unsigned short* w2_pred1 = B0 + 1376256;   // 589824
  unsigned short* w2_lat3  = B0 + 1966080;   // 131072
  unsigned short* w2_pred2 = B0 + 2097152;   // 589824
  unsigned short* w2_up    = B0 + 2686976;   // 589824
  unsigned short* w2_head  = B0 + 3276800;   // 9*384*256 = 884736 -> 4161536
  unsigned short* x5 = B0 + 4161536;         // 663552   -> 4825088
  unsigned short* x4 = B0 + 4825088;         // 2508800  -> 7333888
  unsigned short* x3 = B0 + 7333888;         // 9750528  -> 17084416
  unsigned short* P  = B0 + 17084416;        // 12111872 -> 29196288 (p3..p7 concat)
  unsigned short* R  = B0 + 29196288;        // 19501056 -> 48697344 (c5b/c4b/c3b; U later)
  float* bias_h = (float*)(B0 + 48697344);   // 384 f32  -> 48698112
  float* zb     = (float*)(B0 + 48698112);   // 256 f32  -> 48698624
  float* biasP  = (float*)(B0 + 48698624);   // 768 f32  -> 48700160
  // P level pixel offsets (px, per level, batch-major inside level)
  const int pxP[5] = {0, 35912, 44624, 46672, 47184};   // p3,p4,p5,p6,p7
  unsigned short* p3 = P;
  unsigned short* p5 = P + (size_t)pxP[2] * 256;
  unsigned short* p6 = P + (size_t)pxP[3] * 256;
  unsigned short* p7 = P + (size_t)pxP[4] * 256;
  unsigned short* U  = R;                    // R dead after FPN; 12.1M <= 19.5M

  if (ws_size < 48700160ull * 2ull) {        // diagnostic: priors only
    priors_kernel<<<dim3((NPTOT + 255) / 256), dim3(256), 0, stream>>>(priors);
    return;
  }

  auto wc = [&](const float* w_, unsigned short* w2_, int Cout, int Cin, int ntap,
                int rs, int ro) {
    int total = Cout * Cin * ntap;
    k_wconv<<<dim3((total + 255) / 256), dim3(256), 0, stream>>>(w_, w2_, Cout, Cin, ntap, rs, ro);
  };
  auto tonhwc = [&](const float* in_, unsigned short* out_, int C, int HW) {
    k_tobf16nhwc<<<dim3((HW + 63) / 64, C / 64, 8), dim3(256), 0, stream>>>(in_, out_, C, HW);
  };
  // single-level conv
  auto conv1 = [&](const unsigned short* in_, const unsigned short* w2_, const float* b_,
                   void* out_, int Cin, int Hi, int Wi, int Ho, int Wo, int pad, int ntap,
                   int Cout, int relu, int outMode, int pbase) {
    LvTab lv{};
    int nb = (Ho * Wo + 127) / 128;
    lv.pre[0] = 0; for (int i = 1; i < 6; ++i) lv.pre[i] = nb + (i - 1) * 1000000;
    lv.pxIn[0] = 0; lv.pxOut[0] = 0;
    lv.Hi[0] = Hi; lv.Wi[0] = Wi; lv.Ho[0] = Ho; lv.Wo[0] = Wo; lv.pbase[0] = pbase;
    lv.Cin[0] = Cin; lv.bOff[0] = 0; lv.wOff[0] = 0;
    dim3 g(nb, (Cout + 127) / 128, 8);
    if (ntap == 1)
      k_conv<1><<<g, dim3(256), 0, stream>>>(in_, w2_, b_, out_, zb, lv,
                                             pad, Cout, Cout, relu, outMode);
    else
      k_conv<9><<<g, dim3(256), 0, stream>>>(in_, w2_, b_, out_, zb, lv,
                                             pad, Cout, Cout, relu, outMode);
  };
  // batched pred conv: pred2 -> p3, pred1 -> p4, pred0 -> p5 (one launch)
  auto convP = [&]() {
    LvTab lv{};
    const int HiL[3] = {69, 35, 18}, HoL[3] = {67, 33, 16};
    const long long wOffL[3] = {1572864, 851968, 0};   // pred2/1/0 rel w2_pred0
    const int pxInL[3]  = {12392, 2592, 0};            // x3/x4/x5 rel x5 (px)
    const int pxOutL[3] = {0, 35912, 44624};           // p3/p4/p5 in P
    const int bOffL[3]  = {0, 256, 512};               // biasP packing
    int acc_ = 0;
    for (int i = 0; i < 3; ++i) {
      lv.pre[i] = acc_;
      acc_ += (HoL[i] * HoL[i] + 127) / 128;
      lv.pxIn[i] = pxInL[i]; lv.pxOut[i] = pxOutL[i];
      lv.Hi[i] = HiL[i]; lv.Wi[i] = HiL[i]; lv.Ho[i] = HoL[i]; lv.Wo[i] = HoL[i];
      lv.pbase[i] = 0; lv.Cin[i] = 256; lv.bOff[i] = bOffL[i]; lv.wOff[i] = wOffL[i];
    }
    lv.pre[3] = acc_; lv.pre[4] = acc_ + 1000000; lv.pre[5] = acc_ + 2000000;
    dim3 g(acc_, 2, 8);
    k_conv<9><<<g, dim3(256), 0, stream>>>(x5, w2_pred0, biasP, P, zb, lv,
                                           0, 256, 256, 1, 0);
  };
  // 5-level batched conv (Cin=256, ntap=9, pad=1, same-size)
  const int Hl[5] = {67, 33, 16, 8, 4};
  const int pbl[5] = {0, 13467, 16734, 17502, 17694};
  auto conv5 = [&](const unsigned short* in_, const unsigned short* w2_, const float* b_,
                   void* out_, int Cout, int CoutRows, int relu, int outMode) {
    LvTab lv{};
    int acc_ = 0;
    for (int i = 0; i < 5; ++i) {
      lv.pre[i] = acc_;
      acc_ += (Hl[i] * Hl[i] + 127) / 128;
      lv.pxIn[i] = pxP[i]; lv.pxOut[i] = pxP[i];
      lv.Hi[i] = Hl[i]; lv.Wi[i] = Hl[i]; lv.Ho[i] = Hl[i]; lv.Wo[i] = Hl[i];
      lv.pbase[i] = pbl[i]; lv.Cin[i] = 256; lv.bOff[i] = 0; lv.wOff[i] = 0;
    }
    lv.pre[5] = acc_;
    dim3 g(acc_, (Cout + 127) / 128, 8);
    k_conv<9><<<g, dim3(256), 0, stream>>>(in_, w2_, b_, out_, zb, lv,
                                           1, Cout, CoutRows, relu, outMode);
  };

  // ---- zero region + weights (bf16 repack; head rows zero-padded to 384) ----
  k_zero<<<dim3(1), dim3(256), 0, stream>>>(zb);
  hipMemsetAsync(w2_head, 0, 9ull * HROWS * 256 * 2, stream);
  wc(lat_w5, w2_lat5, 256, 2048, 1, 256, 0);
  wc(pred_w0, w2_pred0, 256, 256, 9, 256, 0);
  wc(lat_w4, w2_lat4, 256, 1024, 1, 256, 0);
  wc(pred_w1, w2_pred1, 256, 256, 9, 256, 0);
  wc(lat_w3, w2_lat3, 256, 512, 1, 256, 0);
  wc(pred_w2, w2_pred2, 256, 256, 9, 256, 0);
  wc(up_w, w2_up, 256, 256, 9, 256, 0);
  wc(bbox_w, w2_head, 12, 256, 9, HROWS, 0);
  wc(conf_w, w2_head, 243, 256, 9, HROWS, 12);
  wc(mask_w, w2_head, 96, 256, 9, HROWS, 255);
  k_bias_head<<<dim3(1), dim3(384), 0, stream>>>(bbox_b, conf_b, mask_b, bias_h);
  k_bias3<<<dim3(1), dim3(768), 0, stream>>>(pred_b2, pred_b1, pred_b0, biasP);

  // ---- FPN laterals + resize chain ----
  tonhwc(c5, R, 2048, 324);
  conv1(R, w2_lat5, lat_b5, x5, 2048, 18, 18, 18, 18, 0, 1, 256, 0, 0, 0);
  tonhwc(c4, R, 1024, 1225);
  conv1(R, w2_lat4, lat_b4, x4, 1024, 35, 35, 35, 35, 0, 1, 256, 0, 0, 0);
  k_resize_add_nhwc<<<dim3((1225 * 32 + 255) / 256, 1, 8), dim3(256), 0, stream>>>(x5, x4, 18, 18, 35, 35);
  tonhwc(c3, R, 512, 4761);
  conv1(R, w2_lat3, lat_b3, x3, 512, 69, 69, 69, 69, 0, 1, 256, 0, 0, 0);
  k_resize_add_nhwc<<<dim3((4761 * 32 + 255) / 256, 1, 8), dim3(256), 0, stream>>>(x4, x3, 35, 35, 69, 69);

  // ---- pred convs: ONE batched launch (x5,x4,x3 all final) ----
  convP();
  k_down_nhwc<<<dim3((64 * 32 + 255) / 256, 1, 8), dim3(256), 0, stream>>>(p5, p6, 16, 16);
  k_down_nhwc<<<dim3((16 * 32 + 255) / 256, 1, 8), dim3(256), 0, stream>>>(p6, p7, 8, 8);

  // ---- heads: ONE batched up-conv + ONE batched fused head conv ----
  conv5(P, w2_up, up_b, U, 256, 256, 1, 0);
  conv5(U, w2_head, bias_h, out, HCOUT, HROWS, 0, 1);

  priors_kernel<<<dim3((NPTOT + 255) / 256), dim3(256), 0, stream>>>(priors);
}